// Round 8
// baseline (1067.658 us; speedup 1.0000x reference)
//
#include <hip/hip_runtime.h>
#include <cstdint>

#define NN   50000
#define SS   2048
#define KSUB 64
#define HH   128
#define EE   (SS * 256)
#define SKK  (SS * KSUB)    // 131072
#define LLAY 5

typedef __attribute__((ext_vector_type(8))) short bhalf8;
typedef __attribute__((ext_vector_type(4))) float f32x4;

__device__ __forceinline__ ushort f2b(float f) {
  uint u = __builtin_bit_cast(uint, f);
  uint r = (u + 0x7FFFu + ((u >> 16) & 1u)) >> 16;
  return (ushort)r;
}
__device__ __forceinline__ float b2f(ushort u) {
  uint v = ((uint)u) << 16;
  return __builtin_bit_cast(float, v);
}
// split fp32 -> (hi, lo) bf16 pair; hi + lo ~= f with ~2^-18 residual
__device__ __forceinline__ void fsplit(float f, ushort& hi, ushort& lo) {
  hi = f2b(f);
  lo = f2b(f - b2f(hi));
}
// byte offset into a [64][128]-short LDS tile, T2 XOR swizzle (row stride 256B)
__device__ __forceinline__ int zoff(int row, int col) {
  return row * 256 + (((col * 2) & 255) ^ ((row & 7) << 4));
}

// ---------------------------------------------------------------------------
// Fold node_proj through init_proj; emit split bf16 B^T layout [n][c]
// ---------------------------------------------------------------------------
__global__ void fold_M_k(const float* __restrict__ Wn, const float* __restrict__ Wi,
                         ushort* __restrict__ Mth, ushort* __restrict__ Mtl) {
  int c = blockIdx.x, n = threadIdx.x;
  float s = 0.f;
  for (int k = 0; k < HH; ++k) s = fmaf(Wn[c * HH + k], Wi[k * HH + n], s);
  ushort hi, lo; fsplit(s, hi, lo);
  Mth[n * HH + c] = hi; Mtl[n * HH + c] = lo;
}

__global__ void fold_vec_k(const float* __restrict__ Wi, const float* __restrict__ wl,
                           const float* __restrict__ bnb, const float* __restrict__ blb,
                           const float* __restrict__ bi, const float* __restrict__ remb,
                           float* __restrict__ vl, float* __restrict__ c0,
                           float* __restrict__ rev) {
  int n = threadIdx.x;
  float svl = 0.f, sc0 = bi[n], r0 = 0.f, r1 = 0.f;
  for (int k = 0; k < HH; ++k) {
    svl = fmaf(wl[k], Wi[(HH + k) * HH + n], svl);
    sc0 = fmaf(bnb[k], Wi[k * HH + n], sc0);
    sc0 = fmaf(blb[k], Wi[(HH + k) * HH + n], sc0);
    r0  = fmaf(remb[k],      Wi[(2 * HH + k) * HH + n], r0);
    r1  = fmaf(remb[HH + k], Wi[(2 * HH + k) * HH + n], r1);
  }
  vl[n] = svl; c0[n] = sc0; rev[n] = r0; rev[HH + n] = r1;
}

// ---------------------------------------------------------------------------
// Transpose+convert all layer weights to split bf16 B^T layout (one launch).
// ---------------------------------------------------------------------------
__global__ void wconv_k(const float* __restrict__ w1, const float* __restrict__ w2,
                        const float* __restrict__ mp2w,
                        ushort* __restrict__ w1th, ushort* __restrict__ w1tl,
                        ushort* __restrict__ w2th, ushort* __restrict__ w2tl,
                        ushort* __restrict__ mp2th, ushort* __restrict__ mp2tl) {
  int b = blockIdx.x, n = threadIdx.x;
  ushort hi, lo;
  if (b < 640) {
    int l = b >> 7, k = b & 127;
    fsplit(w1[((size_t)l * HH + k) * HH + n], hi, lo);
    w1th[((size_t)l * HH + n) * HH + k] = hi;
    w1tl[((size_t)l * HH + n) * HH + k] = lo;
  } else if (b < 1280) {
    int bb = b - 640; int l = bb >> 7, k = bb & 127;
    fsplit(w2[((size_t)l * HH + k) * HH + n], hi, lo);
    w2th[((size_t)l * HH + n) * HH + k] = hi;
    w2tl[((size_t)l * HH + n) * HH + k] = lo;
  } else {
    int bb = b - 1280; int l = bb >> 8, k = bb & 255;
    fsplit(mp2w[((size_t)l * 256 + k) * HH + n], hi, lo);
    mp2th[((size_t)l * HH + n) * 256 + k] = hi;
    mp2tl[((size_t)l * HH + n) * 256 + k] = lo;
  }
}

// ---------------------------------------------------------------------------
// Per-node multiplicity count (for scatter-mean 1/cnt)
// ---------------------------------------------------------------------------
__global__ void count_k(const int* __restrict__ idc, int* __restrict__ cnt) {
  int i = blockIdx.x * 256 + threadIdx.x;
  if (i < SKK) atomicAdd(&cnt[idc[i]], 1);
}

// ---------------------------------------------------------------------------
// Per-subgraph counting sort of edges by dst -> CSR
// ---------------------------------------------------------------------------
__launch_bounds__(256)
__global__ void presort_k(const int* __restrict__ e_src, const int* __restrict__ e_dst,
                          const int* __restrict__ edge_ptr, int* __restrict__ row_ptr,
                          int* __restrict__ ssrc) {
  __shared__ int cnt[KSUB];
  __shared__ int base[KSUB];
  __shared__ int cur[KSUB];
  const int s = blockIdx.x, tid = threadIdx.x;
  const int p0 = edge_ptr[s], p1 = edge_ptr[s + 1];
  if (tid < KSUB) cnt[tid] = 0;
  __syncthreads();
  for (int e = p0 + tid; e < p1; e += 256) atomicAdd(&cnt[e_dst[e]], 1);
  __syncthreads();
  if (tid == 0) {
    int a = 0;
    for (int d = 0; d < KSUB; ++d) { base[d] = a; a += cnt[d]; }
  }
  __syncthreads();
  if (tid < KSUB) { row_ptr[s * KSUB + tid] = p0 + base[tid]; cur[tid] = base[tid]; }
  if (s == 0 && tid == 0) row_ptr[SS * KSUB] = edge_ptr[SS];
  __syncthreads();
  for (int e = p0 + tid; e < p1; e += 256) {
    int d = e_dst[e];
    int pos = atomicAdd(&cur[d], 1);
    ssrc[p0 + pos] = e_src[e];
  }
}

// ---------------------------------------------------------------------------
// MEGA kernel: per subgraph (64 rows):
//   phase A: h_new = bn(uf) + h_old (residual) [skip BN if FIRST];
//            BN coef computed INLINE from stats; write h_new, keep fp32 in LDS
//   phase B: GIN aggregation (interleaved channel mapping)
//   phase C: split z_agg -> swizzled bf16 LDS tile Z (aliases hl)
//   MLP1:    t = relu(Z @ W1 + b1) -> swizzled LDS tile T (aliases Z)
//            (W1 fragments preloaded to regs before the MFMA loop — T14)
//   MLP2:    z = T @ W2 + b2 -> global zh/zl (split)
//            + fp32 atomic accumulate into xa_acc[node] (replaces the whole
//              scatter_mean kernel + node-CSR machinery)
// ---------------------------------------------------------------------------
template <bool FIRST>
__launch_bounds__(256, 4)
__global__ void gin_mega_k(float* __restrict__ h, const float* __restrict__ uf,
                           const float* __restrict__ stats,
                           const float* __restrict__ gamma, const float* __restrict__ beta,
                           const int* __restrict__ row_ptr, const int* __restrict__ ssrc,
                           const float* __restrict__ gin_eps, const int layer,
                           const ushort* __restrict__ B1h, const ushort* __restrict__ B1l,
                           const ushort* __restrict__ B2h, const ushort* __restrict__ B2l,
                           const float* __restrict__ bias1, const float* __restrict__ bias2,
                           ushort* __restrict__ zh, ushort* __restrict__ zl,
                           const int* __restrict__ idc, float* __restrict__ xa_acc) {
  constexpr int LDH = 132;
  __shared__ __align__(16) char smem[KSUB * LDH * 4];   // 33792 B, phase-aliased
  float*  hl = (float*)smem;                 // [64][132] fp32 (phases A,B)
  ushort* Zh = (ushort*)smem;                // [64][128] swizzled (phases C..MLP2)
  ushort* Zl = (ushort*)(smem + KSUB * HH * 2);
  const int s = blockIdx.x, tid = threadIdx.x;
  const size_t base = (size_t)s * KSUB * HH;

  // ---- phase A (BN coef inline; c constant across 'it' since 1024 % 128 == 0) ----
  float csc[4], csh[4];
  const int cb = (tid * 4) & 127;
  if constexpr (!FIRST) {
    const float invM = 1.0f / (float)SKK;
#pragma unroll
    for (int e = 0; e < 4; ++e) {
      const float mu = stats[cb + e] * invM;
      const float var = fmaf(-mu, mu, stats[HH + cb + e] * invM);
      const float sc = rsqrtf(var + 1e-5f) * gamma[cb + e];
      csc[e] = sc; csh[e] = fmaf(-mu, sc, beta[cb + e]);
    }
  }
#pragma unroll
  for (int it = 0; it < 8; ++it) {
    const int idx = it * 1024 + tid * 4;
    const int m = idx >> 7, c = idx & 127;
    float4 hv = *(const float4*)&h[base + idx];
    if constexpr (!FIRST) {
      float4 u4 = *(const float4*)&uf[base + idx];
      hv.x += fmaf(u4.x, csc[0], csh[0]);
      hv.y += fmaf(u4.y, csc[1], csh[1]);
      hv.z += fmaf(u4.z, csc[2], csh[2]);
      hv.w += fmaf(u4.w, csc[3], csh[3]);
      *(float4*)&h[base + idx] = hv;
    }
    *(float4*)&hl[m * LDH + c] = hv;
  }
  __syncthreads();

  // ---- phase B: aggregation (interleaved channel mapping) ----
  const float ep1 = 1.0f + gin_eps[layer];
  const int d = tid >> 2, q4 = (tid & 3) * 4;   // cols q4 + 16*j + k
  const int g = s * KSUB + d;
  const int e0 = row_ptr[g], e1 = row_ptr[g + 1];
  float a[32];
  {
    const float* hp0 = &hl[d * LDH + q4];
#pragma unroll
    for (int j = 0; j < 8; ++j) {
      float4 v = *(const float4*)(hp0 + 16 * j);
      a[4 * j + 0] = ep1 * v.x; a[4 * j + 1] = ep1 * v.y;
      a[4 * j + 2] = ep1 * v.z; a[4 * j + 3] = ep1 * v.w;
    }
    for (int e = e0; e < e1; ++e) {
      const float* hp = &hl[ssrc[e] * LDH + q4];
#pragma unroll
      for (int j = 0; j < 8; ++j) {
        float4 v = *(const float4*)(hp + 16 * j);
        a[4 * j + 0] += v.x; a[4 * j + 1] += v.y;
        a[4 * j + 2] += v.z; a[4 * j + 3] += v.w;
      }
    }
  }
  __syncthreads();          // all hl reads done (Z aliases hl)

  // ---- phase C: split z_agg into swizzled LDS tile (8B writes) ----
#pragma unroll
  for (int j = 0; j < 8; ++j) {
    ushort th[4], tl[4];
#pragma unroll
    for (int k = 0; k < 4; ++k) fsplit(a[4 * j + k], th[k], tl[k]);
    const int o = zoff(d, q4 + 16 * j);
    *(uint2*)((char*)Zh + o) = *(uint2*)th;
    *(uint2*)((char*)Zl + o) = *(uint2*)tl;
  }
  __syncthreads();

  // ---- MLP GEMMs ----
  const int lane = tid & 63, wv = tid >> 6;
  const int fr = lane & 15, quad = lane >> 4;
  const int nj0 = wv * 32 + fr, nj1 = nj0 + 16;

  // preload ALL W1 fragments into regs (L2-resident; latency hides under LDS reads)
  bhalf8 b1h[4][2], b1l[4][2];
#pragma unroll
  for (int ch = 0; ch < 4; ++ch)
#pragma unroll
    for (int j = 0; j < 2; ++j) {
      const size_t off = (size_t)(wv * 32 + j * 16 + fr) * HH + ch * 32 + quad * 8;
      b1h[ch][j] = *(const bhalf8*)(B1h + off);
      b1l[ch][j] = *(const bhalf8*)(B1l + off);
    }

  f32x4 acc[4][2];
#pragma unroll
  for (int i = 0; i < 4; ++i) { acc[i][0] = (f32x4){0,0,0,0}; acc[i][1] = (f32x4){0,0,0,0}; }

  // MLP1: t = relu(Z @ W1 + b1)
#pragma unroll
  for (int ch = 0; ch < 4; ++ch) {
    bhalf8 afh[4], afl[4];
#pragma unroll
    for (int i = 0; i < 4; ++i) {
      const int o = zoff(i * 16 + fr, ch * 32 + quad * 8);
      afh[i] = *(const bhalf8*)((const char*)Zh + o);
      afl[i] = *(const bhalf8*)((const char*)Zl + o);
    }
#pragma unroll
    for (int i = 0; i < 4; ++i)
#pragma unroll
      for (int j = 0; j < 2; ++j) {
        acc[i][j] = __builtin_amdgcn_mfma_f32_16x16x32_bf16(afh[i], b1h[ch][j], acc[i][j], 0, 0, 0);
        acc[i][j] = __builtin_amdgcn_mfma_f32_16x16x32_bf16(afl[i], b1h[ch][j], acc[i][j], 0, 0, 0);
        acc[i][j] = __builtin_amdgcn_mfma_f32_16x16x32_bf16(afh[i], b1l[ch][j], acc[i][j], 0, 0, 0);
      }
  }
  __syncthreads();          // all Z reads done (T aliases Z)

  // preload W2 fragments (latency hides under epilogue 1 + barrier)
  bhalf8 b2h[4][2], b2l[4][2];
#pragma unroll
  for (int ch = 0; ch < 4; ++ch)
#pragma unroll
    for (int j = 0; j < 2; ++j) {
      const size_t off = (size_t)(wv * 32 + j * 16 + fr) * HH + ch * 32 + quad * 8;
      b2h[ch][j] = *(const bhalf8*)(B2h + off);
      b2l[ch][j] = *(const bhalf8*)(B2l + off);
    }

  // epilogue 1: T = relu(acc + b1), split, into swizzled LDS
  {
    const float b10 = bias1[nj0], b11 = bias1[nj1];
#pragma unroll
    for (int i = 0; i < 4; ++i)
#pragma unroll
      for (int r = 0; r < 4; ++r) {
        const int row = i * 16 + quad * 4 + r;
        const float o0 = fmaxf(acc[i][0][r] + b10, 0.f);
        const float o1 = fmaxf(acc[i][1][r] + b11, 0.f);
        ushort h0, l0, h1, l1; fsplit(o0, h0, l0); fsplit(o1, h1, l1);
        *(ushort*)((char*)Zh + zoff(row, nj0)) = h0;
        *(ushort*)((char*)Zl + zoff(row, nj0)) = l0;
        *(ushort*)((char*)Zh + zoff(row, nj1)) = h1;
        *(ushort*)((char*)Zl + zoff(row, nj1)) = l1;
      }
  }
  __syncthreads();

  // MLP2: z = T @ W2 + b2
#pragma unroll
  for (int i = 0; i < 4; ++i) { acc[i][0] = (f32x4){0,0,0,0}; acc[i][1] = (f32x4){0,0,0,0}; }
#pragma unroll
  for (int ch = 0; ch < 4; ++ch) {
    bhalf8 afh[4], afl[4];
#pragma unroll
    for (int i = 0; i < 4; ++i) {
      const int o = zoff(i * 16 + fr, ch * 32 + quad * 8);
      afh[i] = *(const bhalf8*)((const char*)Zh + o);
      afl[i] = *(const bhalf8*)((const char*)Zl + o);
    }
#pragma unroll
    for (int i = 0; i < 4; ++i)
#pragma unroll
      for (int j = 0; j < 2; ++j) {
        acc[i][j] = __builtin_amdgcn_mfma_f32_16x16x32_bf16(afh[i], b2h[ch][j], acc[i][j], 0, 0, 0);
        acc[i][j] = __builtin_amdgcn_mfma_f32_16x16x32_bf16(afl[i], b2h[ch][j], acc[i][j], 0, 0, 0);
        acc[i][j] = __builtin_amdgcn_mfma_f32_16x16x32_bf16(afh[i], b2l[ch][j], acc[i][j], 0, 0, 0);
      }
  }

  // epilogue 2: z -> global (split) + fp32 atomic accumulate into xa_acc
  {
    const float b20 = bias2[nj0], b21 = bias2[nj1];
#pragma unroll
    for (int i = 0; i < 4; ++i)
#pragma unroll
      for (int r = 0; r < 4; ++r) {
        const int row = i * 16 + quad * 4 + r;
        const int gid = idc[s * KSUB + row];
        const size_t gb = base + (size_t)row * HH;
        const float o0 = acc[i][0][r] + b20;
        const float o1 = acc[i][1][r] + b21;
        ushort h0, l0, h1, l1; fsplit(o0, h0, l0); fsplit(o1, h1, l1);
        zh[gb + nj0] = h0; zl[gb + nj0] = l0;
        zh[gb + nj1] = h1; zl[gb + nj1] = l1;
        unsafeAtomicAdd(&xa_acc[(size_t)gid * HH + nj0], o0);
        unsafeAtomicAdd(&xa_acc[(size_t)gid * HH + nj1], o1);
      }
  }
}

// ---------------------------------------------------------------------------
// MP-2 GEMM: verified 128-row LDS-staged structure + T14 issue-early prefetch.
// K-half 2 now stages from fp32 xa_acc (atomic sums) scaled by 1/cnt, with
// on-the-fly fsplit (mgemm0-style) — replaces the xah/xal materialization.
// ---------------------------------------------------------------------------
__launch_bounds__(256, 3)
__global__ void mp2_k(const ushort* __restrict__ Ah, const ushort* __restrict__ Al,
                      const float* __restrict__ xaf,
                      const ushort* __restrict__ Bh, const ushort* __restrict__ Bl,
                      const float* __restrict__ bias, float* __restrict__ Cf,
                      const int* __restrict__ idc, const int* __restrict__ cnt,
                      float* __restrict__ stats) {
  constexpr int LDP = 40;   // LDS row stride in shorts
  __shared__ __align__(16) ushort Ash[128 * LDP];
  __shared__ __align__(16) ushort Asl[128 * LDP];
  __shared__ __align__(16) ushort Bsh[128 * LDP];
  __shared__ __align__(16) ushort Bsl[128 * LDP];
  const int tid = threadIdx.x;
  const int row0 = blockIdx.x * 128;
  const int lane = tid & 63, wv = tid >> 6;
  const int wm = (wv >> 1) * 64, wn = (wv & 1) * 64;
  const int fr = lane & 15, quad = lane >> 4;
  const int sr = tid >> 1;            // staging row 0..127
  const int sc = (tid & 1) * 16;      // staging column offset {0,16}
  const int grow = idc[row0 + sr];    // gather node for K-half 2 (hoisted)
  const float rcp = 1.0f / (float)max(cnt[grow], 1);

  f32x4 acc[4][4];
#pragma unroll
  for (int i = 0; i < 4; ++i)
#pragma unroll
    for (int j = 0; j < 4; ++j) acc[i][j] = (f32x4){0.f, 0.f, 0.f, 0.f};

  uint4  pa0, pa1, pa2, pa3;          // prefetch regs, bf16 z path (ch<4)
  float4 pf0, pf1, pf2, pf3;          // prefetch regs, fp32 xa path (ch>=4)
  uint4  pb0, pb1, pb2, pb3;
  auto LA = [&](int ch) {
    if (ch < 4) {
      const size_t off = (size_t)(row0 + sr) * HH + ch * 32 + sc;
      pa0 = *(const uint4*)(Ah + off); pa1 = *(const uint4*)(Ah + off + 8);
      pa2 = *(const uint4*)(Al + off); pa3 = *(const uint4*)(Al + off + 8);
    } else {
      const float* src = xaf + (size_t)grow * HH + (ch - 4) * 32 + sc;
      pf0 = *(const float4*)(src);     pf1 = *(const float4*)(src + 4);
      pf2 = *(const float4*)(src + 8); pf3 = *(const float4*)(src + 12);
    }
  };
  auto LB = [&](int ch) {
    const size_t off = (size_t)sr * 256 + ch * 32 + sc;
    pb0 = *(const uint4*)(Bh + off); pb1 = *(const uint4*)(Bh + off + 8);
    pb2 = *(const uint4*)(Bl + off); pb3 = *(const uint4*)(Bl + off + 8);
  };

  LA(0); LB(0);
#pragma unroll
  for (int ch = 0; ch < 8; ++ch) {
    // ---- write prefetched chunk to LDS ----
    if (ch < 4) {
      *(uint4*)&Ash[sr * LDP + sc]     = pa0;
      *(uint4*)&Ash[sr * LDP + sc + 8] = pa1;
      *(uint4*)&Asl[sr * LDP + sc]     = pa2;
      *(uint4*)&Asl[sr * LDP + sc + 8] = pa3;
    } else {
      float fv[16];
      *(float4*)&fv[0]  = pf0; *(float4*)&fv[4]  = pf1;
      *(float4*)&fv[8]  = pf2; *(float4*)&fv[12] = pf3;
      ushort hi[16], lo[16];
#pragma unroll
      for (int e = 0; e < 16; ++e) fsplit(fv[e] * rcp, hi[e], lo[e]);
      *(uint4*)&Ash[sr * LDP + sc]     = *(uint4*)&hi[0];
      *(uint4*)&Ash[sr * LDP + sc + 8] = *(uint4*)&hi[8];
      *(uint4*)&Asl[sr * LDP + sc]     = *(uint4*)&lo[0];
      *(uint4*)&Asl[sr * LDP + sc + 8] = *(uint4*)&lo[8];
    }
    *(uint4*)&Bsh[sr * LDP + sc]     = pb0;
    *(uint4*)&Bsh[sr * LDP + sc + 8] = pb1;
    *(uint4*)&Bsl[sr * LDP + sc]     = pb2;
    *(uint4*)&Bsl[sr * LDP + sc + 8] = pb3;
    __syncthreads();
    // ---- issue next chunk's global loads (fly during MFMA) ----
    if (ch < 7) { LA(ch + 1); LB(ch + 1); }
    // ---- one K=32 MFMA step, bf16x3 ----
    bhalf8 afh[4], afl[4], bfh[4], bfl[4];
#pragma unroll
    for (int i = 0; i < 4; ++i) {
      const int r = (wm + i * 16 + fr) * LDP + quad * 8;
      afh[i] = *(const bhalf8*)&Ash[r];
      afl[i] = *(const bhalf8*)&Asl[r];
    }
#pragma unroll
    for (int j = 0; j < 4; ++j) {
      const int r = (wn + j * 16 + fr) * LDP + quad * 8;
      bfh[j] = *(const bhalf8*)&Bsh[r];
      bfl[j] = *(const bhalf8*)&Bsl[r];
    }
#pragma unroll
    for (int i = 0; i < 4; ++i)
#pragma unroll
      for (int j = 0; j < 4; ++j) {
        acc[i][j] = __builtin_amdgcn_mfma_f32_16x16x32_bf16(afh[i], bfh[j], acc[i][j], 0, 0, 0);
        acc[i][j] = __builtin_amdgcn_mfma_f32_16x16x32_bf16(afl[i], bfh[j], acc[i][j], 0, 0, 0);
        acc[i][j] = __builtin_amdgcn_mfma_f32_16x16x32_bf16(afh[i], bfl[j], acc[i][j], 0, 0, 0);
      }
    __syncthreads();
  }

  // ---- epilogue: relu + bias, uf write, BN stats ----
  const int nj[4] = {wn + fr, wn + 16 + fr, wn + 32 + fr, wn + 48 + fr};
  float bb[4];
#pragma unroll
  for (int j = 0; j < 4; ++j) bb[j] = bias[nj[j]];
  float psum[4] = {0.f, 0.f, 0.f, 0.f}, psq[4] = {0.f, 0.f, 0.f, 0.f};
#pragma unroll
  for (int i = 0; i < 4; ++i)
#pragma unroll
    for (int r = 0; r < 4; ++r) {
      const int m = row0 + wm + i * 16 + quad * 4 + r;
      const size_t base = (size_t)m * HH;
#pragma unroll
      for (int j = 0; j < 4; ++j) {
        float o = fmaxf(acc[i][j][r] + bb[j], 0.f);
        Cf[base + nj[j]] = o;
        psum[j] += o; psq[j] += o * o;
      }
    }
  float* ssum = (float*)Ash;      // dead past last barrier
  float* ssq = ssum + HH;
  if (tid < HH) { ssum[tid] = 0.f; ssq[tid] = 0.f; }
  __syncthreads();
#pragma unroll
  for (int j = 0; j < 4; ++j) {
    atomicAdd(&ssum[nj[j]], psum[j]);
    atomicAdd(&ssq[nj[j]], psq[j]);
  }
  __syncthreads();
  if (tid < HH) {
    unsafeAtomicAdd(&stats[tid], ssum[tid]);
    unsafeAtomicAdd(&stats[HH + tid], ssq[tid]);
  }
}

// ---------------------------------------------------------------------------
// Split-bf16 MFMA GEMM (round-0 verified LDS-staged version) — MODE 0 only.
// ---------------------------------------------------------------------------
__launch_bounds__(256, 2)
__global__ void mgemm0_k(const float* __restrict__ Afp,
                         const ushort* __restrict__ Bh, const ushort* __restrict__ Bl,
                         float* __restrict__ Cf,
                         const int* __restrict__ idc, const float* __restrict__ log_probs,
                         const int* __restrict__ root_local, const float* __restrict__ vl,
                         const float* __restrict__ c0v, const float* __restrict__ rev) {
  constexpr int LDP = 40;
  __shared__ __align__(16) ushort Ash[128 * LDP];
  __shared__ __align__(16) ushort Asl[128 * LDP];
  __shared__ __align__(16) ushort Bsh[128 * LDP];
  __shared__ __align__(16) ushort Bsl[128 * LDP];
  const int tid = threadIdx.x;
  const int row0 = blockIdx.x * 128;
  const int lane = tid & 63, wv = tid >> 6;
  const int wm = (wv >> 1) * 64, wn = (wv & 1) * 64;
  const int fr = lane & 15, quad = lane >> 4;
  const int sr = tid >> 1;
  const int sc = (tid & 1) * 16;

  f32x4 acc[4][4];
#pragma unroll
  for (int i = 0; i < 4; ++i)
#pragma unroll
    for (int j = 0; j < 4; ++j) acc[i][j] = (f32x4){0.f, 0.f, 0.f, 0.f};

  for (int ch = 0; ch < 4; ++ch) {
    {
      const float* src = Afp + (size_t)idc[row0 + sr] * HH + ch * 32 + sc;
      float fv[16];
      *(float4*)&fv[0]  = *(const float4*)(src);
      *(float4*)&fv[4]  = *(const float4*)(src + 4);
      *(float4*)&fv[8]  = *(const float4*)(src + 8);
      *(float4*)&fv[12] = *(const float4*)(src + 12);
      ushort hi[16], lo[16];
#pragma unroll
      for (int e = 0; e < 16; ++e) fsplit(fv[e], hi[e], lo[e]);
      *(uint4*)&Ash[sr * LDP + sc]     = *(uint4*)&hi[0];
      *(uint4*)&Ash[sr * LDP + sc + 8] = *(uint4*)&hi[8];
      *(uint4*)&Asl[sr * LDP + sc]     = *(uint4*)&lo[0];
      *(uint4*)&Asl[sr * LDP + sc + 8] = *(uint4*)&lo[8];
    }
    {
      const size_t off = (size_t)sr * HH + ch * 32 + sc;
      *(uint4*)&Bsh[sr * LDP + sc]     = *(const uint4*)(Bh + off);
      *(uint4*)&Bsh[sr * LDP + sc + 8] = *(const uint4*)(Bh + off + 8);
      *(uint4*)&Bsl[sr * LDP + sc]     = *(const uint4*)(Bl + off);
      *(uint4*)&Bsl[sr * LDP + sc + 8] = *(const uint4*)(Bl + off + 8);
    }
    __syncthreads();
    bhalf8 afh[4], afl[4], bfh[4], bfl[4];
#pragma unroll
    for (int i = 0; i < 4; ++i) {
      const int r = (wm + i * 16 + fr) * LDP + quad * 8;
      afh[i] = *(const bhalf8*)&Ash[r];
      afl[i] = *(const bhalf8*)&Asl[r];
    }
#pragma unroll
    for (int j = 0; j < 4; ++j) {
      const int r = (wn + j * 16 + fr) * LDP + quad * 8;
      bfh[j] = *(const bhalf8*)&Bsh[r];
      bfl[j] = *(const bhalf8*)&Bsl[r];
    }
#pragma unroll
    for (int i = 0; i < 4; ++i)
#pragma unroll
      for (int j = 0; j < 4; ++j) {
        acc[i][j] = __builtin_amdgcn_mfma_f32_16x16x32_bf16(afh[i], bfh[j], acc[i][j], 0, 0, 0);
        acc[i][j] = __builtin_amdgcn_mfma_f32_16x16x32_bf16(afl[i], bfh[j], acc[i][j], 0, 0, 0);
        acc[i][j] = __builtin_amdgcn_mfma_f32_16x16x32_bf16(afh[i], bfl[j], acc[i][j], 0, 0, 0);
      }
    __syncthreads();
  }

  const int nj[4] = {wn + fr, wn + 16 + fr, wn + 32 + fr, wn + 48 + fr};
  float c0a[4], vla[4], re0[4], re1[4];
#pragma unroll
  for (int j = 0; j < 4; ++j) {
    c0a[j] = c0v[nj[j]]; vla[j] = vl[nj[j]];
    re0[j] = rev[nj[j]]; re1[j] = rev[HH + nj[j]];
  }
#pragma unroll
  for (int i = 0; i < 4; ++i)
#pragma unroll
    for (int r = 0; r < 4; ++r) {
      const int m = row0 + wm + i * 16 + quad * 4 + r;
      const int s = m >> 6;
      const float lp = log_probs[s];
      const bool isr = (m & 63) == root_local[s];
      const size_t base = (size_t)m * HH;
#pragma unroll
      for (int j = 0; j < 4; ++j)
        Cf[base + nj[j]] = acc[i][j][r] + c0a[j] + lp * vla[j] + (isr ? re1[j] : re0[j]);
    }
}

// ---------------------------------------------------------------------------
// Final BN apply with residual; coef computed inline from stats.
// ---------------------------------------------------------------------------
__launch_bounds__(256)
__global__ void bn_apply_k(const float* __restrict__ u, float* __restrict__ h,
                           const float* __restrict__ stats,
                           const float* __restrict__ gamma, const float* __restrict__ beta) {
  size_t i4 = (size_t)(blockIdx.x * 256 + threadIdx.x) * 4;
  int c = (int)(i4 & 127);
  const float invM = 1.0f / (float)SKK;
  float sc[4], sh[4];
#pragma unroll
  for (int e = 0; e < 4; ++e) {
    const float mu = stats[c + e] * invM;
    const float var = fmaf(-mu, mu, stats[HH + c + e] * invM);
    const float s = rsqrtf(var + 1e-5f) * gamma[c + e];
    sc[e] = s; sh[e] = fmaf(-mu, s, beta[c + e]);
  }
  float4 uv = *(const float4*)(u + i4);
  float4 hv = *(const float4*)(h + i4);
  float4 o;
  o.x = fmaf(uv.x, sc[0], sh[0]) + hv.x;
  o.y = fmaf(uv.y, sc[1], sh[1]) + hv.y;
  o.z = fmaf(uv.z, sc[2], sh[2]) + hv.z;
  o.w = fmaf(uv.w, sc[3], sh[3]) + hv.w;
  *(float4*)(h + i4) = o;
}

// ---------------------------------------------------------------------------
extern "C" void kernel_launch(void* const* d_in, const int* in_sizes, int n_in,
                              void* d_out, int out_size, void* d_ws, size_t ws_size,
                              hipStream_t stream) {
  const float* x          = (const float*)d_in[0];
  const float* log_probs  = (const float*)d_in[1];
  const float* node_w     = (const float*)d_in[2];
  const float* node_b     = (const float*)d_in[3];
  const float* logp_w     = (const float*)d_in[4];
  const float* logp_b     = (const float*)d_in[5];
  const float* root_emb   = (const float*)d_in[6];
  const float* init_w     = (const float*)d_in[7];
  const float* init_b     = (const float*)d_in[8];
  const float* gin_eps    = (const float*)d_in[9];
  const float* w1         = (const float*)d_in[10];
  const float* b1         = (const float*)d_in[11];
  const float* w2         = (const float*)d_in[12];
  const float* b2         = (const float*)d_in[13];
  const float* mp2w       = (const float*)d_in[14];
  const float* mp2b       = (const float*)d_in[15];
  const float* gamma      = (const float*)d_in[16];
  const float* beta       = (const float*)d_in[17];
  const int*   nodes      = (const int*)d_in[18];
  const int*   root_local = (const int*)d_in[19];
  const int*   edge_idx   = (const int*)d_in[20];
  const int*   edge_ptr   = (const int*)d_in[21];
  float* h = (float*)d_out;   // fp32 residual stream lives in d_out

  // ---- workspace carve ----
  char* wp = (char*)d_ws;
  auto take = [&](size_t bytes) { char* p = wp; wp += (bytes + 255) & ~(size_t)255; return p; };
  ushort* zh    = (ushort*)take((size_t)SKK * HH * 2);   // 32 MB
  ushort* zl    = (ushort*)take((size_t)SKK * HH * 2);
  float*  uf    = (float*)take((size_t)SKK * HH * 4);    // 64 MB
  float*  xa_acc = (float*)take((size_t)NN * HH * 4);    // 25.6 MB fp32 atomic sums
  ushort* Mth   = (ushort*)take((size_t)HH * HH * 2);
  ushort* Mtl   = (ushort*)take((size_t)HH * HH * 2);
  ushort* w1th  = (ushort*)take((size_t)LLAY * HH * HH * 2);
  ushort* w1tl  = (ushort*)take((size_t)LLAY * HH * HH * 2);
  ushort* w2th  = (ushort*)take((size_t)LLAY * HH * HH * 2);
  ushort* w2tl  = (ushort*)take((size_t)LLAY * HH * HH * 2);
  ushort* mp2th = (ushort*)take((size_t)LLAY * HH * 256 * 2);
  ushort* mp2tl = (ushort*)take((size_t)LLAY * HH * 256 * 2);
  float* vl       = (float*)take(HH * 4);
  float* c0v      = (float*)take(HH * 4);
  float* rev      = (float*)take(2 * HH * 4);
  float* bn_stats = (float*)take(LLAY * 2 * HH * 4);
  int*   cnti     = (int*)take((size_t)NN * 4);
  int*   row_ptr  = (int*)take((size_t)(SKK + 1) * 4);
  int*   ssrc     = (int*)take((size_t)EE * 4);

  // ---- prologue ----
  hipMemsetAsync(cnti, 0, (size_t)NN * 4, stream);
  hipMemsetAsync(bn_stats, 0, LLAY * 2 * HH * 4, stream);
  fold_M_k<<<HH, HH, 0, stream>>>(node_w, init_w, Mth, Mtl);
  fold_vec_k<<<1, HH, 0, stream>>>(init_w, logp_w, node_b, logp_b, init_b, root_emb,
                                   vl, c0v, rev);
  wconv_k<<<2560, HH, 0, stream>>>(w1, w2, mp2w, w1th, w1tl, w2th, w2tl, mp2th, mp2tl);
  count_k<<<SKK / 256, 256, 0, stream>>>(nodes, cnti);
  presort_k<<<SS, 256, 0, stream>>>(edge_idx, edge_idx + EE, edge_ptr, row_ptr, ssrc);

  // initial h (fp32, in d_out)
  mgemm0_k<<<SKK / 128, 256, 0, stream>>>(x, Mth, Mtl, h,
                                          nodes, log_probs, root_local, vl, c0v, rev);

  for (int l = 0; l < LLAY; ++l) {
    hipMemsetAsync(xa_acc, 0, (size_t)NN * HH * 4, stream);
    if (l == 0) {
      gin_mega_k<true><<<SS, 256, 0, stream>>>(h, nullptr, nullptr, nullptr, nullptr,
                                               row_ptr, ssrc, gin_eps, l,
                                               w1th + (size_t)l * HH * HH,
                                               w1tl + (size_t)l * HH * HH,
                                               w2th + (size_t)l * HH * HH,
                                               w2tl + (size_t)l * HH * HH,
                                               b1 + l * HH, b2 + l * HH, zh, zl,
                                               nodes, xa_acc);
    } else {
      gin_mega_k<false><<<SS, 256, 0, stream>>>(h, uf, bn_stats + (l - 1) * 2 * HH,
                                                gamma + (l - 1) * HH, beta + (l - 1) * HH,
                                                row_ptr, ssrc, gin_eps, l,
                                                w1th + (size_t)l * HH * HH,
                                                w1tl + (size_t)l * HH * HH,
                                                w2th + (size_t)l * HH * HH,
                                                w2tl + (size_t)l * HH * HH,
                                                b1 + l * HH, b2 + l * HH, zh, zl,
                                                nodes, xa_acc);
    }
    mp2_k<<<SKK / 128, 256, 0, stream>>>(zh, zl, xa_acc,
                                         mp2th + (size_t)l * HH * 256,
                                         mp2tl + (size_t)l * HH * 256,
                                         mp2b + l * HH, uf, nodes, cnti,
                                         bn_stats + l * 2 * HH);
  }
  // final BN+residual apply (layer 4) -> h in d_out
  bn_apply_k<<<(SKK * HH / 4) / 256, 256, 0, stream>>>(uf, h, bn_stats + 4 * 2 * HH,
                                                       gamma + 4 * HH, beta + 4 * HH);
}

// Round 9
// 992.255 us; speedup vs baseline: 1.0760x; 1.0760x over previous
//
#include <hip/hip_runtime.h>
#include <cstdint>

#define NN   50000
#define SS   2048
#define KSUB 64
#define HH   128
#define EE   (SS * 256)
#define SKK  (SS * KSUB)    // 131072
#define LLAY 5
#define NBLK 196            // ceil(NN/256)

typedef __attribute__((ext_vector_type(8))) short bhalf8;
typedef __attribute__((ext_vector_type(4))) float f32x4;

__device__ __forceinline__ ushort f2b(float f) {
  uint u = __builtin_bit_cast(uint, f);
  uint r = (u + 0x7FFFu + ((u >> 16) & 1u)) >> 16;
  return (ushort)r;
}
__device__ __forceinline__ float b2f(ushort u) {
  uint v = ((uint)u) << 16;
  return __builtin_bit_cast(float, v);
}
// split fp32 -> (hi, lo) bf16 pair; hi + lo ~= f with ~2^-18 residual
__device__ __forceinline__ void fsplit(float f, ushort& hi, ushort& lo) {
  hi = f2b(f);
  lo = f2b(f - b2f(hi));
}
// byte offset into a [64][128]-short LDS tile, T2 XOR swizzle (row stride 256B)
__device__ __forceinline__ int zoff(int row, int col) {
  return row * 256 + (((col * 2) & 255) ^ ((row & 7) << 4));
}

// ---------------------------------------------------------------------------
// Fold node_proj through init_proj; emit split bf16 B^T layout [n][c]
// ---------------------------------------------------------------------------
__global__ void fold_M_k(const float* __restrict__ Wn, const float* __restrict__ Wi,
                         ushort* __restrict__ Mth, ushort* __restrict__ Mtl) {
  int c = blockIdx.x, n = threadIdx.x;
  float s = 0.f;
  for (int k = 0; k < HH; ++k) s = fmaf(Wn[c * HH + k], Wi[k * HH + n], s);
  ushort hi, lo; fsplit(s, hi, lo);
  Mth[n * HH + c] = hi; Mtl[n * HH + c] = lo;
}

__global__ void fold_vec_k(const float* __restrict__ Wi, const float* __restrict__ wl,
                           const float* __restrict__ bnb, const float* __restrict__ blb,
                           const float* __restrict__ bi, const float* __restrict__ remb,
                           float* __restrict__ vl, float* __restrict__ c0,
                           float* __restrict__ rev) {
  int n = threadIdx.x;
  float svl = 0.f, sc0 = bi[n], r0 = 0.f, r1 = 0.f;
  for (int k = 0; k < HH; ++k) {
    svl = fmaf(wl[k], Wi[(HH + k) * HH + n], svl);
    sc0 = fmaf(bnb[k], Wi[k * HH + n], sc0);
    sc0 = fmaf(blb[k], Wi[(HH + k) * HH + n], sc0);
    r0  = fmaf(remb[k],      Wi[(2 * HH + k) * HH + n], r0);
    r1  = fmaf(remb[HH + k], Wi[(2 * HH + k) * HH + n], r1);
  }
  vl[n] = svl; c0[n] = sc0; rev[n] = r0; rev[HH + n] = r1;
}

// ---------------------------------------------------------------------------
// Transpose+convert all layer weights to split bf16 B^T layout (one launch).
// ---------------------------------------------------------------------------
__global__ void wconv_k(const float* __restrict__ w1, const float* __restrict__ w2,
                        const float* __restrict__ mp2w,
                        ushort* __restrict__ w1th, ushort* __restrict__ w1tl,
                        ushort* __restrict__ w2th, ushort* __restrict__ w2tl,
                        ushort* __restrict__ mp2th, ushort* __restrict__ mp2tl) {
  int b = blockIdx.x, n = threadIdx.x;
  ushort hi, lo;
  if (b < 640) {
    int l = b >> 7, k = b & 127;
    fsplit(w1[((size_t)l * HH + k) * HH + n], hi, lo);
    w1th[((size_t)l * HH + n) * HH + k] = hi;
    w1tl[((size_t)l * HH + n) * HH + k] = lo;
  } else if (b < 1280) {
    int bb = b - 640; int l = bb >> 7, k = bb & 127;
    fsplit(w2[((size_t)l * HH + k) * HH + n], hi, lo);
    w2th[((size_t)l * HH + n) * HH + k] = hi;
    w2tl[((size_t)l * HH + n) * HH + k] = lo;
  } else {
    int bb = b - 1280; int l = bb >> 8, k = bb & 255;
    fsplit(mp2w[((size_t)l * 256 + k) * HH + n], hi, lo);
    mp2th[((size_t)l * HH + n) * 256 + k] = hi;
    mp2tl[((size_t)l * HH + n) * 256 + k] = lo;
  }
}

// ---------------------------------------------------------------------------
// Node-CSR construction: count -> exclusive scan -> fill
// ---------------------------------------------------------------------------
__global__ void count_k(const int* __restrict__ idc, int* __restrict__ cnt) {
  int i = blockIdx.x * 256 + threadIdx.x;
  if (i < SKK) atomicAdd(&cnt[idc[i]], 1);
}

__global__ void scan1_k(const int* __restrict__ cnt, int* __restrict__ excl,
                        int* __restrict__ bsum) {
  __shared__ int sh[256];
  const int tid = threadIdx.x;
  const int i = blockIdx.x * 256 + tid;
  int v = (i < NN) ? cnt[i] : 0;
  sh[tid] = v;
  __syncthreads();
#pragma unroll
  for (int off = 1; off < 256; off <<= 1) {
    int t = (tid >= off) ? sh[tid - off] : 0;
    __syncthreads();
    sh[tid] += t;
    __syncthreads();
  }
  excl[i] = sh[tid] - v;
  if (tid == 255) bsum[blockIdx.x] = sh[tid];
}

__global__ void scan2_k(int* __restrict__ bsum, int* __restrict__ boff) {
  __shared__ int sh[256];
  const int tid = threadIdx.x;
  int v = (tid < NBLK) ? bsum[tid] : 0;
  sh[tid] = v;
  __syncthreads();
#pragma unroll
  for (int off = 1; off < 256; off <<= 1) {
    int t = (tid >= off) ? sh[tid - off] : 0;
    __syncthreads();
    sh[tid] += t;
    __syncthreads();
  }
  boff[tid] = sh[tid] - v;
}

__global__ void scan3_k(const int* __restrict__ excl, const int* __restrict__ boff,
                        int* __restrict__ node_ptr) {
  int i = blockIdx.x * 256 + threadIdx.x;
  if (i < NN) node_ptr[i] = excl[i] + boff[blockIdx.x];
  if (i == 0) node_ptr[NN] = SKK;
}

__global__ void fill_rows_k(const int* __restrict__ idc, const int* __restrict__ node_ptr,
                            int* __restrict__ cur, int* __restrict__ rowlist) {
  int i = blockIdx.x * 256 + threadIdx.x;
  if (i < SKK) {
    int id = idc[i];
    int pos = atomicAdd(&cur[id], 1);
    rowlist[node_ptr[id] + pos] = i;
  }
}

// ---------------------------------------------------------------------------
// Cross-subgraph scatter-mean as a GATHER. Vectorized: 32 lanes/node,
// 8B uint2 loads per lane, 8 nodes/block.
// ---------------------------------------------------------------------------
__launch_bounds__(256)
__global__ void scatter_mean_k(const ushort* __restrict__ zh, const ushort* __restrict__ zl,
                               const int* __restrict__ node_ptr,
                               const int* __restrict__ rowlist,
                               ushort* __restrict__ xah, ushort* __restrict__ xal) {
  const int tid = threadIdx.x;
  const int n = blockIdx.x * 8 + (tid >> 5);
  if (n >= NN) return;
  const int c4 = (tid & 31) * 4;
  const int p0 = node_ptr[n], p1 = node_ptr[n + 1];
  float s0 = 0.f, s1 = 0.f, s2 = 0.f, s3 = 0.f;
  for (int p = p0; p < p1; ++p) {
    const size_t off = (size_t)rowlist[p] * HH + c4;
    uint2 vh = *(const uint2*)(zh + off);
    uint2 vl = *(const uint2*)(zl + off);
    s0 += b2f((ushort)vh.x) + b2f((ushort)vl.x);
    s1 += b2f((ushort)(vh.x >> 16)) + b2f((ushort)(vl.x >> 16));
    s2 += b2f((ushort)vh.y) + b2f((ushort)vl.y);
    s3 += b2f((ushort)(vh.y >> 16)) + b2f((ushort)(vl.y >> 16));
  }
  const float inv = 1.0f / (float)max(p1 - p0, 1);
  ushort h0, l0, h1, l1, h2, l2, h3, l3;
  fsplit(s0 * inv, h0, l0); fsplit(s1 * inv, h1, l1);
  fsplit(s2 * inv, h2, l2); fsplit(s3 * inv, h3, l3);
  uint2 oh, ol;
  oh.x = (uint)h0 | ((uint)h1 << 16); oh.y = (uint)h2 | ((uint)h3 << 16);
  ol.x = (uint)l0 | ((uint)l1 << 16); ol.y = (uint)l2 | ((uint)l3 << 16);
  *(uint2*)(xah + (size_t)n * HH + c4) = oh;
  *(uint2*)(xal + (size_t)n * HH + c4) = ol;
}

// ---------------------------------------------------------------------------
// Per-subgraph counting sort of edges by dst -> CSR
// ---------------------------------------------------------------------------
__launch_bounds__(256)
__global__ void presort_k(const int* __restrict__ e_src, const int* __restrict__ e_dst,
                          const int* __restrict__ edge_ptr, int* __restrict__ row_ptr,
                          int* __restrict__ ssrc) {
  __shared__ int cnt[KSUB];
  __shared__ int base[KSUB];
  __shared__ int cur[KSUB];
  const int s = blockIdx.x, tid = threadIdx.x;
  const int p0 = edge_ptr[s], p1 = edge_ptr[s + 1];
  if (tid < KSUB) cnt[tid] = 0;
  __syncthreads();
  for (int e = p0 + tid; e < p1; e += 256) atomicAdd(&cnt[e_dst[e]], 1);
  __syncthreads();
  if (tid == 0) {
    int a = 0;
    for (int d = 0; d < KSUB; ++d) { base[d] = a; a += cnt[d]; }
  }
  __syncthreads();
  if (tid < KSUB) { row_ptr[s * KSUB + tid] = p0 + base[tid]; cur[tid] = base[tid]; }
  if (s == 0 && tid == 0) row_ptr[SS * KSUB] = edge_ptr[SS];
  __syncthreads();
  for (int e = p0 + tid; e < p1; e += 256) {
    int d = e_dst[e];
    int pos = atomicAdd(&cur[d], 1);
    ssrc[p0 + pos] = e_src[e];
  }
}

// ---------------------------------------------------------------------------
// MEGA kernel: per subgraph (64 rows):
//   phase A: h_new = bn(uf) + h_old (residual) [skip BN if FIRST];
//            BN coef computed INLINE from stats; write h_new, keep fp32 in LDS
//   phase B: GIN aggregation (interleaved channel mapping)
//   phase C: split z_agg -> swizzled bf16 LDS tile Z (aliases hl)
//   MLP1:    t = relu(Z @ W1 + b1) -> swizzled LDS tile T (aliases Z)
//   MLP2:    z = T @ W2 + b2 -> staged into dead Z/T LDS tiles (swizzled),
//            then COALESCED copy-out (4x dwordx4/thread/buffer, 1KB/wave-inst)
//            — fixes the 2x HBM write amplification of scalar 2B stores.
// ---------------------------------------------------------------------------
template <bool FIRST>
__launch_bounds__(256, 4)
__global__ void gin_mega_k(float* __restrict__ h, const float* __restrict__ uf,
                           const float* __restrict__ stats,
                           const float* __restrict__ gamma, const float* __restrict__ beta,
                           const int* __restrict__ row_ptr, const int* __restrict__ ssrc,
                           const float* __restrict__ gin_eps, const int layer,
                           const ushort* __restrict__ B1h, const ushort* __restrict__ B1l,
                           const ushort* __restrict__ B2h, const ushort* __restrict__ B2l,
                           const float* __restrict__ bias1, const float* __restrict__ bias2,
                           ushort* __restrict__ zh, ushort* __restrict__ zl) {
  constexpr int LDH = 132;
  __shared__ __align__(16) char smem[KSUB * LDH * 4];   // 33792 B, phase-aliased
  float*  hl = (float*)smem;                 // [64][132] fp32 (phases A,B)
  ushort* Zh = (ushort*)smem;                // [64][128] swizzled (phases C..out)
  ushort* Zl = (ushort*)(smem + KSUB * HH * 2);
  const int s = blockIdx.x, tid = threadIdx.x;
  const size_t base = (size_t)s * KSUB * HH;

  // ---- phase A (BN coef inline; c constant across 'it' since 1024 % 128 == 0) ----
  float csc[4], csh[4];
  const int cb = (tid * 4) & 127;
  if constexpr (!FIRST) {
    const float invM = 1.0f / (float)SKK;
#pragma unroll
    for (int e = 0; e < 4; ++e) {
      const float mu = stats[cb + e] * invM;
      const float var = fmaf(-mu, mu, stats[HH + cb + e] * invM);
      const float sc = rsqrtf(var + 1e-5f) * gamma[cb + e];
      csc[e] = sc; csh[e] = fmaf(-mu, sc, beta[cb + e]);
    }
  }
#pragma unroll
  for (int it = 0; it < 8; ++it) {
    const int idx = it * 1024 + tid * 4;
    const int m = idx >> 7, c = idx & 127;
    float4 hv = *(const float4*)&h[base + idx];
    if constexpr (!FIRST) {
      float4 u4 = *(const float4*)&uf[base + idx];
      hv.x += fmaf(u4.x, csc[0], csh[0]);
      hv.y += fmaf(u4.y, csc[1], csh[1]);
      hv.z += fmaf(u4.z, csc[2], csh[2]);
      hv.w += fmaf(u4.w, csc[3], csh[3]);
      *(float4*)&h[base + idx] = hv;
    }
    *(float4*)&hl[m * LDH + c] = hv;
  }
  __syncthreads();

  // ---- phase B: aggregation (interleaved channel mapping) ----
  const float ep1 = 1.0f + gin_eps[layer];
  const int d = tid >> 2, q4 = (tid & 3) * 4;   // cols q4 + 16*j + k
  const int g = s * KSUB + d;
  const int e0 = row_ptr[g], e1 = row_ptr[g + 1];
  float a[32];
  {
    const float* hp0 = &hl[d * LDH + q4];
#pragma unroll
    for (int j = 0; j < 8; ++j) {
      float4 v = *(const float4*)(hp0 + 16 * j);
      a[4 * j + 0] = ep1 * v.x; a[4 * j + 1] = ep1 * v.y;
      a[4 * j + 2] = ep1 * v.z; a[4 * j + 3] = ep1 * v.w;
    }
    for (int e = e0; e < e1; ++e) {
      const float* hp = &hl[ssrc[e] * LDH + q4];
#pragma unroll
      for (int j = 0; j < 8; ++j) {
        float4 v = *(const float4*)(hp + 16 * j);
        a[4 * j + 0] += v.x; a[4 * j + 1] += v.y;
        a[4 * j + 2] += v.z; a[4 * j + 3] += v.w;
      }
    }
  }
  __syncthreads();          // all hl reads done (Z aliases hl)

  // ---- phase C: split z_agg into swizzled LDS tile (8B writes) ----
#pragma unroll
  for (int j = 0; j < 8; ++j) {
    ushort th[4], tl[4];
#pragma unroll
    for (int k = 0; k < 4; ++k) fsplit(a[4 * j + k], th[k], tl[k]);
    const int o = zoff(d, q4 + 16 * j);
    *(uint2*)((char*)Zh + o) = *(uint2*)th;
    *(uint2*)((char*)Zl + o) = *(uint2*)tl;
  }
  __syncthreads();

  // ---- MLP GEMMs ----
  const int lane = tid & 63, wv = tid >> 6;
  const int fr = lane & 15, quad = lane >> 4;
  const int nj0 = wv * 32 + fr, nj1 = nj0 + 16;

  f32x4 acc[4][2];
#pragma unroll
  for (int i = 0; i < 4; ++i) { acc[i][0] = (f32x4){0,0,0,0}; acc[i][1] = (f32x4){0,0,0,0}; }

  // MLP1: t = relu(Z @ W1 + b1)
#pragma unroll
  for (int ch = 0; ch < 4; ++ch) {
    bhalf8 afh[4], afl[4], bfh[2], bfl[2];
#pragma unroll
    for (int i = 0; i < 4; ++i) {
      const int o = zoff(i * 16 + fr, ch * 32 + quad * 8);
      afh[i] = *(const bhalf8*)((const char*)Zh + o);
      afl[i] = *(const bhalf8*)((const char*)Zl + o);
    }
#pragma unroll
    for (int j = 0; j < 2; ++j) {
      const size_t off = (size_t)(wv * 32 + j * 16 + fr) * HH + ch * 32 + quad * 8;
      bfh[j] = *(const bhalf8*)(B1h + off);
      bfl[j] = *(const bhalf8*)(B1l + off);
    }
#pragma unroll
    for (int i = 0; i < 4; ++i)
#pragma unroll
      for (int j = 0; j < 2; ++j) {
        acc[i][j] = __builtin_amdgcn_mfma_f32_16x16x32_bf16(afh[i], bfh[j], acc[i][j], 0, 0, 0);
        acc[i][j] = __builtin_amdgcn_mfma_f32_16x16x32_bf16(afl[i], bfh[j], acc[i][j], 0, 0, 0);
        acc[i][j] = __builtin_amdgcn_mfma_f32_16x16x32_bf16(afh[i], bfl[j], acc[i][j], 0, 0, 0);
      }
  }
  __syncthreads();          // all Z reads done (T aliases Z)

  // epilogue 1: T = relu(acc + b1), split, into swizzled LDS
  {
    const float b10 = bias1[nj0], b11 = bias1[nj1];
#pragma unroll
    for (int i = 0; i < 4; ++i)
#pragma unroll
      for (int r = 0; r < 4; ++r) {
        const int row = i * 16 + quad * 4 + r;
        const float o0 = fmaxf(acc[i][0][r] + b10, 0.f);
        const float o1 = fmaxf(acc[i][1][r] + b11, 0.f);
        ushort h0, l0, h1, l1; fsplit(o0, h0, l0); fsplit(o1, h1, l1);
        *(ushort*)((char*)Zh + zoff(row, nj0)) = h0;
        *(ushort*)((char*)Zl + zoff(row, nj0)) = l0;
        *(ushort*)((char*)Zh + zoff(row, nj1)) = h1;
        *(ushort*)((char*)Zl + zoff(row, nj1)) = l1;
      }
  }
  __syncthreads();

  // MLP2: z = T @ W2 + b2
#pragma unroll
  for (int i = 0; i < 4; ++i) { acc[i][0] = (f32x4){0,0,0,0}; acc[i][1] = (f32x4){0,0,0,0}; }
#pragma unroll
  for (int ch = 0; ch < 4; ++ch) {
    bhalf8 afh[4], afl[4], bfh[2], bfl[2];
#pragma unroll
    for (int i = 0; i < 4; ++i) {
      const int o = zoff(i * 16 + fr, ch * 32 + quad * 8);
      afh[i] = *(const bhalf8*)((const char*)Zh + o);
      afl[i] = *(const bhalf8*)((const char*)Zl + o);
    }
#pragma unroll
    for (int j = 0; j < 2; ++j) {
      const size_t off = (size_t)(wv * 32 + j * 16 + fr) * HH + ch * 32 + quad * 8;
      bfh[j] = *(const bhalf8*)(B2h + off);
      bfl[j] = *(const bhalf8*)(B2l + off);
    }
#pragma unroll
    for (int i = 0; i < 4; ++i)
#pragma unroll
      for (int j = 0; j < 2; ++j) {
        acc[i][j] = __builtin_amdgcn_mfma_f32_16x16x32_bf16(afh[i], bfh[j], acc[i][j], 0, 0, 0);
        acc[i][j] = __builtin_amdgcn_mfma_f32_16x16x32_bf16(afl[i], bfh[j], acc[i][j], 0, 0, 0);
        acc[i][j] = __builtin_amdgcn_mfma_f32_16x16x32_bf16(afh[i], bfl[j], acc[i][j], 0, 0, 0);
      }
  }
  __syncthreads();          // all T reads done — Z/T tiles now dead, reuse for z

  // epilogue 2a: split z into swizzled LDS (same pattern as epilogue 1)
  {
    const float b20 = bias2[nj0], b21 = bias2[nj1];
#pragma unroll
    for (int i = 0; i < 4; ++i)
#pragma unroll
      for (int r = 0; r < 4; ++r) {
        const int row = i * 16 + quad * 4 + r;
        const float o0 = acc[i][0][r] + b20;
        const float o1 = acc[i][1][r] + b21;
        ushort h0, l0, h1, l1; fsplit(o0, h0, l0); fsplit(o1, h1, l1);
        *(ushort*)((char*)Zh + zoff(row, nj0)) = h0;
        *(ushort*)((char*)Zl + zoff(row, nj0)) = l0;
        *(ushort*)((char*)Zh + zoff(row, nj1)) = h1;
        *(ushort*)((char*)Zl + zoff(row, nj1)) = l1;
      }
  }
  __syncthreads();

  // epilogue 2b: coalesced copy-out. Thread t, iter k: 16B at global ushort
  // index t*8 + k*2048 -> lanes contiguous (1KB per wave-instruction).
#pragma unroll
  for (int k = 0; k < 4; ++k) {
    const int gidx = tid * 8 + k * 2048;         // ushort index in [0, 8192)
    const int row = gidx >> 7;
    const int col = gidx & 127;
    const int o = zoff(row, col);
    *(uint4*)(zh + base + gidx) = *(const uint4*)((const char*)Zh + o);
    *(uint4*)(zl + base + gidx) = *(const uint4*)((const char*)Zl + o);
  }
}

// ---------------------------------------------------------------------------
// MP-2 GEMM: verified 128-row LDS-staged structure + T14 issue-early prefetch.
// ---------------------------------------------------------------------------
__launch_bounds__(256, 3)
__global__ void mp2_k(const ushort* __restrict__ Ah, const ushort* __restrict__ Al,
                      const ushort* __restrict__ A2h, const ushort* __restrict__ A2l,
                      const ushort* __restrict__ Bh, const ushort* __restrict__ Bl,
                      const float* __restrict__ bias, float* __restrict__ Cf,
                      const int* __restrict__ idc, float* __restrict__ stats) {
  constexpr int LDP = 40;   // LDS row stride in shorts
  __shared__ __align__(16) ushort Ash[128 * LDP];
  __shared__ __align__(16) ushort Asl[128 * LDP];
  __shared__ __align__(16) ushort Bsh[128 * LDP];
  __shared__ __align__(16) ushort Bsl[128 * LDP];
  const int tid = threadIdx.x;
  const int row0 = blockIdx.x * 128;
  const int lane = tid & 63, wv = tid >> 6;
  const int wm = (wv >> 1) * 64, wn = (wv & 1) * 64;
  const int fr = lane & 15, quad = lane >> 4;
  const int sr = tid >> 1;            // staging row 0..127
  const int sc = (tid & 1) * 16;      // staging short-offset {0,16}
  const int grow = idc[row0 + sr];    // gather row for K-half 2 (hoisted)

  f32x4 acc[4][4];
#pragma unroll
  for (int i = 0; i < 4; ++i)
#pragma unroll
    for (int j = 0; j < 4; ++j) acc[i][j] = (f32x4){0.f, 0.f, 0.f, 0.f};

  uint4 pa0, pa1, pa2, pa3, pb0, pb1, pb2, pb3;   // prefetch registers
  auto LA = [&](int ch) {
    const ushort *sh_, *sl_;
    if (ch >= 4) {
      const size_t off = (size_t)grow * HH + (ch - 4) * 32 + sc;
      sh_ = A2h + off; sl_ = A2l + off;
    } else {
      const size_t off = (size_t)(row0 + sr) * HH + ch * 32 + sc;
      sh_ = Ah + off; sl_ = Al + off;
    }
    pa0 = *(const uint4*)(sh_);     pa1 = *(const uint4*)(sh_ + 8);
    pa2 = *(const uint4*)(sl_);     pa3 = *(const uint4*)(sl_ + 8);
  };
  auto LB = [&](int ch) {
    const size_t off = (size_t)sr * 256 + ch * 32 + sc;
    pb0 = *(const uint4*)(Bh + off); pb1 = *(const uint4*)(Bh + off + 8);
    pb2 = *(const uint4*)(Bl + off); pb3 = *(const uint4*)(Bl + off + 8);
  };

  LA(0); LB(0);
#pragma unroll
  for (int ch = 0; ch < 8; ++ch) {
    // ---- write prefetched chunk to LDS ----
    *(uint4*)&Ash[sr * LDP + sc]     = pa0;
    *(uint4*)&Ash[sr * LDP + sc + 8] = pa1;
    *(uint4*)&Asl[sr * LDP + sc]     = pa2;
    *(uint4*)&Asl[sr * LDP + sc + 8] = pa3;
    *(uint4*)&Bsh[sr * LDP + sc]     = pb0;
    *(uint4*)&Bsh[sr * LDP + sc + 8] = pb1;
    *(uint4*)&Bsl[sr * LDP + sc]     = pb2;
    *(uint4*)&Bsl[sr * LDP + sc + 8] = pb3;
    __syncthreads();
    // ---- issue next chunk's global loads (fly during MFMA) ----
    if (ch < 7) { LA(ch + 1); LB(ch + 1); }
    // ---- one K=32 MFMA step, bf16x3 ----
    bhalf8 afh[4], afl[4], bfh[4], bfl[4];
#pragma unroll
    for (int i = 0; i < 4; ++i) {
      const int r = (wm + i * 16 + fr) * LDP + quad * 8;
      afh[i] = *(const bhalf8*)&Ash[r];
      afl[i] = *(const bhalf8*)&Asl[r];
    }
#pragma unroll
    for (int j = 0; j < 4; ++j) {
      const int r = (wn + j * 16 + fr) * LDP + quad * 8;
      bfh[j] = *(const bhalf8*)&Bsh[r];
      bfl[j] = *(const bhalf8*)&Bsl[r];
    }
#pragma unroll
    for (int i = 0; i < 4; ++i)
#pragma unroll
      for (int j = 0; j < 4; ++j) {
        acc[i][j] = __builtin_amdgcn_mfma_f32_16x16x32_bf16(afh[i], bfh[j], acc[i][j], 0, 0, 0);
        acc[i][j] = __builtin_amdgcn_mfma_f32_16x16x32_bf16(afl[i], bfh[j], acc[i][j], 0, 0, 0);
        acc[i][j] = __builtin_amdgcn_mfma_f32_16x16x32_bf16(afh[i], bfl[j], acc[i][j], 0, 0, 0);
      }
    __syncthreads();
  }

  // ---- epilogue: relu + bias, uf write, BN stats ----
  const int nj[4] = {wn + fr, wn + 16 + fr, wn + 32 + fr, wn + 48 + fr};
  float bb[4];
#pragma unroll
  for (int j = 0; j < 4; ++j) bb[j] = bias[nj[j]];
  float psum[4] = {0.f, 0.f, 0.f, 0.f}, psq[4] = {0.f, 0.f, 0.f, 0.f};
#pragma unroll
  for (int i = 0; i < 4; ++i)
#pragma unroll
    for (int r = 0; r < 4; ++r) {
      const int m = row0 + wm + i * 16 + quad * 4 + r;
      const size_t base = (size_t)m * HH;
#pragma unroll
      for (int j = 0; j < 4; ++j) {
        float o = fmaxf(acc[i][j][r] + bb[j], 0.f);
        Cf[base + nj[j]] = o;
        psum[j] += o; psq[j] += o * o;
      }
    }
  float* ssum = (float*)Ash;      // dead past last barrier
  float* ssq = ssum + HH;
  if (tid < HH) { ssum[tid] = 0.f; ssq[tid] = 0.f; }
  __syncthreads();
#pragma unroll
  for (int j = 0; j < 4; ++j) {
    atomicAdd(&ssum[nj[j]], psum[j]);
    atomicAdd(&ssq[nj[j]], psq[j]);
  }
  __syncthreads();
  if (tid < HH) {
    unsafeAtomicAdd(&stats[tid], ssum[tid]);
    unsafeAtomicAdd(&stats[HH + tid], ssq[tid]);
  }
}

// ---------------------------------------------------------------------------
// Split-bf16 MFMA GEMM (round-0 verified LDS-staged version) — MODE 0 only.
// ---------------------------------------------------------------------------
__launch_bounds__(256, 2)
__global__ void mgemm0_k(const float* __restrict__ Afp,
                         const ushort* __restrict__ Bh, const ushort* __restrict__ Bl,
                         float* __restrict__ Cf,
                         const int* __restrict__ idc, const float* __restrict__ log_probs,
                         const int* __restrict__ root_local, const float* __restrict__ vl,
                         const float* __restrict__ c0v, const float* __restrict__ rev) {
  constexpr int LDP = 40;
  __shared__ __align__(16) ushort Ash[128 * LDP];
  __shared__ __align__(16) ushort Asl[128 * LDP];
  __shared__ __align__(16) ushort Bsh[128 * LDP];
  __shared__ __align__(16) ushort Bsl[128 * LDP];
  const int tid = threadIdx.x;
  const int row0 = blockIdx.x * 128;
  const int lane = tid & 63, wv = tid >> 6;
  const int wm = (wv >> 1) * 64, wn = (wv & 1) * 64;
  const int fr = lane & 15, quad = lane >> 4;
  const int sr = tid >> 1;
  const int sc = (tid & 1) * 16;

  f32x4 acc[4][4];
#pragma unroll
  for (int i = 0; i < 4; ++i)
#pragma unroll
    for (int j = 0; j < 4; ++j) acc[i][j] = (f32x4){0.f, 0.f, 0.f, 0.f};

  for (int ch = 0; ch < 4; ++ch) {
    {
      const float* src = Afp + (size_t)idc[row0 + sr] * HH + ch * 32 + sc;
      float fv[16];
      *(float4*)&fv[0]  = *(const float4*)(src);
      *(float4*)&fv[4]  = *(const float4*)(src + 4);
      *(float4*)&fv[8]  = *(const float4*)(src + 8);
      *(float4*)&fv[12] = *(const float4*)(src + 12);
      ushort hi[16], lo[16];
#pragma unroll
      for (int e = 0; e < 16; ++e) fsplit(fv[e], hi[e], lo[e]);
      *(uint4*)&Ash[sr * LDP + sc]     = *(uint4*)&hi[0];
      *(uint4*)&Ash[sr * LDP + sc + 8] = *(uint4*)&hi[8];
      *(uint4*)&Asl[sr * LDP + sc]     = *(uint4*)&lo[0];
      *(uint4*)&Asl[sr * LDP + sc + 8] = *(uint4*)&lo[8];
    }
    {
      const size_t off = (size_t)sr * HH + ch * 32 + sc;
      *(uint4*)&Bsh[sr * LDP + sc]     = *(const uint4*)(Bh + off);
      *(uint4*)&Bsh[sr * LDP + sc + 8] = *(const uint4*)(Bh + off + 8);
      *(uint4*)&Bsl[sr * LDP + sc]     = *(const uint4*)(Bl + off);
      *(uint4*)&Bsl[sr * LDP + sc + 8] = *(const uint4*)(Bl + off + 8);
    }
    __syncthreads();
    bhalf8 afh[4], afl[4], bfh[4], bfl[4];
#pragma unroll
    for (int i = 0; i < 4; ++i) {
      const int r = (wm + i * 16 + fr) * LDP + quad * 8;
      afh[i] = *(const bhalf8*)&Ash[r];
      afl[i] = *(const bhalf8*)&Asl[r];
    }
#pragma unroll
    for (int j = 0; j < 4; ++j) {
      const int r = (wn + j * 16 + fr) * LDP + quad * 8;
      bfh[j] = *(const bhalf8*)&Bsh[r];
      bfl[j] = *(const bhalf8*)&Bsl[r];
    }
#pragma unroll
    for (int i = 0; i < 4; ++i)
#pragma unroll
      for (int j = 0; j < 4; ++j) {
        acc[i][j] = __builtin_amdgcn_mfma_f32_16x16x32_bf16(afh[i], bfh[j], acc[i][j], 0, 0, 0);
        acc[i][j] = __builtin_amdgcn_mfma_f32_16x16x32_bf16(afl[i], bfh[j], acc[i][j], 0, 0, 0);
        acc[i][j] = __builtin_amdgcn_mfma_f32_16x16x32_bf16(afh[i], bfl[j], acc[i][j], 0, 0, 0);
      }
    __syncthreads();
  }

  const int nj[4] = {wn + fr, wn + 16 + fr, wn + 32 + fr, wn + 48 + fr};
  float c0a[4], vla[4], re0[4], re1[4];
#pragma unroll
  for (int j = 0; j < 4; ++j) {
    c0a[j] = c0v[nj[j]]; vla[j] = vl[nj[j]];
    re0[j] = rev[nj[j]]; re1[j] = rev[HH + nj[j]];
  }
#pragma unroll
  for (int i = 0; i < 4; ++i)
#pragma unroll
    for (int r = 0; r < 4; ++r) {
      const int m = row0 + wm + i * 16 + quad * 4 + r;
      const int s = m >> 6;
      const float lp = log_probs[s];
      const bool isr = (m & 63) == root_local[s];
      const size_t base = (size_t)m * HH;
#pragma unroll
      for (int j = 0; j < 4; ++j)
        Cf[base + nj[j]] = acc[i][j][r] + c0a[j] + lp * vla[j] + (isr ? re1[j] : re0[j]);
    }
}

// ---------------------------------------------------------------------------
// Final BN apply with residual; coef computed inline from stats.
// ---------------------------------------------------------------------------
__launch_bounds__(256)
__global__ void bn_apply_k(const float* __restrict__ u, float* __restrict__ h,
                           const float* __restrict__ stats,
                           const float* __restrict__ gamma, const float* __restrict__ beta) {
  size_t i4 = (size_t)(blockIdx.x * 256 + threadIdx.x) * 4;
  int c = (int)(i4 & 127);
  const float invM = 1.0f / (float)SKK;
  float sc[4], sh[4];
#pragma unroll
  for (int e = 0; e < 4; ++e) {
    const float mu = stats[c + e] * invM;
    const float var = fmaf(-mu, mu, stats[HH + c + e] * invM);
    const float s = rsqrtf(var + 1e-5f) * gamma[c + e];
    sc[e] = s; sh[e] = fmaf(-mu, s, beta[c + e]);
  }
  float4 uv = *(const float4*)(u + i4);
  float4 hv = *(const float4*)(h + i4);
  float4 o;
  o.x = fmaf(uv.x, sc[0], sh[0]) + hv.x;
  o.y = fmaf(uv.y, sc[1], sh[1]) + hv.y;
  o.z = fmaf(uv.z, sc[2], sh[2]) + hv.z;
  o.w = fmaf(uv.w, sc[3], sh[3]) + hv.w;
  *(float4*)(h + i4) = o;
}

// ---------------------------------------------------------------------------
extern "C" void kernel_launch(void* const* d_in, const int* in_sizes, int n_in,
                              void* d_out, int out_size, void* d_ws, size_t ws_size,
                              hipStream_t stream) {
  const float* x          = (const float*)d_in[0];
  const float* log_probs  = (const float*)d_in[1];
  const float* node_w     = (const float*)d_in[2];
  const float* node_b     = (const float*)d_in[3];
  const float* logp_w     = (const float*)d_in[4];
  const float* logp_b     = (const float*)d_in[5];
  const float* root_emb   = (const float*)d_in[6];
  const float* init_w     = (const float*)d_in[7];
  const float* init_b     = (const float*)d_in[8];
  const float* gin_eps    = (const float*)d_in[9];
  const float* w1         = (const float*)d_in[10];
  const float* b1         = (const float*)d_in[11];
  const float* w2         = (const float*)d_in[12];
  const float* b2         = (const float*)d_in[13];
  const float* mp2w       = (const float*)d_in[14];
  const float* mp2b       = (const float*)d_in[15];
  const float* gamma      = (const float*)d_in[16];
  const float* beta       = (const float*)d_in[17];
  const int*   nodes      = (const int*)d_in[18];
  const int*   root_local = (const int*)d_in[19];
  const int*   edge_idx   = (const int*)d_in[20];
  const int*   edge_ptr   = (const int*)d_in[21];
  float* h = (float*)d_out;   // fp32 residual stream lives in d_out

  // ---- workspace carve ----
  char* wp = (char*)d_ws;
  auto take = [&](size_t bytes) { char* p = wp; wp += (bytes + 255) & ~(size_t)255; return p; };
  ushort* zh    = (ushort*)take((size_t)SKK * HH * 2);   // 32 MB
  ushort* zl    = (ushort*)take((size_t)SKK * HH * 2);
  float*  uf    = (float*)take((size_t)SKK * HH * 4);    // 64 MB
  ushort* xah   = (ushort*)take((size_t)NN * HH * 2);
  ushort* xal   = (ushort*)take((size_t)NN * HH * 2);
  ushort* Mth   = (ushort*)take((size_t)HH * HH * 2);
  ushort* Mtl   = (ushort*)take((size_t)HH * HH * 2);
  ushort* w1th  = (ushort*)take((size_t)LLAY * HH * HH * 2);
  ushort* w1tl  = (ushort*)take((size_t)LLAY * HH * HH * 2);
  ushort* w2th  = (ushort*)take((size_t)LLAY * HH * HH * 2);
  ushort* w2tl  = (ushort*)take((size_t)LLAY * HH * HH * 2);
  ushort* mp2th = (ushort*)take((size_t)LLAY * HH * 256 * 2);
  ushort* mp2tl = (ushort*)take((size_t)LLAY * HH * 256 * 2);
  float* vl       = (float*)take(HH * 4);
  float* c0v      = (float*)take(HH * 4);
  float* rev      = (float*)take(2 * HH * 4);
  float* bn_stats = (float*)take(LLAY * 2 * HH * 4);
  int*   cnti     = (int*)take((size_t)NN * 4);
  int*   excl     = (int*)take((size_t)NBLK * 256 * 4);
  int*   bsum     = (int*)take(256 * 4);
  int*   boff     = (int*)take(256 * 4);
  int*   node_ptr = (int*)take((size_t)(NN + 1) * 4);
  int*   cur      = (int*)take((size_t)NN * 4);
  int*   rowlist  = (int*)take((size_t)SKK * 4);
  int*   row_ptr  = (int*)take((size_t)(SKK + 1) * 4);
  int*   ssrc     = (int*)take((size_t)EE * 4);

  // ---- prologue ----
  hipMemsetAsync(cnti, 0, (size_t)NN * 4, stream);
  hipMemsetAsync(cur, 0, (size_t)NN * 4, stream);
  hipMemsetAsync(bn_stats, 0, LLAY * 2 * HH * 4, stream);
  fold_M_k<<<HH, HH, 0, stream>>>(node_w, init_w, Mth, Mtl);
  fold_vec_k<<<1, HH, 0, stream>>>(init_w, logp_w, node_b, logp_b, init_b, root_emb,
                                   vl, c0v, rev);
  wconv_k<<<2560, HH, 0, stream>>>(w1, w2, mp2w, w1th, w1tl, w2th, w2tl, mp2th, mp2tl);
  count_k<<<SKK / 256, 256, 0, stream>>>(nodes, cnti);
  scan1_k<<<NBLK, 256, 0, stream>>>(cnti, excl, bsum);
  scan2_k<<<1, 256, 0, stream>>>(bsum, boff);
  scan3_k<<<NBLK, 256, 0, stream>>>(excl, boff, node_ptr);
  fill_rows_k<<<SKK / 256, 256, 0, stream>>>(nodes, node_ptr, cur, rowlist);
  presort_k<<<SS, 256, 0, stream>>>(edge_idx, edge_idx + EE, edge_ptr, row_ptr, ssrc);

  // initial h (fp32, in d_out)
  mgemm0_k<<<SKK / 128, 256, 0, stream>>>(x, Mth, Mtl, h,
                                          nodes, log_probs, root_local, vl, c0v, rev);

  for (int l = 0; l < LLAY; ++l) {
    if (l == 0) {
      gin_mega_k<true><<<SS, 256, 0, stream>>>(h, nullptr, nullptr, nullptr, nullptr,
                                               row_ptr, ssrc, gin_eps, l,
                                               w1th + (size_t)l * HH * HH,
                                               w1tl + (size_t)l * HH * HH,
                                               w2th + (size_t)l * HH * HH,
                                               w2tl + (size_t)l * HH * HH,
                                               b1 + l * HH, b2 + l * HH, zh, zl);
    } else {
      gin_mega_k<false><<<SS, 256, 0, stream>>>(h, uf, bn_stats + (l - 1) * 2 * HH,
                                                gamma + (l - 1) * HH, beta + (l - 1) * HH,
                                                row_ptr, ssrc, gin_eps, l,
                                                w1th + (size_t)l * HH * HH,
                                                w1tl + (size_t)l * HH * HH,
                                                w2th + (size_t)l * HH * HH,
                                                w2tl + (size_t)l * HH * HH,
                                                b1 + l * HH, b2 + l * HH, zh, zl);
    }
    scatter_mean_k<<<(NN + 7) / 8, 256, 0, stream>>>(zh, zl, node_ptr, rowlist, xah, xal);
    mp2_k<<<SKK / 128, 256, 0, stream>>>(zh, zl, xah, xal,
                                         mp2th + (size_t)l * HH * 256,
                                         mp2tl + (size_t)l * HH * 256,
                                         mp2b + l * HH, uf, nodes,
                                         bn_stats + l * 2 * HH);
  }
  // final BN+residual apply (layer 4) -> h in d_out
  bn_apply_k<<<(SKK * HH / 4) / 256, 256, 0, stream>>>(uf, h, bn_stats + 4 * 2 * HH,
                                                       gamma + 4 * HH, beta + 4 * HH);
}

// Round 10
// 990.093 us; speedup vs baseline: 1.0783x; 1.0022x over previous
//
#include <hip/hip_runtime.h>
#include <cstdint>

#define NN   50000
#define SS   2048
#define KSUB 64
#define HH   128
#define EE   (SS * 256)
#define SKK  (SS * KSUB)    // 131072
#define LLAY 5
#define NBLK 196            // ceil(NN/256)

typedef __attribute__((ext_vector_type(8))) short bhalf8;
typedef __attribute__((ext_vector_type(4))) float f32x4;

__device__ __forceinline__ ushort f2b(float f) {
  uint u = __builtin_bit_cast(uint, f);
  uint r = (u + 0x7FFFu + ((u >> 16) & 1u)) >> 16;
  return (ushort)r;
}
__device__ __forceinline__ float b2f(ushort u) {
  uint v = ((uint)u) << 16;
  return __builtin_bit_cast(float, v);
}
// split fp32 -> (hi, lo) bf16 pair; hi + lo ~= f with ~2^-18 residual
__device__ __forceinline__ void fsplit(float f, ushort& hi, ushort& lo) {
  hi = f2b(f);
  lo = f2b(f - b2f(hi));
}
// byte offset into a [64][128]-short LDS tile, T2 XOR swizzle (row stride 256B)
__device__ __forceinline__ int zoff(int row, int col) {
  return row * 256 + (((col * 2) & 255) ^ ((row & 7) << 4));
}

// ---------------------------------------------------------------------------
// Fold node_proj through init_proj; emit split bf16 B^T layout [n][c]
// ---------------------------------------------------------------------------
__global__ void fold_M_k(const float* __restrict__ Wn, const float* __restrict__ Wi,
                         ushort* __restrict__ Mth, ushort* __restrict__ Mtl) {
  int c = blockIdx.x, n = threadIdx.x;
  float s = 0.f;
  for (int k = 0; k < HH; ++k) s = fmaf(Wn[c * HH + k], Wi[k * HH + n], s);
  ushort hi, lo; fsplit(s, hi, lo);
  Mth[n * HH + c] = hi; Mtl[n * HH + c] = lo;
}

__global__ void fold_vec_k(const float* __restrict__ Wi, const float* __restrict__ wl,
                           const float* __restrict__ bnb, const float* __restrict__ blb,
                           const float* __restrict__ bi, const float* __restrict__ remb,
                           float* __restrict__ vl, float* __restrict__ c0,
                           float* __restrict__ rev) {
  int n = threadIdx.x;
  float svl = 0.f, sc0 = bi[n], r0 = 0.f, r1 = 0.f;
  for (int k = 0; k < HH; ++k) {
    svl = fmaf(wl[k], Wi[(HH + k) * HH + n], svl);
    sc0 = fmaf(bnb[k], Wi[k * HH + n], sc0);
    sc0 = fmaf(blb[k], Wi[(HH + k) * HH + n], sc0);
    r0  = fmaf(remb[k],      Wi[(2 * HH + k) * HH + n], r0);
    r1  = fmaf(remb[HH + k], Wi[(2 * HH + k) * HH + n], r1);
  }
  vl[n] = svl; c0[n] = sc0; rev[n] = r0; rev[HH + n] = r1;
}

// ---------------------------------------------------------------------------
// Transpose+convert all layer weights to split bf16 B^T layout (one launch).
// ---------------------------------------------------------------------------
__global__ void wconv_k(const float* __restrict__ w1, const float* __restrict__ w2,
                        const float* __restrict__ mp2w,
                        ushort* __restrict__ w1th, ushort* __restrict__ w1tl,
                        ushort* __restrict__ w2th, ushort* __restrict__ w2tl,
                        ushort* __restrict__ mp2th, ushort* __restrict__ mp2tl) {
  int b = blockIdx.x, n = threadIdx.x;
  ushort hi, lo;
  if (b < 640) {
    int l = b >> 7, k = b & 127;
    fsplit(w1[((size_t)l * HH + k) * HH + n], hi, lo);
    w1th[((size_t)l * HH + n) * HH + k] = hi;
    w1tl[((size_t)l * HH + n) * HH + k] = lo;
  } else if (b < 1280) {
    int bb = b - 640; int l = bb >> 7, k = bb & 127;
    fsplit(w2[((size_t)l * HH + k) * HH + n], hi, lo);
    w2th[((size_t)l * HH + n) * HH + k] = hi;
    w2tl[((size_t)l * HH + n) * HH + k] = lo;
  } else {
    int bb = b - 1280; int l = bb >> 8, k = bb & 255;
    fsplit(mp2w[((size_t)l * 256 + k) * HH + n], hi, lo);
    mp2th[((size_t)l * HH + n) * 256 + k] = hi;
    mp2tl[((size_t)l * HH + n) * 256 + k] = lo;
  }
}

// ---------------------------------------------------------------------------
// Node-CSR construction: count -> exclusive scan -> fill
// ---------------------------------------------------------------------------
__global__ void count_k(const int* __restrict__ idc, int* __restrict__ cnt) {
  int i = blockIdx.x * 256 + threadIdx.x;
  if (i < SKK) atomicAdd(&cnt[idc[i]], 1);
}

__global__ void scan1_k(const int* __restrict__ cnt, int* __restrict__ excl,
                        int* __restrict__ bsum) {
  __shared__ int sh[256];
  const int tid = threadIdx.x;
  const int i = blockIdx.x * 256 + tid;
  int v = (i < NN) ? cnt[i] : 0;
  sh[tid] = v;
  __syncthreads();
#pragma unroll
  for (int off = 1; off < 256; off <<= 1) {
    int t = (tid >= off) ? sh[tid - off] : 0;
    __syncthreads();
    sh[tid] += t;
    __syncthreads();
  }
  excl[i] = sh[tid] - v;
  if (tid == 255) bsum[blockIdx.x] = sh[tid];
}

__global__ void scan2_k(int* __restrict__ bsum, int* __restrict__ boff) {
  __shared__ int sh[256];
  const int tid = threadIdx.x;
  int v = (tid < NBLK) ? bsum[tid] : 0;
  sh[tid] = v;
  __syncthreads();
#pragma unroll
  for (int off = 1; off < 256; off <<= 1) {
    int t = (tid >= off) ? sh[tid - off] : 0;
    __syncthreads();
    sh[tid] += t;
    __syncthreads();
  }
  boff[tid] = sh[tid] - v;
}

__global__ void scan3_k(const int* __restrict__ excl, const int* __restrict__ boff,
                        int* __restrict__ node_ptr) {
  int i = blockIdx.x * 256 + threadIdx.x;
  if (i < NN) node_ptr[i] = excl[i] + boff[blockIdx.x];
  if (i == 0) node_ptr[NN] = SKK;
}

__global__ void fill_rows_k(const int* __restrict__ idc, const int* __restrict__ node_ptr,
                            int* __restrict__ cur, int* __restrict__ rowlist) {
  int i = blockIdx.x * 256 + threadIdx.x;
  if (i < SKK) {
    int id = idc[i];
    int pos = atomicAdd(&cur[id], 1);
    rowlist[node_ptr[id] + pos] = i;
  }
}

// ---------------------------------------------------------------------------
// Cross-subgraph scatter-mean as a GATHER. Vectorized: 32 lanes/node,
// 8B uint2 loads per lane, 8 nodes/block.
// ---------------------------------------------------------------------------
__launch_bounds__(256)
__global__ void scatter_mean_k(const ushort* __restrict__ zh, const ushort* __restrict__ zl,
                               const int* __restrict__ node_ptr,
                               const int* __restrict__ rowlist,
                               ushort* __restrict__ xah, ushort* __restrict__ xal) {
  const int tid = threadIdx.x;
  const int n = blockIdx.x * 8 + (tid >> 5);
  if (n >= NN) return;
  const int c4 = (tid & 31) * 4;
  const int p0 = node_ptr[n], p1 = node_ptr[n + 1];
  float s0 = 0.f, s1 = 0.f, s2 = 0.f, s3 = 0.f;
  for (int p = p0; p < p1; ++p) {
    const size_t off = (size_t)rowlist[p] * HH + c4;
    uint2 vh = *(const uint2*)(zh + off);
    uint2 vl = *(const uint2*)(zl + off);
    s0 += b2f((ushort)vh.x) + b2f((ushort)vl.x);
    s1 += b2f((ushort)(vh.x >> 16)) + b2f((ushort)(vl.x >> 16));
    s2 += b2f((ushort)vh.y) + b2f((ushort)vl.y);
    s3 += b2f((ushort)(vh.y >> 16)) + b2f((ushort)(vl.y >> 16));
  }
  const float inv = 1.0f / (float)max(p1 - p0, 1);
  ushort h0, l0, h1, l1, h2, l2, h3, l3;
  fsplit(s0 * inv, h0, l0); fsplit(s1 * inv, h1, l1);
  fsplit(s2 * inv, h2, l2); fsplit(s3 * inv, h3, l3);
  uint2 oh, ol;
  oh.x = (uint)h0 | ((uint)h1 << 16); oh.y = (uint)h2 | ((uint)h3 << 16);
  ol.x = (uint)l0 | ((uint)l1 << 16); ol.y = (uint)l2 | ((uint)l3 << 16);
  *(uint2*)(xah + (size_t)n * HH + c4) = oh;
  *(uint2*)(xal + (size_t)n * HH + c4) = ol;
}

// ---------------------------------------------------------------------------
// Per-subgraph counting sort of edges by dst -> CSR
// ---------------------------------------------------------------------------
__launch_bounds__(256)
__global__ void presort_k(const int* __restrict__ e_src, const int* __restrict__ e_dst,
                          const int* __restrict__ edge_ptr, int* __restrict__ row_ptr,
                          int* __restrict__ ssrc) {
  __shared__ int cnt[KSUB];
  __shared__ int base[KSUB];
  __shared__ int cur[KSUB];
  const int s = blockIdx.x, tid = threadIdx.x;
  const int p0 = edge_ptr[s], p1 = edge_ptr[s + 1];
  if (tid < KSUB) cnt[tid] = 0;
  __syncthreads();
  for (int e = p0 + tid; e < p1; e += 256) atomicAdd(&cnt[e_dst[e]], 1);
  __syncthreads();
  if (tid == 0) {
    int a = 0;
    for (int d = 0; d < KSUB; ++d) { base[d] = a; a += cnt[d]; }
  }
  __syncthreads();
  if (tid < KSUB) { row_ptr[s * KSUB + tid] = p0 + base[tid]; cur[tid] = base[tid]; }
  if (s == 0 && tid == 0) row_ptr[SS * KSUB] = edge_ptr[SS];
  __syncthreads();
  for (int e = p0 + tid; e < p1; e += 256) {
    int d = e_dst[e];
    int pos = atomicAdd(&cur[d], 1);
    ssrc[p0 + pos] = e_src[e];
  }
}

// ---------------------------------------------------------------------------
// MEGA kernel: per subgraph (64 rows):
//   phase A: h_new = bn(uf) + h_old (residual) [skip BN if FIRST];
//            BN coef computed INLINE from stats; write h_new, keep fp32 in LDS
//            + stage this subgraph's 256 ssrc entries into LDS (1 KB)
//   phase B: GIN aggregation (interleaved channel mapping, ssrc from LDS)
//   phase C: split z_agg -> swizzled bf16 LDS tile Z (aliases hl)
//   MLP1:    t = relu(Z @ W1 + b1) -> swizzled LDS tile T (aliases Z)
//   MLP2:    z = T @ W2 + b2 -> staged into dead Z/T LDS tiles (swizzled),
//            then COALESCED copy-out (4x dwordx4/thread/buffer)
// ---------------------------------------------------------------------------
template <bool FIRST>
__launch_bounds__(256, 4)
__global__ void gin_mega_k(float* __restrict__ h, const float* __restrict__ uf,
                           const float* __restrict__ stats,
                           const float* __restrict__ gamma, const float* __restrict__ beta,
                           const int* __restrict__ row_ptr, const int* __restrict__ ssrc,
                           const float* __restrict__ gin_eps, const int layer,
                           const ushort* __restrict__ B1h, const ushort* __restrict__ B1l,
                           const ushort* __restrict__ B2h, const ushort* __restrict__ B2l,
                           const float* __restrict__ bias1, const float* __restrict__ bias2,
                           ushort* __restrict__ zh, ushort* __restrict__ zl) {
  constexpr int LDH = 132;
  __shared__ __align__(16) char smem[KSUB * LDH * 4];   // 33792 B, phase-aliased
  __shared__ int ssrc_lds[256];                          // 1 KB edge-source cache
  float*  hl = (float*)smem;                 // [64][132] fp32 (phases A,B)
  ushort* Zh = (ushort*)smem;                // [64][128] swizzled (phases C..out)
  ushort* Zl = (ushort*)(smem + KSUB * HH * 2);
  const int s = blockIdx.x, tid = threadIdx.x;
  const size_t base = (size_t)s * KSUB * HH;

  // ---- stage ssrc (coalesced, 1 iteration for ES=256) ----
  const int e_start = row_ptr[s * KSUB];
  {
    const int e_end = row_ptr[s * KSUB + KSUB];
    for (int e = e_start + tid; e < e_end; e += 256)
      ssrc_lds[e - e_start] = ssrc[e];
  }

  // ---- phase A (BN coef inline; c constant across 'it' since 1024 % 128 == 0) ----
  float csc[4], csh[4];
  const int cb = (tid * 4) & 127;
  if constexpr (!FIRST) {
    const float invM = 1.0f / (float)SKK;
#pragma unroll
    for (int e = 0; e < 4; ++e) {
      const float mu = stats[cb + e] * invM;
      const float var = fmaf(-mu, mu, stats[HH + cb + e] * invM);
      const float sc = rsqrtf(var + 1e-5f) * gamma[cb + e];
      csc[e] = sc; csh[e] = fmaf(-mu, sc, beta[cb + e]);
    }
  }
#pragma unroll
  for (int it = 0; it < 8; ++it) {
    const int idx = it * 1024 + tid * 4;
    const int m = idx >> 7, c = idx & 127;
    float4 hv = *(const float4*)&h[base + idx];
    if constexpr (!FIRST) {
      float4 u4 = *(const float4*)&uf[base + idx];
      hv.x += fmaf(u4.x, csc[0], csh[0]);
      hv.y += fmaf(u4.y, csc[1], csh[1]);
      hv.z += fmaf(u4.z, csc[2], csh[2]);
      hv.w += fmaf(u4.w, csc[3], csh[3]);
      *(float4*)&h[base + idx] = hv;
    }
    *(float4*)&hl[m * LDH + c] = hv;
  }
  __syncthreads();

  // ---- phase B: aggregation (interleaved channel mapping; ssrc from LDS) ----
  const float ep1 = 1.0f + gin_eps[layer];
  const int d = tid >> 2, q4 = (tid & 3) * 4;   // cols q4 + 16*j + k
  const int g = s * KSUB + d;
  const int e0 = row_ptr[g], e1 = row_ptr[g + 1];
  float a[32];
  {
    const float* hp0 = &hl[d * LDH + q4];
#pragma unroll
    for (int j = 0; j < 8; ++j) {
      float4 v = *(const float4*)(hp0 + 16 * j);
      a[4 * j + 0] = ep1 * v.x; a[4 * j + 1] = ep1 * v.y;
      a[4 * j + 2] = ep1 * v.z; a[4 * j + 3] = ep1 * v.w;
    }
    for (int e = e0; e < e1; ++e) {
      const float* hp = &hl[ssrc_lds[e - e_start] * LDH + q4];
#pragma unroll
      for (int j = 0; j < 8; ++j) {
        float4 v = *(const float4*)(hp + 16 * j);
        a[4 * j + 0] += v.x; a[4 * j + 1] += v.y;
        a[4 * j + 2] += v.z; a[4 * j + 3] += v.w;
      }
    }
  }
  __syncthreads();          // all hl reads done (Z aliases hl)

  // ---- phase C: split z_agg into swizzled LDS tile (8B writes) ----
#pragma unroll
  for (int j = 0; j < 8; ++j) {
    ushort th[4], tl[4];
#pragma unroll
    for (int k = 0; k < 4; ++k) fsplit(a[4 * j + k], th[k], tl[k]);
    const int o = zoff(d, q4 + 16 * j);
    *(uint2*)((char*)Zh + o) = *(uint2*)th;
    *(uint2*)((char*)Zl + o) = *(uint2*)tl;
  }
  __syncthreads();

  // ---- MLP GEMMs ----
  const int lane = tid & 63, wv = tid >> 6;
  const int fr = lane & 15, quad = lane >> 4;
  const int nj0 = wv * 32 + fr, nj1 = nj0 + 16;

  f32x4 acc[4][2];
#pragma unroll
  for (int i = 0; i < 4; ++i) { acc[i][0] = (f32x4){0,0,0,0}; acc[i][1] = (f32x4){0,0,0,0}; }

  // MLP1: t = relu(Z @ W1 + b1)
#pragma unroll
  for (int ch = 0; ch < 4; ++ch) {
    bhalf8 afh[4], afl[4], bfh[2], bfl[2];
#pragma unroll
    for (int i = 0; i < 4; ++i) {
      const int o = zoff(i * 16 + fr, ch * 32 + quad * 8);
      afh[i] = *(const bhalf8*)((const char*)Zh + o);
      afl[i] = *(const bhalf8*)((const char*)Zl + o);
    }
#pragma unroll
    for (int j = 0; j < 2; ++j) {
      const size_t off = (size_t)(wv * 32 + j * 16 + fr) * HH + ch * 32 + quad * 8;
      bfh[j] = *(const bhalf8*)(B1h + off);
      bfl[j] = *(const bhalf8*)(B1l + off);
    }
#pragma unroll
    for (int i = 0; i < 4; ++i)
#pragma unroll
      for (int j = 0; j < 2; ++j) {
        acc[i][j] = __builtin_amdgcn_mfma_f32_16x16x32_bf16(afh[i], bfh[j], acc[i][j], 0, 0, 0);
        acc[i][j] = __builtin_amdgcn_mfma_f32_16x16x32_bf16(afl[i], bfh[j], acc[i][j], 0, 0, 0);
        acc[i][j] = __builtin_amdgcn_mfma_f32_16x16x32_bf16(afh[i], bfl[j], acc[i][j], 0, 0, 0);
      }
  }
  __syncthreads();          // all Z reads done (T aliases Z)

  // epilogue 1: T = relu(acc + b1), split, into swizzled LDS
  {
    const float b10 = bias1[nj0], b11 = bias1[nj1];
#pragma unroll
    for (int i = 0; i < 4; ++i)
#pragma unroll
      for (int r = 0; r < 4; ++r) {
        const int row = i * 16 + quad * 4 + r;
        const float o0 = fmaxf(acc[i][0][r] + b10, 0.f);
        const float o1 = fmaxf(acc[i][1][r] + b11, 0.f);
        ushort h0, l0, h1, l1; fsplit(o0, h0, l0); fsplit(o1, h1, l1);
        *(ushort*)((char*)Zh + zoff(row, nj0)) = h0;
        *(ushort*)((char*)Zl + zoff(row, nj0)) = l0;
        *(ushort*)((char*)Zh + zoff(row, nj1)) = h1;
        *(ushort*)((char*)Zl + zoff(row, nj1)) = l1;
      }
  }
  __syncthreads();

  // MLP2: z = T @ W2 + b2
#pragma unroll
  for (int i = 0; i < 4; ++i) { acc[i][0] = (f32x4){0,0,0,0}; acc[i][1] = (f32x4){0,0,0,0}; }
#pragma unroll
  for (int ch = 0; ch < 4; ++ch) {
    bhalf8 afh[4], afl[4], bfh[2], bfl[2];
#pragma unroll
    for (int i = 0; i < 4; ++i) {
      const int o = zoff(i * 16 + fr, ch * 32 + quad * 8);
      afh[i] = *(const bhalf8*)((const char*)Zh + o);
      afl[i] = *(const bhalf8*)((const char*)Zl + o);
    }
#pragma unroll
    for (int j = 0; j < 2; ++j) {
      const size_t off = (size_t)(wv * 32 + j * 16 + fr) * HH + ch * 32 + quad * 8;
      bfh[j] = *(const bhalf8*)(B2h + off);
      bfl[j] = *(const bhalf8*)(B2l + off);
    }
#pragma unroll
    for (int i = 0; i < 4; ++i)
#pragma unroll
      for (int j = 0; j < 2; ++j) {
        acc[i][j] = __builtin_amdgcn_mfma_f32_16x16x32_bf16(afh[i], bfh[j], acc[i][j], 0, 0, 0);
        acc[i][j] = __builtin_amdgcn_mfma_f32_16x16x32_bf16(afl[i], bfh[j], acc[i][j], 0, 0, 0);
        acc[i][j] = __builtin_amdgcn_mfma_f32_16x16x32_bf16(afh[i], bfl[j], acc[i][j], 0, 0, 0);
      }
  }
  __syncthreads();          // all T reads done — Z/T tiles now dead, reuse for z

  // epilogue 2a: split z into swizzled LDS (same pattern as epilogue 1)
  {
    const float b20 = bias2[nj0], b21 = bias2[nj1];
#pragma unroll
    for (int i = 0; i < 4; ++i)
#pragma unroll
      for (int r = 0; r < 4; ++r) {
        const int row = i * 16 + quad * 4 + r;
        const float o0 = acc[i][0][r] + b20;
        const float o1 = acc[i][1][r] + b21;
        ushort h0, l0, h1, l1; fsplit(o0, h0, l0); fsplit(o1, h1, l1);
        *(ushort*)((char*)Zh + zoff(row, nj0)) = h0;
        *(ushort*)((char*)Zl + zoff(row, nj0)) = l0;
        *(ushort*)((char*)Zh + zoff(row, nj1)) = h1;
        *(ushort*)((char*)Zl + zoff(row, nj1)) = l1;
      }
  }
  __syncthreads();

  // epilogue 2b: coalesced copy-out. Thread t, iter k: 16B at global ushort
  // index t*8 + k*2048 -> lanes contiguous (1KB per wave-instruction).
#pragma unroll
  for (int k = 0; k < 4; ++k) {
    const int gidx = tid * 8 + k * 2048;         // ushort index in [0, 8192)
    const int row = gidx >> 7;
    const int col = gidx & 127;
    const int o = zoff(row, col);
    *(uint4*)(zh + base + gidx) = *(const uint4*)((const char*)Zh + o);
    *(uint4*)(zl + base + gidx) = *(const uint4*)((const char*)Zl + o);
  }
}

// ---------------------------------------------------------------------------
// MP-2 GEMM: verified 128-row LDS-staged structure + T14 issue-early prefetch.
// ---------------------------------------------------------------------------
__launch_bounds__(256, 3)
__global__ void mp2_k(const ushort* __restrict__ Ah, const ushort* __restrict__ Al,
                      const ushort* __restrict__ A2h, const ushort* __restrict__ A2l,
                      const ushort* __restrict__ Bh, const ushort* __restrict__ Bl,
                      const float* __restrict__ bias, float* __restrict__ Cf,
                      const int* __restrict__ idc, float* __restrict__ stats) {
  constexpr int LDP = 40;   // LDS row stride in shorts
  __shared__ __align__(16) ushort Ash[128 * LDP];
  __shared__ __align__(16) ushort Asl[128 * LDP];
  __shared__ __align__(16) ushort Bsh[128 * LDP];
  __shared__ __align__(16) ushort Bsl[128 * LDP];
  const int tid = threadIdx.x;
  const int row0 = blockIdx.x * 128;
  const int lane = tid & 63, wv = tid >> 6;
  const int wm = (wv >> 1) * 64, wn = (wv & 1) * 64;
  const int fr = lane & 15, quad = lane >> 4;
  const int sr = tid >> 1;            // staging row 0..127
  const int sc = (tid & 1) * 16;      // staging short-offset {0,16}
  const int grow = idc[row0 + sr];    // gather row for K-half 2 (hoisted)

  f32x4 acc[4][4];
#pragma unroll
  for (int i = 0; i < 4; ++i)
#pragma unroll
    for (int j = 0; j < 4; ++j) acc[i][j] = (f32x4){0.f, 0.f, 0.f, 0.f};

  uint4 pa0, pa1, pa2, pa3, pb0, pb1, pb2, pb3;   // prefetch registers
  auto LA = [&](int ch) {
    const ushort *sh_, *sl_;
    if (ch >= 4) {
      const size_t off = (size_t)grow * HH + (ch - 4) * 32 + sc;
      sh_ = A2h + off; sl_ = A2l + off;
    } else {
      const size_t off = (size_t)(row0 + sr) * HH + ch * 32 + sc;
      sh_ = Ah + off; sl_ = Al + off;
    }
    pa0 = *(const uint4*)(sh_);     pa1 = *(const uint4*)(sh_ + 8);
    pa2 = *(const uint4*)(sl_);     pa3 = *(const uint4*)(sl_ + 8);
  };
  auto LB = [&](int ch) {
    const size_t off = (size_t)sr * 256 + ch * 32 + sc;
    pb0 = *(const uint4*)(Bh + off); pb1 = *(const uint4*)(Bh + off + 8);
    pb2 = *(const uint4*)(Bl + off); pb3 = *(const uint4*)(Bl + off + 8);
  };

  LA(0); LB(0);
#pragma unroll
  for (int ch = 0; ch < 8; ++ch) {
    // ---- write prefetched chunk to LDS ----
    *(uint4*)&Ash[sr * LDP + sc]     = pa0;
    *(uint4*)&Ash[sr * LDP + sc + 8] = pa1;
    *(uint4*)&Asl[sr * LDP + sc]     = pa2;
    *(uint4*)&Asl[sr * LDP + sc + 8] = pa3;
    *(uint4*)&Bsh[sr * LDP + sc]     = pb0;
    *(uint4*)&Bsh[sr * LDP + sc + 8] = pb1;
    *(uint4*)&Bsl[sr * LDP + sc]     = pb2;
    *(uint4*)&Bsl[sr * LDP + sc + 8] = pb3;
    __syncthreads();
    // ---- issue next chunk's global loads (fly during MFMA) ----
    if (ch < 7) { LA(ch + 1); LB(ch + 1); }
    // ---- one K=32 MFMA step, bf16x3 ----
    bhalf8 afh[4], afl[4], bfh[4], bfl[4];
#pragma unroll
    for (int i = 0; i < 4; ++i) {
      const int r = (wm + i * 16 + fr) * LDP + quad * 8;
      afh[i] = *(const bhalf8*)&Ash[r];
      afl[i] = *(const bhalf8*)&Asl[r];
    }
#pragma unroll
    for (int j = 0; j < 4; ++j) {
      const int r = (wn + j * 16 + fr) * LDP + quad * 8;
      bfh[j] = *(const bhalf8*)&Bsh[r];
      bfl[j] = *(const bhalf8*)&Bsl[r];
    }
#pragma unroll
    for (int i = 0; i < 4; ++i)
#pragma unroll
      for (int j = 0; j < 4; ++j) {
        acc[i][j] = __builtin_amdgcn_mfma_f32_16x16x32_bf16(afh[i], bfh[j], acc[i][j], 0, 0, 0);
        acc[i][j] = __builtin_amdgcn_mfma_f32_16x16x32_bf16(afl[i], bfh[j], acc[i][j], 0, 0, 0);
        acc[i][j] = __builtin_amdgcn_mfma_f32_16x16x32_bf16(afh[i], bfl[j], acc[i][j], 0, 0, 0);
      }
    __syncthreads();
  }

  // ---- epilogue: relu + bias, uf write, BN stats ----
  const int nj[4] = {wn + fr, wn + 16 + fr, wn + 32 + fr, wn + 48 + fr};
  float bb[4];
#pragma unroll
  for (int j = 0; j < 4; ++j) bb[j] = bias[nj[j]];
  float psum[4] = {0.f, 0.f, 0.f, 0.f}, psq[4] = {0.f, 0.f, 0.f, 0.f};
#pragma unroll
  for (int i = 0; i < 4; ++i)
#pragma unroll
    for (int r = 0; r < 4; ++r) {
      const int m = row0 + wm + i * 16 + quad * 4 + r;
      const size_t base = (size_t)m * HH;
#pragma unroll
      for (int j = 0; j < 4; ++j) {
        float o = fmaxf(acc[i][j][r] + bb[j], 0.f);
        Cf[base + nj[j]] = o;
        psum[j] += o; psq[j] += o * o;
      }
    }
  float* ssum = (float*)Ash;      // dead past last barrier
  float* ssq = ssum + HH;
  if (tid < HH) { ssum[tid] = 0.f; ssq[tid] = 0.f; }
  __syncthreads();
#pragma unroll
  for (int j = 0; j < 4; ++j) {
    atomicAdd(&ssum[nj[j]], psum[j]);
    atomicAdd(&ssq[nj[j]], psq[j]);
  }
  __syncthreads();
  if (tid < HH) {
    unsafeAtomicAdd(&stats[tid], ssum[tid]);
    unsafeAtomicAdd(&stats[HH + tid], ssq[tid]);
  }
}

// ---------------------------------------------------------------------------
// Init GEMM (MODE 0): verified LDS-staged structure + T14 issue-early
// prefetch (same transform as mp2_k round 6) + 3 blocks/CU.
// ---------------------------------------------------------------------------
__launch_bounds__(256, 3)
__global__ void mgemm0_k(const float* __restrict__ Afp,
                         const ushort* __restrict__ Bh, const ushort* __restrict__ Bl,
                         float* __restrict__ Cf,
                         const int* __restrict__ idc, const float* __restrict__ log_probs,
                         const int* __restrict__ root_local, const float* __restrict__ vl,
                         const float* __restrict__ c0v, const float* __restrict__ rev) {
  constexpr int LDP = 40;
  __shared__ __align__(16) ushort Ash[128 * LDP];
  __shared__ __align__(16) ushort Asl[128 * LDP];
  __shared__ __align__(16) ushort Bsh[128 * LDP];
  __shared__ __align__(16) ushort Bsl[128 * LDP];
  const int tid = threadIdx.x;
  const int row0 = blockIdx.x * 128;
  const int lane = tid & 63, wv = tid >> 6;
  const int wm = (wv >> 1) * 64, wn = (wv & 1) * 64;
  const int fr = lane & 15, quad = lane >> 4;
  const int sr = tid >> 1;
  const int sc = (tid & 1) * 16;
  const int arow = idc[row0 + sr];   // hoisted gather row

  f32x4 acc[4][4];
#pragma unroll
  for (int i = 0; i < 4; ++i)
#pragma unroll
    for (int j = 0; j < 4; ++j) acc[i][j] = (f32x4){0.f, 0.f, 0.f, 0.f};

  float4 pf0, pf1, pf2, pf3;
  uint4  pb0, pb1, pb2, pb3;
  auto LA = [&](int ch) {
    const float* src = Afp + (size_t)arow * HH + ch * 32 + sc;
    pf0 = *(const float4*)(src);     pf1 = *(const float4*)(src + 4);
    pf2 = *(const float4*)(src + 8); pf3 = *(const float4*)(src + 12);
  };
  auto LB = [&](int ch) {
    const size_t off = (size_t)sr * HH + ch * 32 + sc;
    pb0 = *(const uint4*)(Bh + off); pb1 = *(const uint4*)(Bh + off + 8);
    pb2 = *(const uint4*)(Bl + off); pb3 = *(const uint4*)(Bl + off + 8);
  };

  LA(0); LB(0);
#pragma unroll
  for (int ch = 0; ch < 4; ++ch) {
    {
      float fv[16];
      *(float4*)&fv[0]  = pf0; *(float4*)&fv[4]  = pf1;
      *(float4*)&fv[8]  = pf2; *(float4*)&fv[12] = pf3;
      ushort hi[16], lo[16];
#pragma unroll
      for (int e = 0; e < 16; ++e) fsplit(fv[e], hi[e], lo[e]);
      *(uint4*)&Ash[sr * LDP + sc]     = *(uint4*)&hi[0];
      *(uint4*)&Ash[sr * LDP + sc + 8] = *(uint4*)&hi[8];
      *(uint4*)&Asl[sr * LDP + sc]     = *(uint4*)&lo[0];
      *(uint4*)&Asl[sr * LDP + sc + 8] = *(uint4*)&lo[8];
    }
    *(uint4*)&Bsh[sr * LDP + sc]     = pb0;
    *(uint4*)&Bsh[sr * LDP + sc + 8] = pb1;
    *(uint4*)&Bsl[sr * LDP + sc]     = pb2;
    *(uint4*)&Bsl[sr * LDP + sc + 8] = pb3;
    __syncthreads();
    if (ch < 3) { LA(ch + 1); LB(ch + 1); }
    bhalf8 afh[4], afl[4], bfh[4], bfl[4];
#pragma unroll
    for (int i = 0; i < 4; ++i) {
      const int r = (wm + i * 16 + fr) * LDP + quad * 8;
      afh[i] = *(const bhalf8*)&Ash[r];
      afl[i] = *(const bhalf8*)&Asl[r];
    }
#pragma unroll
    for (int j = 0; j < 4; ++j) {
      const int r = (wn + j * 16 + fr) * LDP + quad * 8;
      bfh[j] = *(const bhalf8*)&Bsh[r];
      bfl[j] = *(const bhalf8*)&Bsl[r];
    }
#pragma unroll
    for (int i = 0; i < 4; ++i)
#pragma unroll
      for (int j = 0; j < 4; ++j) {
        acc[i][j] = __builtin_amdgcn_mfma_f32_16x16x32_bf16(afh[i], bfh[j], acc[i][j], 0, 0, 0);
        acc[i][j] = __builtin_amdgcn_mfma_f32_16x16x32_bf16(afl[i], bfh[j], acc[i][j], 0, 0, 0);
        acc[i][j] = __builtin_amdgcn_mfma_f32_16x16x32_bf16(afh[i], bfl[j], acc[i][j], 0, 0, 0);
      }
    __syncthreads();
  }

  const int nj[4] = {wn + fr, wn + 16 + fr, wn + 32 + fr, wn + 48 + fr};
  float c0a[4], vla[4], re0[4], re1[4];
#pragma unroll
  for (int j = 0; j < 4; ++j) {
    c0a[j] = c0v[nj[j]]; vla[j] = vl[nj[j]];
    re0[j] = rev[nj[j]]; re1[j] = rev[HH + nj[j]];
  }
#pragma unroll
  for (int i = 0; i < 4; ++i)
#pragma unroll
    for (int r = 0; r < 4; ++r) {
      const int m = row0 + wm + i * 16 + quad * 4 + r;
      const int s = m >> 6;
      const float lp = log_probs[s];
      const bool isr = (m & 63) == root_local[s];
      const size_t base = (size_t)m * HH;
#pragma unroll
      for (int j = 0; j < 4; ++j)
        Cf[base + nj[j]] = acc[i][j][r] + c0a[j] + lp * vla[j] + (isr ? re1[j] : re0[j]);
    }
}

// ---------------------------------------------------------------------------
// Final BN apply with residual; coef computed inline from stats.
// ---------------------------------------------------------------------------
__launch_bounds__(256)
__global__ void bn_apply_k(const float* __restrict__ u, float* __restrict__ h,
                           const float* __restrict__ stats,
                           const float* __restrict__ gamma, const float* __restrict__ beta) {
  size_t i4 = (size_t)(blockIdx.x * 256 + threadIdx.x) * 4;
  int c = (int)(i4 & 127);
  const float invM = 1.0f / (float)SKK;
  float sc[4], sh[4];
#pragma unroll
  for (int e = 0; e < 4; ++e) {
    const float mu = stats[c + e] * invM;
    const float var = fmaf(-mu, mu, stats[HH + c + e] * invM);
    const float s = rsqrtf(var + 1e-5f) * gamma[c + e];
    sc[e] = s; sh[e] = fmaf(-mu, s, beta[c + e]);
  }
  float4 uv = *(const float4*)(u + i4);
  float4 hv = *(const float4*)(h + i4);
  float4 o;
  o.x = fmaf(uv.x, sc[0], sh[0]) + hv.x;
  o.y = fmaf(uv.y, sc[1], sh[1]) + hv.y;
  o.z = fmaf(uv.z, sc[2], sh[2]) + hv.z;
  o.w = fmaf(uv.w, sc[3], sh[3]) + hv.w;
  *(float4*)(h + i4) = o;
}

// ---------------------------------------------------------------------------
extern "C" void kernel_launch(void* const* d_in, const int* in_sizes, int n_in,
                              void* d_out, int out_size, void* d_ws, size_t ws_size,
                              hipStream_t stream) {
  const float* x          = (const float*)d_in[0];
  const float* log_probs  = (const float*)d_in[1];
  const float* node_w     = (const float*)d_in[2];
  const float* node_b     = (const float*)d_in[3];
  const float* logp_w     = (const float*)d_in[4];
  const float* logp_b     = (const float*)d_in[5];
  const float* root_emb   = (const float*)d_in[6];
  const float* init_w     = (const float*)d_in[7];
  const float* init_b     = (const float*)d_in[8];
  const float* gin_eps    = (const float*)d_in[9];
  const float* w1         = (const float*)d_in[10];
  const float* b1         = (const float*)d_in[11];
  const float* w2         = (const float*)d_in[12];
  const float* b2         = (const float*)d_in[13];
  const float* mp2w       = (const float*)d_in[14];
  const float* mp2b       = (const float*)d_in[15];
  const float* gamma      = (const float*)d_in[16];
  const float* beta       = (const float*)d_in[17];
  const int*   nodes      = (const int*)d_in[18];
  const int*   root_local = (const int*)d_in[19];
  const int*   edge_idx   = (const int*)d_in[20];
  const int*   edge_ptr   = (const int*)d_in[21];
  float* h = (float*)d_out;   // fp32 residual stream lives in d_out

  // ---- workspace carve ----
  char* wp = (char*)d_ws;
  auto take = [&](size_t bytes) { char* p = wp; wp += (bytes + 255) & ~(size_t)255; return p; };
  ushort* zh    = (ushort*)take((size_t)SKK * HH * 2);   // 32 MB
  ushort* zl    = (ushort*)take((size_t)SKK * HH * 2);
  float*  uf    = (float*)take((size_t)SKK * HH * 4);    // 64 MB
  ushort* xah   = (ushort*)take((size_t)NN * HH * 2);
  ushort* xal   = (ushort*)take((size_t)NN * HH * 2);
  ushort* Mth   = (ushort*)take((size_t)HH * HH * 2);
  ushort* Mtl   = (ushort*)take((size_t)HH * HH * 2);
  ushort* w1th  = (ushort*)take((size_t)LLAY * HH * HH * 2);
  ushort* w1tl  = (ushort*)take((size_t)LLAY * HH * HH * 2);
  ushort* w2th  = (ushort*)take((size_t)LLAY * HH * HH * 2);
  ushort* w2tl  = (ushort*)take((size_t)LLAY * HH * HH * 2);
  ushort* mp2th = (ushort*)take((size_t)LLAY * HH * 256 * 2);
  ushort* mp2tl = (ushort*)take((size_t)LLAY * HH * 256 * 2);
  float* vl       = (float*)take(HH * 4);
  float* c0v      = (float*)take(HH * 4);
  float* rev      = (float*)take(2 * HH * 4);
  float* bn_stats = (float*)take(LLAY * 2 * HH * 4);
  int*   cnti     = (int*)take((size_t)NN * 4);
  int*   excl     = (int*)take((size_t)NBLK * 256 * 4);
  int*   bsum     = (int*)take(256 * 4);
  int*   boff     = (int*)take(256 * 4);
  int*   node_ptr = (int*)take((size_t)(NN + 1) * 4);
  int*   cur      = (int*)take((size_t)NN * 4);
  int*   rowlist  = (int*)take((size_t)SKK * 4);
  int*   row_ptr  = (int*)take((size_t)(SKK + 1) * 4);
  int*   ssrc     = (int*)take((size_t)EE * 4);

  // ---- prologue ----
  hipMemsetAsync(cnti, 0, (size_t)NN * 4, stream);
  hipMemsetAsync(cur, 0, (size_t)NN * 4, stream);
  hipMemsetAsync(bn_stats, 0, LLAY * 2 * HH * 4, stream);
  fold_M_k<<<HH, HH, 0, stream>>>(node_w, init_w, Mth, Mtl);
  fold_vec_k<<<1, HH, 0, stream>>>(init_w, logp_w, node_b, logp_b, init_b, root_emb,
                                   vl, c0v, rev);
  wconv_k<<<2560, HH, 0, stream>>>(w1, w2, mp2w, w1th, w1tl, w2th, w2tl, mp2th, mp2tl);
  count_k<<<SKK / 256, 256, 0, stream>>>(nodes, cnti);
  scan1_k<<<NBLK, 256, 0, stream>>>(cnti, excl, bsum);
  scan2_k<<<1, 256, 0, stream>>>(bsum, boff);
  scan3_k<<<NBLK, 256, 0, stream>>>(excl, boff, node_ptr);
  fill_rows_k<<<SKK / 256, 256, 0, stream>>>(nodes, node_ptr, cur, rowlist);
  presort_k<<<SS, 256, 0, stream>>>(edge_idx, edge_idx + EE, edge_ptr, row_ptr, ssrc);

  // initial h (fp32, in d_out)
  mgemm0_k<<<SKK / 128, 256, 0, stream>>>(x, Mth, Mtl, h,
                                          nodes, log_probs, root_local, vl, c0v, rev);

  for (int l = 0; l < LLAY; ++l) {
    if (l == 0) {
      gin_mega_k<true><<<SS, 256, 0, stream>>>(h, nullptr, nullptr, nullptr, nullptr,
                                               row_ptr, ssrc, gin_eps, l,
                                               w1th + (size_t)l * HH * HH,
                                               w1tl + (size_t)l * HH * HH,
                                               w2th + (size_t)l * HH * HH,
                                               w2tl + (size_t)l * HH * HH,
                                               b1 + l * HH, b2 + l * HH, zh, zl);
    } else {
      gin_mega_k<false><<<SS, 256, 0, stream>>>(h, uf, bn_stats + (l - 1) * 2 * HH,
                                                gamma + (l - 1) * HH, beta + (l - 1) * HH,
                                                row_ptr, ssrc, gin_eps, l,
                                                w1th + (size_t)l * HH * HH,
                                                w1tl + (size_t)l * HH * HH,
                                                w2th + (size_t)l * HH * HH,
                                                w2tl + (size_t)l * HH * HH,
                                                b1 + l * HH, b2 + l * HH, zh, zl);
    }
    scatter_mean_k<<<(NN + 7) / 8, 256, 0, stream>>>(zh, zl, node_ptr, rowlist, xah, xal);
    mp2_k<<<SKK / 128, 256, 0, stream>>>(zh, zl, xah, xal,
                                         mp2th + (size_t)l * HH * 256,
                                         mp2tl + (size_t)l * HH * 256,
                                         mp2b + l * HH, uf, nodes,
                                         bn_stats + l * 2 * HH);
  }
  // final BN+residual apply (layer 4) -> h in d_out
  bn_apply_k<<<(SKK * HH / 4) / 256, 256, 0, stream>>>(uf, h, bn_stats + 4 * 2 * HH,
                                                       gamma + 4 * HH, beta + 4 * HH);
}

// Round 11
// 980.699 us; speedup vs baseline: 1.0887x; 1.0096x over previous
//
#include <hip/hip_runtime.h>
#include <cstdint>

#define NN   50000
#define SS   2048
#define KSUB 64
#define HH   128
#define EE   (SS * 256)
#define SKK  (SS * KSUB)    // 131072
#define LLAY 5
#define NBLK 196            // ceil(NN/256)

typedef __attribute__((ext_vector_type(8))) short bhalf8;
typedef __attribute__((ext_vector_type(4))) float f32x4;

__device__ __forceinline__ ushort f2b(float f) {
  uint u = __builtin_bit_cast(uint, f);
  uint r = (u + 0x7FFFu + ((u >> 16) & 1u)) >> 16;
  return (ushort)r;
}
__device__ __forceinline__ float b2f(ushort u) {
  uint v = ((uint)u) << 16;
  return __builtin_bit_cast(float, v);
}
// split fp32 -> (hi, lo) bf16 pair; hi + lo ~= f with ~2^-18 residual
__device__ __forceinline__ void fsplit(float f, ushort& hi, ushort& lo) {
  hi = f2b(f);
  lo = f2b(f - b2f(hi));
}
// byte offset into a [64][128]-short LDS tile, T2 XOR swizzle (row stride 256B)
__device__ __forceinline__ int zoff(int row, int col) {
  return row * 256 + (((col * 2) & 255) ^ ((row & 7) << 4));
}

// ---------------------------------------------------------------------------
// Fold node_proj through init_proj; emit split bf16 B^T layout [n][c]
// ---------------------------------------------------------------------------
__global__ void fold_M_k(const float* __restrict__ Wn, const float* __restrict__ Wi,
                         ushort* __restrict__ Mth, ushort* __restrict__ Mtl) {
  int c = blockIdx.x, n = threadIdx.x;
  float s = 0.f;
  for (int k = 0; k < HH; ++k) s = fmaf(Wn[c * HH + k], Wi[k * HH + n], s);
  ushort hi, lo; fsplit(s, hi, lo);
  Mth[n * HH + c] = hi; Mtl[n * HH + c] = lo;
}

__global__ void fold_vec_k(const float* __restrict__ Wi, const float* __restrict__ wl,
                           const float* __restrict__ bnb, const float* __restrict__ blb,
                           const float* __restrict__ bi, const float* __restrict__ remb,
                           float* __restrict__ vl, float* __restrict__ c0,
                           float* __restrict__ rev) {
  int n = threadIdx.x;
  float svl = 0.f, sc0 = bi[n], r0 = 0.f, r1 = 0.f;
  for (int k = 0; k < HH; ++k) {
    svl = fmaf(wl[k], Wi[(HH + k) * HH + n], svl);
    sc0 = fmaf(bnb[k], Wi[k * HH + n], sc0);
    sc0 = fmaf(blb[k], Wi[(HH + k) * HH + n], sc0);
    r0  = fmaf(remb[k],      Wi[(2 * HH + k) * HH + n], r0);
    r1  = fmaf(remb[HH + k], Wi[(2 * HH + k) * HH + n], r1);
  }
  vl[n] = svl; c0[n] = sc0; rev[n] = r0; rev[HH + n] = r1;
}

// ---------------------------------------------------------------------------
// Transpose+convert all layer weights to split bf16 B^T layout (one launch).
// ---------------------------------------------------------------------------
__global__ void wconv_k(const float* __restrict__ w1, const float* __restrict__ w2,
                        const float* __restrict__ mp2w,
                        ushort* __restrict__ w1th, ushort* __restrict__ w1tl,
                        ushort* __restrict__ w2th, ushort* __restrict__ w2tl,
                        ushort* __restrict__ mp2th, ushort* __restrict__ mp2tl) {
  int b = blockIdx.x, n = threadIdx.x;
  ushort hi, lo;
  if (b < 640) {
    int l = b >> 7, k = b & 127;
    fsplit(w1[((size_t)l * HH + k) * HH + n], hi, lo);
    w1th[((size_t)l * HH + n) * HH + k] = hi;
    w1tl[((size_t)l * HH + n) * HH + k] = lo;
  } else if (b < 1280) {
    int bb = b - 640; int l = bb >> 7, k = bb & 127;
    fsplit(w2[((size_t)l * HH + k) * HH + n], hi, lo);
    w2th[((size_t)l * HH + n) * HH + k] = hi;
    w2tl[((size_t)l * HH + n) * HH + k] = lo;
  } else {
    int bb = b - 1280; int l = bb >> 8, k = bb & 255;
    fsplit(mp2w[((size_t)l * 256 + k) * HH + n], hi, lo);
    mp2th[((size_t)l * HH + n) * 256 + k] = hi;
    mp2tl[((size_t)l * HH + n) * 256 + k] = lo;
  }
}

// ---------------------------------------------------------------------------
// Node-CSR construction: count -> exclusive scan -> fill
// ---------------------------------------------------------------------------
__global__ void count_k(const int* __restrict__ idc, int* __restrict__ cnt) {
  int i = blockIdx.x * 256 + threadIdx.x;
  if (i < SKK) atomicAdd(&cnt[idc[i]], 1);
}

__global__ void scan1_k(const int* __restrict__ cnt, int* __restrict__ excl,
                        int* __restrict__ bsum) {
  __shared__ int sh[256];
  const int tid = threadIdx.x;
  const int i = blockIdx.x * 256 + tid;
  int v = (i < NN) ? cnt[i] : 0;
  sh[tid] = v;
  __syncthreads();
#pragma unroll
  for (int off = 1; off < 256; off <<= 1) {
    int t = (tid >= off) ? sh[tid - off] : 0;
    __syncthreads();
    sh[tid] += t;
    __syncthreads();
  }
  excl[i] = sh[tid] - v;
  if (tid == 255) bsum[blockIdx.x] = sh[tid];
}

__global__ void scan2_k(int* __restrict__ bsum, int* __restrict__ boff) {
  __shared__ int sh[256];
  const int tid = threadIdx.x;
  int v = (tid < NBLK) ? bsum[tid] : 0;
  sh[tid] = v;
  __syncthreads();
#pragma unroll
  for (int off = 1; off < 256; off <<= 1) {
    int t = (tid >= off) ? sh[tid - off] : 0;
    __syncthreads();
    sh[tid] += t;
    __syncthreads();
  }
  boff[tid] = sh[tid] - v;
}

__global__ void scan3_k(const int* __restrict__ excl, const int* __restrict__ boff,
                        int* __restrict__ node_ptr) {
  int i = blockIdx.x * 256 + threadIdx.x;
  if (i < NN) node_ptr[i] = excl[i] + boff[blockIdx.x];
  if (i == 0) node_ptr[NN] = SKK;
}

__global__ void fill_rows_k(const int* __restrict__ idc, const int* __restrict__ node_ptr,
                            int* __restrict__ cur, int* __restrict__ rowlist) {
  int i = blockIdx.x * 256 + threadIdx.x;
  if (i < SKK) {
    int id = idc[i];
    int pos = atomicAdd(&cur[id], 1);
    rowlist[node_ptr[id] + pos] = i;
  }
}

// ---------------------------------------------------------------------------
// Cross-subgraph scatter-mean as a GATHER. Vectorized: 16 lanes/node,
// 16B uint4 loads per lane, 16 nodes/block.
// ---------------------------------------------------------------------------
__launch_bounds__(256)
__global__ void scatter_mean_k(const ushort* __restrict__ zh, const ushort* __restrict__ zl,
                               const int* __restrict__ node_ptr,
                               const int* __restrict__ rowlist,
                               ushort* __restrict__ xah, ushort* __restrict__ xal) {
  const int tid = threadIdx.x;
  const int n = blockIdx.x * 16 + (tid >> 4);
  if (n >= NN) return;
  const int c8 = (tid & 15) * 8;
  const int p0 = node_ptr[n], p1 = node_ptr[n + 1];
  float s[8] = {0.f, 0.f, 0.f, 0.f, 0.f, 0.f, 0.f, 0.f};
  for (int p = p0; p < p1; ++p) {
    const size_t off = (size_t)rowlist[p] * HH + c8;
    uint4 vh = *(const uint4*)(zh + off);
    uint4 vl = *(const uint4*)(zl + off);
    const uint hw[4] = {vh.x, vh.y, vh.z, vh.w};
    const uint lw[4] = {vl.x, vl.y, vl.z, vl.w};
#pragma unroll
    for (int k = 0; k < 4; ++k) {
      s[2 * k]     += b2f((ushort)hw[k])        + b2f((ushort)lw[k]);
      s[2 * k + 1] += b2f((ushort)(hw[k] >> 16)) + b2f((ushort)(lw[k] >> 16));
    }
  }
  const float inv = 1.0f / (float)max(p1 - p0, 1);
  ushort hi[8], lo[8];
#pragma unroll
  for (int k = 0; k < 8; ++k) fsplit(s[k] * inv, hi[k], lo[k]);
  *(uint4*)(xah + (size_t)n * HH + c8) = *(uint4*)hi;
  *(uint4*)(xal + (size_t)n * HH + c8) = *(uint4*)lo;
}

// ---------------------------------------------------------------------------
// Per-subgraph counting sort of edges by dst -> CSR
// ---------------------------------------------------------------------------
__launch_bounds__(256)
__global__ void presort_k(const int* __restrict__ e_src, const int* __restrict__ e_dst,
                          const int* __restrict__ edge_ptr, int* __restrict__ row_ptr,
                          int* __restrict__ ssrc) {
  __shared__ int cnt[KSUB];
  __shared__ int base[KSUB];
  __shared__ int cur[KSUB];
  const int s = blockIdx.x, tid = threadIdx.x;
  const int p0 = edge_ptr[s], p1 = edge_ptr[s + 1];
  if (tid < KSUB) cnt[tid] = 0;
  __syncthreads();
  for (int e = p0 + tid; e < p1; e += 256) atomicAdd(&cnt[e_dst[e]], 1);
  __syncthreads();
  if (tid == 0) {
    int a = 0;
    for (int d = 0; d < KSUB; ++d) { base[d] = a; a += cnt[d]; }
  }
  __syncthreads();
  if (tid < KSUB) { row_ptr[s * KSUB + tid] = p0 + base[tid]; cur[tid] = base[tid]; }
  if (s == 0 && tid == 0) row_ptr[SS * KSUB] = edge_ptr[SS];
  __syncthreads();
  for (int e = p0 + tid; e < p1; e += 256) {
    int d = e_dst[e];
    int pos = atomicAdd(&cur[d], 1);
    ssrc[p0 + pos] = e_src[e];
  }
}

// ---------------------------------------------------------------------------
// MEGA kernel: per subgraph (64 rows):
//   phase A: h_new = bn(uf) + h_old (residual) [skip BN if FIRST];
//            BN coef computed INLINE from stats; write h_new, keep fp32 in LDS
//            + stage this subgraph's 256 ssrc entries into LDS (1 KB)
//   phase B: GIN aggregation (interleaved channel mapping, ssrc from LDS)
//   phase C: split z_agg -> swizzled bf16 LDS tile Z (aliases hl)
//   MLP1:    t = relu(Z @ W1 + b1) -> swizzled LDS tile T (aliases Z)
//   MLP2:    z = T @ W2 + b2 -> staged into dead Z/T LDS tiles (swizzled),
//            then COALESCED copy-out (4x dwordx4/thread/buffer)
// ---------------------------------------------------------------------------
template <bool FIRST>
__launch_bounds__(256, 4)
__global__ void gin_mega_k(float* __restrict__ h, const float* __restrict__ uf,
                           const float* __restrict__ stats,
                           const float* __restrict__ gamma, const float* __restrict__ beta,
                           const int* __restrict__ row_ptr, const int* __restrict__ ssrc,
                           const float* __restrict__ gin_eps, const int layer,
                           const ushort* __restrict__ B1h, const ushort* __restrict__ B1l,
                           const ushort* __restrict__ B2h, const ushort* __restrict__ B2l,
                           const float* __restrict__ bias1, const float* __restrict__ bias2,
                           ushort* __restrict__ zh, ushort* __restrict__ zl) {
  constexpr int LDH = 132;
  __shared__ __align__(16) char smem[KSUB * LDH * 4];   // 33792 B, phase-aliased
  __shared__ int ssrc_lds[256];                          // 1 KB edge-source cache
  float*  hl = (float*)smem;                 // [64][132] fp32 (phases A,B)
  ushort* Zh = (ushort*)smem;                // [64][128] swizzled (phases C..out)
  ushort* Zl = (ushort*)(smem + KSUB * HH * 2);
  const int s = blockIdx.x, tid = threadIdx.x;
  const size_t base = (size_t)s * KSUB * HH;

  // ---- stage ssrc (coalesced, 1 iteration for ES=256) ----
  const int e_start = row_ptr[s * KSUB];
  {
    const int e_end = row_ptr[s * KSUB + KSUB];
    for (int e = e_start + tid; e < e_end; e += 256)
      ssrc_lds[e - e_start] = ssrc[e];
  }

  // ---- phase A (BN coef inline; c constant across 'it' since 1024 % 128 == 0) ----
  float csc[4], csh[4];
  const int cb = (tid * 4) & 127;
  if constexpr (!FIRST) {
    const float invM = 1.0f / (float)SKK;
#pragma unroll
    for (int e = 0; e < 4; ++e) {
      const float mu = stats[cb + e] * invM;
      const float var = fmaf(-mu, mu, stats[HH + cb + e] * invM);
      const float sc = rsqrtf(var + 1e-5f) * gamma[cb + e];
      csc[e] = sc; csh[e] = fmaf(-mu, sc, beta[cb + e]);
    }
  }
#pragma unroll
  for (int it = 0; it < 8; ++it) {
    const int idx = it * 1024 + tid * 4;
    const int m = idx >> 7, c = idx & 127;
    float4 hv = *(const float4*)&h[base + idx];
    if constexpr (!FIRST) {
      float4 u4 = *(const float4*)&uf[base + idx];
      hv.x += fmaf(u4.x, csc[0], csh[0]);
      hv.y += fmaf(u4.y, csc[1], csh[1]);
      hv.z += fmaf(u4.z, csc[2], csh[2]);
      hv.w += fmaf(u4.w, csc[3], csh[3]);
      *(float4*)&h[base + idx] = hv;
    }
    *(float4*)&hl[m * LDH + c] = hv;
  }
  __syncthreads();

  // ---- phase B: aggregation (interleaved channel mapping; ssrc from LDS) ----
  const float ep1 = 1.0f + gin_eps[layer];
  const int d = tid >> 2, q4 = (tid & 3) * 4;   // cols q4 + 16*j + k
  const int g = s * KSUB + d;
  const int e0 = row_ptr[g], e1 = row_ptr[g + 1];
  float a[32];
  {
    const float* hp0 = &hl[d * LDH + q4];
#pragma unroll
    for (int j = 0; j < 8; ++j) {
      float4 v = *(const float4*)(hp0 + 16 * j);
      a[4 * j + 0] = ep1 * v.x; a[4 * j + 1] = ep1 * v.y;
      a[4 * j + 2] = ep1 * v.z; a[4 * j + 3] = ep1 * v.w;
    }
    for (int e = e0; e < e1; ++e) {
      const float* hp = &hl[ssrc_lds[e - e_start] * LDH + q4];
#pragma unroll
      for (int j = 0; j < 8; ++j) {
        float4 v = *(const float4*)(hp + 16 * j);
        a[4 * j + 0] += v.x; a[4 * j + 1] += v.y;
        a[4 * j + 2] += v.z; a[4 * j + 3] += v.w;
      }
    }
  }
  __syncthreads();          // all hl reads done (Z aliases hl)

  // ---- phase C: split z_agg into swizzled LDS tile (8B writes) ----
#pragma unroll
  for (int j = 0; j < 8; ++j) {
    ushort th[4], tl[4];
#pragma unroll
    for (int k = 0; k < 4; ++k) fsplit(a[4 * j + k], th[k], tl[k]);
    const int o = zoff(d, q4 + 16 * j);
    *(uint2*)((char*)Zh + o) = *(uint2*)th;
    *(uint2*)((char*)Zl + o) = *(uint2*)tl;
  }
  __syncthreads();

  // ---- MLP GEMMs ----
  const int lane = tid & 63, wv = tid >> 6;
  const int fr = lane & 15, quad = lane >> 4;
  const int nj0 = wv * 32 + fr, nj1 = nj0 + 16;

  f32x4 acc[4][2];
#pragma unroll
  for (int i = 0; i < 4; ++i) { acc[i][0] = (f32x4){0,0,0,0}; acc[i][1] = (f32x4){0,0,0,0}; }

  // MLP1: t = relu(Z @ W1 + b1)
#pragma unroll
  for (int ch = 0; ch < 4; ++ch) {
    bhalf8 afh[4], afl[4], bfh[2], bfl[2];
#pragma unroll
    for (int i = 0; i < 4; ++i) {
      const int o = zoff(i * 16 + fr, ch * 32 + quad * 8);
      afh[i] = *(const bhalf8*)((const char*)Zh + o);
      afl[i] = *(const bhalf8*)((const char*)Zl + o);
    }
#pragma unroll
    for (int j = 0; j < 2; ++j) {
      const size_t off = (size_t)(wv * 32 + j * 16 + fr) * HH + ch * 32 + quad * 8;
      bfh[j] = *(const bhalf8*)(B1h + off);
      bfl[j] = *(const bhalf8*)(B1l + off);
    }
#pragma unroll
    for (int i = 0; i < 4; ++i)
#pragma unroll
      for (int j = 0; j < 2; ++j) {
        acc[i][j] = __builtin_amdgcn_mfma_f32_16x16x32_bf16(afh[i], bfh[j], acc[i][j], 0, 0, 0);
        acc[i][j] = __builtin_amdgcn_mfma_f32_16x16x32_bf16(afl[i], bfh[j], acc[i][j], 0, 0, 0);
        acc[i][j] = __builtin_amdgcn_mfma_f32_16x16x32_bf16(afh[i], bfl[j], acc[i][j], 0, 0, 0);
      }
  }
  __syncthreads();          // all Z reads done (T aliases Z)

  // epilogue 1: T = relu(acc + b1), split, into swizzled LDS
  {
    const float b10 = bias1[nj0], b11 = bias1[nj1];
#pragma unroll
    for (int i = 0; i < 4; ++i)
#pragma unroll
      for (int r = 0; r < 4; ++r) {
        const int row = i * 16 + quad * 4 + r;
        const float o0 = fmaxf(acc[i][0][r] + b10, 0.f);
        const float o1 = fmaxf(acc[i][1][r] + b11, 0.f);
        ushort h0, l0, h1, l1; fsplit(o0, h0, l0); fsplit(o1, h1, l1);
        *(ushort*)((char*)Zh + zoff(row, nj0)) = h0;
        *(ushort*)((char*)Zl + zoff(row, nj0)) = l0;
        *(ushort*)((char*)Zh + zoff(row, nj1)) = h1;
        *(ushort*)((char*)Zl + zoff(row, nj1)) = l1;
      }
  }
  __syncthreads();

  // MLP2: z = T @ W2 + b2
#pragma unroll
  for (int i = 0; i < 4; ++i) { acc[i][0] = (f32x4){0,0,0,0}; acc[i][1] = (f32x4){0,0,0,0}; }
#pragma unroll
  for (int ch = 0; ch < 4; ++ch) {
    bhalf8 afh[4], afl[4], bfh[2], bfl[2];
#pragma unroll
    for (int i = 0; i < 4; ++i) {
      const int o = zoff(i * 16 + fr, ch * 32 + quad * 8);
      afh[i] = *(const bhalf8*)((const char*)Zh + o);
      afl[i] = *(const bhalf8*)((const char*)Zl + o);
    }
#pragma unroll
    for (int j = 0; j < 2; ++j) {
      const size_t off = (size_t)(wv * 32 + j * 16 + fr) * HH + ch * 32 + quad * 8;
      bfh[j] = *(const bhalf8*)(B2h + off);
      bfl[j] = *(const bhalf8*)(B2l + off);
    }
#pragma unroll
    for (int i = 0; i < 4; ++i)
#pragma unroll
      for (int j = 0; j < 2; ++j) {
        acc[i][j] = __builtin_amdgcn_mfma_f32_16x16x32_bf16(afh[i], bfh[j], acc[i][j], 0, 0, 0);
        acc[i][j] = __builtin_amdgcn_mfma_f32_16x16x32_bf16(afl[i], bfh[j], acc[i][j], 0, 0, 0);
        acc[i][j] = __builtin_amdgcn_mfma_f32_16x16x32_bf16(afh[i], bfl[j], acc[i][j], 0, 0, 0);
      }
  }
  __syncthreads();          // all T reads done — Z/T tiles now dead, reuse for z

  // epilogue 2a: split z into swizzled LDS (same pattern as epilogue 1)
  {
    const float b20 = bias2[nj0], b21 = bias2[nj1];
#pragma unroll
    for (int i = 0; i < 4; ++i)
#pragma unroll
      for (int r = 0; r < 4; ++r) {
        const int row = i * 16 + quad * 4 + r;
        const float o0 = acc[i][0][r] + b20;
        const float o1 = acc[i][1][r] + b21;
        ushort h0, l0, h1, l1; fsplit(o0, h0, l0); fsplit(o1, h1, l1);
        *(ushort*)((char*)Zh + zoff(row, nj0)) = h0;
        *(ushort*)((char*)Zl + zoff(row, nj0)) = l0;
        *(ushort*)((char*)Zh + zoff(row, nj1)) = h1;
        *(ushort*)((char*)Zl + zoff(row, nj1)) = l1;
      }
  }
  __syncthreads();

  // epilogue 2b: coalesced copy-out. Thread t, iter k: 16B at global ushort
  // index t*8 + k*2048 -> lanes contiguous (1KB per wave-instruction).
#pragma unroll
  for (int k = 0; k < 4; ++k) {
    const int gidx = tid * 8 + k * 2048;         // ushort index in [0, 8192)
    const int row = gidx >> 7;
    const int col = gidx & 127;
    const int o = zoff(row, col);
    *(uint4*)(zh + base + gidx) = *(const uint4*)((const char*)Zh + o);
    *(uint4*)(zl + base + gidx) = *(const uint4*)((const char*)Zl + o);
  }
}

// ---------------------------------------------------------------------------
// MP-2 GEMM: verified 128-row LDS-staged structure + TWO-DEEP T14 prefetch:
// loads issued at chunk ch land in LDS at chunk ch+2, giving ~2 chunk-periods
// (~700 cy) to cover HBM latency vs ~300 cy at 1-deep. Two NAMED register
// sets selected by compile-time parity (rule #20: no runtime indexing).
// ---------------------------------------------------------------------------
__launch_bounds__(256, 3)
__global__ void mp2_k(const ushort* __restrict__ Ah, const ushort* __restrict__ Al,
                      const ushort* __restrict__ A2h, const ushort* __restrict__ A2l,
                      const ushort* __restrict__ Bh, const ushort* __restrict__ Bl,
                      const float* __restrict__ bias, float* __restrict__ Cf,
                      const int* __restrict__ idc, float* __restrict__ stats) {
  constexpr int LDP = 40;   // LDS row stride in shorts
  __shared__ __align__(16) ushort Ash[128 * LDP];
  __shared__ __align__(16) ushort Asl[128 * LDP];
  __shared__ __align__(16) ushort Bsh[128 * LDP];
  __shared__ __align__(16) ushort Bsl[128 * LDP];
  const int tid = threadIdx.x;
  const int row0 = blockIdx.x * 128;
  const int lane = tid & 63, wv = tid >> 6;
  const int wm = (wv >> 1) * 64, wn = (wv & 1) * 64;
  const int fr = lane & 15, quad = lane >> 4;
  const int sr = tid >> 1;            // staging row 0..127
  const int sc = (tid & 1) * 16;      // staging short-offset {0,16}
  const int grow = idc[row0 + sr];    // gather row for K-half 2 (hoisted)

  f32x4 acc[4][4];
#pragma unroll
  for (int i = 0; i < 4; ++i)
#pragma unroll
    for (int j = 0; j < 4; ++j) acc[i][j] = (f32x4){0.f, 0.f, 0.f, 0.f};

  // two named prefetch sets (E = even chunks, O = odd chunks)
  uint4 eA0, eA1, eA2, eA3, eB0, eB1, eB2, eB3;
  uint4 oA0, oA1, oA2, oA3, oB0, oB1, oB2, oB3;
  auto aptr = [&](int ch) -> const ushort* {
    if (ch >= 4) return A2h + ((size_t)grow * HH + (ch - 4) * 32 + sc);
    return Ah + ((size_t)(row0 + sr) * HH + ch * 32 + sc);
  };
  auto aptrl = [&](int ch) -> const ushort* {
    if (ch >= 4) return A2l + ((size_t)grow * HH + (ch - 4) * 32 + sc);
    return Al + ((size_t)(row0 + sr) * HH + ch * 32 + sc);
  };
  auto LE = [&](int ch) {
    const ushort* ph = aptr(ch); const ushort* pl = aptrl(ch);
    eA0 = *(const uint4*)(ph); eA1 = *(const uint4*)(ph + 8);
    eA2 = *(const uint4*)(pl); eA3 = *(const uint4*)(pl + 8);
    const size_t off = (size_t)sr * 256 + ch * 32 + sc;
    eB0 = *(const uint4*)(Bh + off); eB1 = *(const uint4*)(Bh + off + 8);
    eB2 = *(const uint4*)(Bl + off); eB3 = *(const uint4*)(Bl + off + 8);
  };
  auto LO = [&](int ch) {
    const ushort* ph = aptr(ch); const ushort* pl = aptrl(ch);
    oA0 = *(const uint4*)(ph); oA1 = *(const uint4*)(ph + 8);
    oA2 = *(const uint4*)(pl); oA3 = *(const uint4*)(pl + 8);
    const size_t off = (size_t)sr * 256 + ch * 32 + sc;
    oB0 = *(const uint4*)(Bh + off); oB1 = *(const uint4*)(Bh + off + 8);
    oB2 = *(const uint4*)(Bl + off); oB3 = *(const uint4*)(Bl + off + 8);
  };
  auto STAGE = [&](uint4 a0, uint4 a1, uint4 a2, uint4 a3,
                   uint4 b0, uint4 b1, uint4 b2, uint4 b3) {
    *(uint4*)&Ash[sr * LDP + sc]     = a0;
    *(uint4*)&Ash[sr * LDP + sc + 8] = a1;
    *(uint4*)&Asl[sr * LDP + sc]     = a2;
    *(uint4*)&Asl[sr * LDP + sc + 8] = a3;
    *(uint4*)&Bsh[sr * LDP + sc]     = b0;
    *(uint4*)&Bsh[sr * LDP + sc + 8] = b1;
    *(uint4*)&Bsl[sr * LDP + sc]     = b2;
    *(uint4*)&Bsl[sr * LDP + sc + 8] = b3;
  };
  auto MFMA_STEP = [&]() {
    bhalf8 afh[4], afl[4], bfh[4], bfl[4];
#pragma unroll
    for (int i = 0; i < 4; ++i) {
      const int r = (wm + i * 16 + fr) * LDP + quad * 8;
      afh[i] = *(const bhalf8*)&Ash[r];
      afl[i] = *(const bhalf8*)&Asl[r];
    }
#pragma unroll
    for (int j = 0; j < 4; ++j) {
      const int r = (wn + j * 16 + fr) * LDP + quad * 8;
      bfh[j] = *(const bhalf8*)&Bsh[r];
      bfl[j] = *(const bhalf8*)&Bsl[r];
    }
#pragma unroll
    for (int i = 0; i < 4; ++i)
#pragma unroll
      for (int j = 0; j < 4; ++j) {
        acc[i][j] = __builtin_amdgcn_mfma_f32_16x16x32_bf16(afh[i], bfh[j], acc[i][j], 0, 0, 0);
        acc[i][j] = __builtin_amdgcn_mfma_f32_16x16x32_bf16(afl[i], bfh[j], acc[i][j], 0, 0, 0);
        acc[i][j] = __builtin_amdgcn_mfma_f32_16x16x32_bf16(afh[i], bfl[j], acc[i][j], 0, 0, 0);
      }
  };

  LE(0); LO(1);
#pragma unroll
  for (int chp = 0; chp < 4; ++chp) {
    // even chunk 2*chp: consume E, refill E with chunk 2*chp+2
    STAGE(eA0, eA1, eA2, eA3, eB0, eB1, eB2, eB3);
    __syncthreads();
    if (chp < 3) LE(2 * chp + 2);
    MFMA_STEP();
    __syncthreads();
    // odd chunk 2*chp+1: consume O, refill O with chunk 2*chp+3
    STAGE(oA0, oA1, oA2, oA3, oB0, oB1, oB2, oB3);
    __syncthreads();
    if (chp < 3) LO(2 * chp + 3);
    MFMA_STEP();
    __syncthreads();
  }

  // ---- epilogue: relu + bias, uf write, BN stats ----
  const int nj[4] = {wn + fr, wn + 16 + fr, wn + 32 + fr, wn + 48 + fr};
  float bb[4];
#pragma unroll
  for (int j = 0; j < 4; ++j) bb[j] = bias[nj[j]];
  float psum[4] = {0.f, 0.f, 0.f, 0.f}, psq[4] = {0.f, 0.f, 0.f, 0.f};
#pragma unroll
  for (int i = 0; i < 4; ++i)
#pragma unroll
    for (int r = 0; r < 4; ++r) {
      const int m = row0 + wm + i * 16 + quad * 4 + r;
      const size_t base = (size_t)m * HH;
#pragma unroll
      for (int j = 0; j < 4; ++j) {
        float o = fmaxf(acc[i][j][r] + bb[j], 0.f);
        Cf[base + nj[j]] = o;
        psum[j] += o; psq[j] += o * o;
      }
    }
  float* ssum = (float*)Ash;      // dead past last barrier
  float* ssq = ssum + HH;
  if (tid < HH) { ssum[tid] = 0.f; ssq[tid] = 0.f; }
  __syncthreads();
#pragma unroll
  for (int j = 0; j < 4; ++j) {
    atomicAdd(&ssum[nj[j]], psum[j]);
    atomicAdd(&ssq[nj[j]], psq[j]);
  }
  __syncthreads();
  if (tid < HH) {
    unsafeAtomicAdd(&stats[tid], ssum[tid]);
    unsafeAtomicAdd(&stats[HH + tid], ssq[tid]);
  }
}

// ---------------------------------------------------------------------------
// Init GEMM (MODE 0): verified LDS-staged structure + T14 issue-early
// prefetch + 3 blocks/CU.
// ---------------------------------------------------------------------------
__launch_bounds__(256, 3)
__global__ void mgemm0_k(const float* __restrict__ Afp,
                         const ushort* __restrict__ Bh, const ushort* __restrict__ Bl,
                         float* __restrict__ Cf,
                         const int* __restrict__ idc, const float* __restrict__ log_probs,
                         const int* __restrict__ root_local, const float* __restrict__ vl,
                         const float* __restrict__ c0v, const float* __restrict__ rev) {
  constexpr int LDP = 40;
  __shared__ __align__(16) ushort Ash[128 * LDP];
  __shared__ __align__(16) ushort Asl[128 * LDP];
  __shared__ __align__(16) ushort Bsh[128 * LDP];
  __shared__ __align__(16) ushort Bsl[128 * LDP];
  const int tid = threadIdx.x;
  const int row0 = blockIdx.x * 128;
  const int lane = tid & 63, wv = tid >> 6;
  const int wm = (wv >> 1) * 64, wn = (wv & 1) * 64;
  const int fr = lane & 15, quad = lane >> 4;
  const int sr = tid >> 1;
  const int sc = (tid & 1) * 16;
  const int arow = idc[row0 + sr];   // hoisted gather row

  f32x4 acc[4][4];
#pragma unroll
  for (int i = 0; i < 4; ++i)
#pragma unroll
    for (int j = 0; j < 4; ++j) acc[i][j] = (f32x4){0.f, 0.f, 0.f, 0.f};

  float4 pf0, pf1, pf2, pf3;
  uint4  pb0, pb1, pb2, pb3;
  auto LA = [&](int ch) {
    const float* src = Afp + (size_t)arow * HH + ch * 32 + sc;
    pf0 = *(const float4*)(src);     pf1 = *(const float4*)(src + 4);
    pf2 = *(const float4*)(src + 8); pf3 = *(const float4*)(src + 12);
  };
  auto LB = [&](int ch) {
    const size_t off = (size_t)sr * HH + ch * 32 + sc;
    pb0 = *(const uint4*)(Bh + off); pb1 = *(const uint4*)(Bh + off + 8);
    pb2 = *(const uint4*)(Bl + off); pb3 = *(const uint4*)(Bl + off + 8);
  };

  LA(0); LB(0);
#pragma unroll
  for (int ch = 0; ch < 4; ++ch) {
    {
      float fv[16];
      *(float4*)&fv[0]  = pf0; *(float4*)&fv[4]  = pf1;
      *(float4*)&fv[8]  = pf2; *(float4*)&fv[12] = pf3;
      ushort hi[16], lo[16];
#pragma unroll
      for (int e = 0; e < 16; ++e) fsplit(fv[e], hi[e], lo[e]);
      *(uint4*)&Ash[sr * LDP + sc]     = *(uint4*)&hi[0];
      *(uint4*)&Ash[sr * LDP + sc + 8] = *(uint4*)&hi[8];
      *(uint4*)&Asl[sr * LDP + sc]     = *(uint4*)&lo[0];
      *(uint4*)&Asl[sr * LDP + sc + 8] = *(uint4*)&lo[8];
    }
    *(uint4*)&Bsh[sr * LDP + sc]     = pb0;
    *(uint4*)&Bsh[sr * LDP + sc + 8] = pb1;
    *(uint4*)&Bsl[sr * LDP + sc]     = pb2;
    *(uint4*)&Bsl[sr * LDP + sc + 8] = pb3;
    __syncthreads();
    if (ch < 3) { LA(ch + 1); LB(ch + 1); }
    bhalf8 afh[4], afl[4], bfh[4], bfl[4];
#pragma unroll
    for (int i = 0; i < 4; ++i) {
      const int r = (wm + i * 16 + fr) * LDP + quad * 8;
      afh[i] = *(const bhalf8*)&Ash[r];
      afl[i] = *(const bhalf8*)&Asl[r];
    }
#pragma unroll
    for (int j = 0; j < 4; ++j) {
      const int r = (wn + j * 16 + fr) * LDP + quad * 8;
      bfh[j] = *(const bhalf8*)&Bsh[r];
      bfl[j] = *(const bhalf8*)&Bsl[r];
    }
#pragma unroll
    for (int i = 0; i < 4; ++i)
#pragma unroll
      for (int j = 0; j < 4; ++j) {
        acc[i][j] = __builtin_amdgcn_mfma_f32_16x16x32_bf16(afh[i], bfh[j], acc[i][j], 0, 0, 0);
        acc[i][j] = __builtin_amdgcn_mfma_f32_16x16x32_bf16(afl[i], bfh[j], acc[i][j], 0, 0, 0);
        acc[i][j] = __builtin_amdgcn_mfma_f32_16x16x32_bf16(afh[i], bfl[j], acc[i][j], 0, 0, 0);
      }
    __syncthreads();
  }

  const int nj[4] = {wn + fr, wn + 16 + fr, wn + 32 + fr, wn + 48 + fr};
  float c0a[4], vla[4], re0[4], re1[4];
#pragma unroll
  for (int j = 0; j < 4; ++j) {
    c0a[j] = c0v[nj[j]]; vla[j] = vl[nj[j]];
    re0[j] = rev[nj[j]]; re1[j] = rev[HH + nj[j]];
  }
#pragma unroll
  for (int i = 0; i < 4; ++i)
#pragma unroll
    for (int r = 0; r < 4; ++r) {
      const int m = row0 + wm + i * 16 + quad * 4 + r;
      const int s = m >> 6;
      const float lp = log_probs[s];
      const bool isr = (m & 63) == root_local[s];
      const size_t base = (size_t)m * HH;
#pragma unroll
      for (int j = 0; j < 4; ++j)
        Cf[base + nj[j]] = acc[i][j][r] + c0a[j] + lp * vla[j] + (isr ? re1[j] : re0[j]);
    }
}

// ---------------------------------------------------------------------------
// Final BN apply with residual; coef computed inline from stats.
// ---------------------------------------------------------------------------
__launch_bounds__(256)
__global__ void bn_apply_k(const float* __restrict__ u, float* __restrict__ h,
                           const float* __restrict__ stats,
                           const float* __restrict__ gamma, const float* __restrict__ beta) {
  size_t i4 = (size_t)(blockIdx.x * 256 + threadIdx.x) * 4;
  int c = (int)(i4 & 127);
  const float invM = 1.0f / (float)SKK;
  float sc[4], sh[4];
#pragma unroll
  for (int e = 0; e < 4; ++e) {
    const float mu = stats[c + e] * invM;
    const float var = fmaf(-mu, mu, stats[HH + c + e] * invM);
    const float s = rsqrtf(var + 1e-5f) * gamma[c + e];
    sc[e] = s; sh[e] = fmaf(-mu, s, beta[c + e]);
  }
  float4 uv = *(const float4*)(u + i4);
  float4 hv = *(const float4*)(h + i4);
  float4 o;
  o.x = fmaf(uv.x, sc[0], sh[0]) + hv.x;
  o.y = fmaf(uv.y, sc[1], sh[1]) + hv.y;
  o.z = fmaf(uv.z, sc[2], sh[2]) + hv.z;
  o.w = fmaf(uv.w, sc[3], sh[3]) + hv.w;
  *(float4*)(h + i4) = o;
}

// ---------------------------------------------------------------------------
extern "C" void kernel_launch(void* const* d_in, const int* in_sizes, int n_in,
                              void* d_out, int out_size, void* d_ws, size_t ws_size,
                              hipStream_t stream) {
  const float* x          = (const float*)d_in[0];
  const float* log_probs  = (const float*)d_in[1];
  const float* node_w     = (const float*)d_in[2];
  const float* node_b     = (const float*)d_in[3];
  const float* logp_w     = (const float*)d_in[4];
  const float* logp_b     = (const float*)d_in[5];
  const float* root_emb   = (const float*)d_in[6];
  const float* init_w     = (const float*)d_in[7];
  const float* init_b     = (const float*)d_in[8];
  const float* gin_eps    = (const float*)d_in[9];
  const float* w1         = (const float*)d_in[10];
  const float* b1         = (const float*)d_in[11];
  const float* w2         = (const float*)d_in[12];
  const float* b2         = (const float*)d_in[13];
  const float* mp2w       = (const float*)d_in[14];
  const float* mp2b       = (const float*)d_in[15];
  const float* gamma      = (const float*)d_in[16];
  const float* beta       = (const float*)d_in[17];
  const int*   nodes      = (const int*)d_in[18];
  const int*   root_local = (const int*)d_in[19];
  const int*   edge_idx   = (const int*)d_in[20];
  const int*   edge_ptr   = (const int*)d_in[21];
  float* h = (float*)d_out;   // fp32 residual stream lives in d_out

  // ---- workspace carve ----
  char* wp = (char*)d_ws;
  auto take = [&](size_t bytes) { char* p = wp; wp += (bytes + 255) & ~(size_t)255; return p; };
  ushort* zh    = (ushort*)take((size_t)SKK * HH * 2);   // 32 MB
  ushort* zl    = (ushort*)take((size_t)SKK * HH * 2);
  float*  uf    = (float*)take((size_t)SKK * HH * 4);    // 64 MB
  ushort* xah   = (ushort*)take((size_t)NN * HH * 2);
  ushort* xal   = (ushort*)take((size_t)NN * HH * 2);
  ushort* Mth   = (ushort*)take((size_t)HH * HH * 2);
  ushort* Mtl   = (ushort*)take((size_t)HH * HH * 2);
  ushort* w1th  = (ushort*)take((size_t)LLAY * HH * HH * 2);
  ushort* w1tl  = (ushort*)take((size_t)LLAY * HH * HH * 2);
  ushort* w2th  = (ushort*)take((size_t)LLAY * HH * HH * 2);
  ushort* w2tl  = (ushort*)take((size_t)LLAY * HH * HH * 2);
  ushort* mp2th = (ushort*)take((size_t)LLAY * HH * 256 * 2);
  ushort* mp2tl = (ushort*)take((size_t)LLAY * HH * 256 * 2);
  float* vl       = (float*)take(HH * 4);
  float* c0v      = (float*)take(HH * 4);
  float* rev      = (float*)take(2 * HH * 4);
  float* bn_stats = (float*)take(LLAY * 2 * HH * 4);
  int*   cnti     = (int*)take((size_t)NN * 4);
  int*   excl     = (int*)take((size_t)NBLK * 256 * 4);
  int*   bsum     = (int*)take(256 * 4);
  int*   boff     = (int*)take(256 * 4);
  int*   node_ptr = (int*)take((size_t)(NN + 1) * 4);
  int*   cur      = (int*)take((size_t)NN * 4);
  int*   rowlist  = (int*)take((size_t)SKK * 4);
  int*   row_ptr  = (int*)take((size_t)(SKK + 1) * 4);
  int*   ssrc     = (int*)take((size_t)EE * 4);

  // ---- prologue ----
  hipMemsetAsync(cnti, 0, (size_t)NN * 4, stream);
  hipMemsetAsync(cur, 0, (size_t)NN * 4, stream);
  hipMemsetAsync(bn_stats, 0, LLAY * 2 * HH * 4, stream);
  fold_M_k<<<HH, HH, 0, stream>>>(node_w, init_w, Mth, Mtl);
  fold_vec_k<<<1, HH, 0, stream>>>(init_w, logp_w, node_b, logp_b, init_b, root_emb,
                                   vl, c0v, rev);
  wconv_k<<<2560, HH, 0, stream>>>(w1, w2, mp2w, w1th, w1tl, w2th, w2tl, mp2th, mp2tl);
  count_k<<<SKK / 256, 256, 0, stream>>>(nodes, cnti);
  scan1_k<<<NBLK, 256, 0, stream>>>(cnti, excl, bsum);
  scan2_k<<<1, 256, 0, stream>>>(bsum, boff);
  scan3_k<<<NBLK, 256, 0, stream>>>(excl, boff, node_ptr);
  fill_rows_k<<<SKK / 256, 256, 0, stream>>>(nodes, node_ptr, cur, rowlist);
  presort_k<<<SS, 256, 0, stream>>>(edge_idx, edge_idx + EE, edge_ptr, row_ptr, ssrc);

  // initial h (fp32, in d_out)
  mgemm0_k<<<SKK / 128, 256, 0, stream>>>(x, Mth, Mtl, h,
                                          nodes, log_probs, root_local, vl, c0v, rev);

  for (int l = 0; l < LLAY; ++l) {
    if (l == 0) {
      gin_mega_k<true><<<SS, 256, 0, stream>>>(h, nullptr, nullptr, nullptr, nullptr,
                                               row_ptr, ssrc, gin_eps, l,
                                               w1th + (size_t)l * HH * HH,
                                               w1tl + (size_t)l * HH * HH,
                                               w2th + (size_t)l * HH * HH,
                                               w2tl + (size_t)l * HH * HH,
                                               b1 + l * HH, b2 + l * HH, zh, zl);
    } else {
      gin_mega_k<false><<<SS, 256, 0, stream>>>(h, uf, bn_stats + (l - 1) * 2 * HH,
                                                gamma + (l - 1) * HH, beta + (l - 1) * HH,
                                                row_ptr, ssrc, gin_eps, l,
                                                w1th + (size_t)l * HH * HH,
                                                w1tl + (size_t)l * HH * HH,
                                                w2th + (size_t)l * HH * HH,
                                                w2tl + (size_t)l * HH * HH,
                                                b1 + l * HH, b2 + l * HH, zh, zl);
    }
    scatter_mean_k<<<(NN + 15) / 16, 256, 0, stream>>>(zh, zl, node_ptr, rowlist, xah, xal);
    mp2_k<<<SKK / 128, 256, 0, stream>>>(zh, zl, xah, xal,
                                         mp2th + (size_t)l * HH * 256,
                                         mp2tl + (size_t)l * HH * 256,
                                         mp2b + l * HH, uf, nodes,
                                         bn_stats + l * 2 * HH);
  }
  // final BN+residual apply (layer 4) -> h in d_out
  bn_apply_k<<<(SKK * HH / 4) / 256, 256, 0, stream>>>(uf, h, bn_stats + 4 * 2 * HH,
                                                       gamma + 4 * HH, beta + 4 * HH);
}

// Round 13
// 977.888 us; speedup vs baseline: 1.0918x; 1.0029x over previous
//
#include <hip/hip_runtime.h>
#include <cstdint>

#define NN   50000
#define SS   2048
#define KSUB 64
#define HH   128
#define EE   (SS * 256)
#define SKK  (SS * KSUB)    // 131072
#define LLAY 5
#define NBLK 196            // ceil(NN/256)

typedef __attribute__((ext_vector_type(8))) short bhalf8;
typedef __attribute__((ext_vector_type(4))) float f32x4;
typedef __attribute__((ext_vector_type(4))) _Float16 half4;

__device__ __forceinline__ ushort f2b(float f) {
  uint u = __builtin_bit_cast(uint, f);
  uint r = (u + 0x7FFFu + ((u >> 16) & 1u)) >> 16;
  return (ushort)r;
}
__device__ __forceinline__ float b2f(ushort u) {
  uint v = ((uint)u) << 16;
  return __builtin_bit_cast(float, v);
}
// split fp32 -> (hi, lo) bf16 pair; hi + lo ~= f with ~2^-18 residual
__device__ __forceinline__ void fsplit(float f, ushort& hi, ushort& lo) {
  hi = f2b(f);
  lo = f2b(f - b2f(hi));
}
// byte offset into a [64][128]-short LDS tile, T2 XOR swizzle (row stride 256B)
__device__ __forceinline__ int zoff(int row, int col) {
  return row * 256 + (((col * 2) & 255) ^ ((row & 7) << 4));
}

// ---------------------------------------------------------------------------
// Fold node_proj through init_proj; emit split bf16 B^T layout [n][c]
// ---------------------------------------------------------------------------
__global__ void fold_M_k(const float* __restrict__ Wn, const float* __restrict__ Wi,
                         ushort* __restrict__ Mth, ushort* __restrict__ Mtl) {
  int c = blockIdx.x, n = threadIdx.x;
  float s = 0.f;
  for (int k = 0; k < HH; ++k) s = fmaf(Wn[c * HH + k], Wi[k * HH + n], s);
  ushort hi, lo; fsplit(s, hi, lo);
  Mth[n * HH + c] = hi; Mtl[n * HH + c] = lo;
}

__global__ void fold_vec_k(const float* __restrict__ Wi, const float* __restrict__ wl,
                           const float* __restrict__ bnb, const float* __restrict__ blb,
                           const float* __restrict__ bi, const float* __restrict__ remb,
                           float* __restrict__ vl, float* __restrict__ c0,
                           float* __restrict__ rev) {
  int n = threadIdx.x;
  float svl = 0.f, sc0 = bi[n], r0 = 0.f, r1 = 0.f;
  for (int k = 0; k < HH; ++k) {
    svl = fmaf(wl[k], Wi[(HH + k) * HH + n], svl);
    sc0 = fmaf(bnb[k], Wi[k * HH + n], sc0);
    sc0 = fmaf(blb[k], Wi[(HH + k) * HH + n], sc0);
    r0  = fmaf(remb[k],      Wi[(2 * HH + k) * HH + n], r0);
    r1  = fmaf(remb[HH + k], Wi[(2 * HH + k) * HH + n], r1);
  }
  vl[n] = svl; c0[n] = sc0; rev[n] = r0; rev[HH + n] = r1;
}

// ---------------------------------------------------------------------------
// Transpose+convert all layer weights to split bf16 B^T layout (one launch).
// ---------------------------------------------------------------------------
__global__ void wconv_k(const float* __restrict__ w1, const float* __restrict__ w2,
                        const float* __restrict__ mp2w,
                        ushort* __restrict__ w1th, ushort* __restrict__ w1tl,
                        ushort* __restrict__ w2th, ushort* __restrict__ w2tl,
                        ushort* __restrict__ mp2th, ushort* __restrict__ mp2tl) {
  int b = blockIdx.x, n = threadIdx.x;
  ushort hi, lo;
  if (b < 640) {
    int l = b >> 7, k = b & 127;
    fsplit(w1[((size_t)l * HH + k) * HH + n], hi, lo);
    w1th[((size_t)l * HH + n) * HH + k] = hi;
    w1tl[((size_t)l * HH + n) * HH + k] = lo;
  } else if (b < 1280) {
    int bb = b - 640; int l = bb >> 7, k = bb & 127;
    fsplit(w2[((size_t)l * HH + k) * HH + n], hi, lo);
    w2th[((size_t)l * HH + n) * HH + k] = hi;
    w2tl[((size_t)l * HH + n) * HH + k] = lo;
  } else {
    int bb = b - 1280; int l = bb >> 8, k = bb & 255;
    fsplit(mp2w[((size_t)l * 256 + k) * HH + n], hi, lo);
    mp2th[((size_t)l * HH + n) * 256 + k] = hi;
    mp2tl[((size_t)l * HH + n) * 256 + k] = lo;
  }
}

// ---------------------------------------------------------------------------
// Node-CSR construction: count -> exclusive scan -> fill
// ---------------------------------------------------------------------------
__global__ void count_k(const int* __restrict__ idc, int* __restrict__ cnt) {
  int i = blockIdx.x * 256 + threadIdx.x;
  if (i < SKK) atomicAdd(&cnt[idc[i]], 1);
}

__global__ void scan1_k(const int* __restrict__ cnt, int* __restrict__ excl,
                        int* __restrict__ bsum) {
  __shared__ int sh[256];
  const int tid = threadIdx.x;
  const int i = blockIdx.x * 256 + tid;
  int v = (i < NN) ? cnt[i] : 0;
  sh[tid] = v;
  __syncthreads();
#pragma unroll
  for (int off = 1; off < 256; off <<= 1) {
    int t = (tid >= off) ? sh[tid - off] : 0;
    __syncthreads();
    sh[tid] += t;
    __syncthreads();
  }
  excl[i] = sh[tid] - v;
  if (tid == 255) bsum[blockIdx.x] = sh[tid];
}

__global__ void scan2_k(int* __restrict__ bsum, int* __restrict__ boff) {
  __shared__ int sh[256];
  const int tid = threadIdx.x;
  int v = (tid < NBLK) ? bsum[tid] : 0;
  sh[tid] = v;
  __syncthreads();
#pragma unroll
  for (int off = 1; off < 256; off <<= 1) {
    int t = (tid >= off) ? sh[tid - off] : 0;
    __syncthreads();
    sh[tid] += t;
    __syncthreads();
  }
  boff[tid] = sh[tid] - v;
}

__global__ void scan3_k(const int* __restrict__ excl, const int* __restrict__ boff,
                        int* __restrict__ node_ptr) {
  int i = blockIdx.x * 256 + threadIdx.x;
  if (i < NN) node_ptr[i] = excl[i] + boff[blockIdx.x];
  if (i == 0) node_ptr[NN] = SKK;
}

__global__ void fill_rows_k(const int* __restrict__ idc, const int* __restrict__ node_ptr,
                            int* __restrict__ cur, int* __restrict__ rowlist) {
  int i = blockIdx.x * 256 + threadIdx.x;
  if (i < SKK) {
    int id = idc[i];
    int pos = atomicAdd(&cur[id], 1);
    rowlist[node_ptr[id] + pos] = i;
  }
}

// ---------------------------------------------------------------------------
// Cross-subgraph scatter-mean as a GATHER. Vectorized: 16 lanes/node,
// 16B uint4 loads per lane, 16 nodes/block.
// ---------------------------------------------------------------------------
__launch_bounds__(256)
__global__ void scatter_mean_k(const ushort* __restrict__ zh, const ushort* __restrict__ zl,
                               const int* __restrict__ node_ptr,
                               const int* __restrict__ rowlist,
                               ushort* __restrict__ xah, ushort* __restrict__ xal) {
  const int tid = threadIdx.x;
  const int n = blockIdx.x * 16 + (tid >> 4);
  if (n >= NN) return;
  const int c8 = (tid & 15) * 8;
  const int p0 = node_ptr[n], p1 = node_ptr[n + 1];
  float s[8] = {0.f, 0.f, 0.f, 0.f, 0.f, 0.f, 0.f, 0.f};
  for (int p = p0; p < p1; ++p) {
    const size_t off = (size_t)rowlist[p] * HH + c8;
    uint4 vh = *(const uint4*)(zh + off);
    uint4 vl = *(const uint4*)(zl + off);
    const uint hw[4] = {vh.x, vh.y, vh.z, vh.w};
    const uint lw[4] = {vl.x, vl.y, vl.z, vl.w};
#pragma unroll
    for (int k = 0; k < 4; ++k) {
      s[2 * k]     += b2f((ushort)hw[k])        + b2f((ushort)lw[k]);
      s[2 * k + 1] += b2f((ushort)(hw[k] >> 16)) + b2f((ushort)(lw[k] >> 16));
    }
  }
  const float inv = 1.0f / (float)max(p1 - p0, 1);
  ushort hi[8], lo[8];
#pragma unroll
  for (int k = 0; k < 8; ++k) fsplit(s[k] * inv, hi[k], lo[k]);
  *(uint4*)(xah + (size_t)n * HH + c8) = *(uint4*)hi;
  *(uint4*)(xal + (size_t)n * HH + c8) = *(uint4*)lo;
}

// ---------------------------------------------------------------------------
// Per-subgraph counting sort of edges by dst -> CSR
// ---------------------------------------------------------------------------
__launch_bounds__(256)
__global__ void presort_k(const int* __restrict__ e_src, const int* __restrict__ e_dst,
                          const int* __restrict__ edge_ptr, int* __restrict__ row_ptr,
                          int* __restrict__ ssrc) {
  __shared__ int cnt[KSUB];
  __shared__ int base[KSUB];
  __shared__ int cur[KSUB];
  const int s = blockIdx.x, tid = threadIdx.x;
  const int p0 = edge_ptr[s], p1 = edge_ptr[s + 1];
  if (tid < KSUB) cnt[tid] = 0;
  __syncthreads();
  for (int e = p0 + tid; e < p1; e += 256) atomicAdd(&cnt[e_dst[e]], 1);
  __syncthreads();
  if (tid == 0) {
    int a = 0;
    for (int d = 0; d < KSUB; ++d) { base[d] = a; a += cnt[d]; }
  }
  __syncthreads();
  if (tid < KSUB) { row_ptr[s * KSUB + tid] = p0 + base[tid]; cur[tid] = base[tid]; }
  if (s == 0 && tid == 0) row_ptr[SS * KSUB] = edge_ptr[SS];
  __syncthreads();
  for (int e = p0 + tid; e < p1; e += 256) {
    int d = e_dst[e];
    int pos = atomicAdd(&cur[d], 1);
    ssrc[p0 + pos] = e_src[e];
  }
}

// ---------------------------------------------------------------------------
// MEGA kernel: per subgraph (64 rows):
//   phase A: h_new = bn(u_fp16) + h_old (residual) [skip BN if FIRST];
//            BN coef computed INLINE from stats; write h_new, keep fp32 in LDS
//            + stage this subgraph's 256 ssrc entries into LDS (1 KB)
//   phase B: GIN aggregation (interleaved channel mapping, ssrc from LDS)
//   phase C: split z_agg -> swizzled bf16 LDS tile Z (aliases hl)
//   MLP1:    t = relu(Z @ W1 + b1) -> swizzled LDS tile T (aliases Z)
//   MLP2:    z = T @ W2 + b2 -> staged into dead Z/T LDS tiles (swizzled),
//            then COALESCED copy-out (4x dwordx4/thread/buffer)
// ---------------------------------------------------------------------------
template <bool FIRST>
__launch_bounds__(256, 4)
__global__ void gin_mega_k(float* __restrict__ h, const _Float16* __restrict__ uh,
                           const float* __restrict__ stats,
                           const float* __restrict__ gamma, const float* __restrict__ beta,
                           const int* __restrict__ row_ptr, const int* __restrict__ ssrc,
                           const float* __restrict__ gin_eps, const int layer,
                           const ushort* __restrict__ B1h, const ushort* __restrict__ B1l,
                           const ushort* __restrict__ B2h, const ushort* __restrict__ B2l,
                           const float* __restrict__ bias1, const float* __restrict__ bias2,
                           ushort* __restrict__ zh, ushort* __restrict__ zl) {
  constexpr int LDH = 132;
  __shared__ __align__(16) char smem[KSUB * LDH * 4];   // 33792 B, phase-aliased
  __shared__ int ssrc_lds[256];                          // 1 KB edge-source cache
  float*  hl = (float*)smem;                 // [64][132] fp32 (phases A,B)
  ushort* Zh = (ushort*)smem;                // [64][128] swizzled (phases C..out)
  ushort* Zl = (ushort*)(smem + KSUB * HH * 2);
  const int s = blockIdx.x, tid = threadIdx.x;
  const size_t base = (size_t)s * KSUB * HH;

  // ---- stage ssrc (coalesced, 1 iteration for ES=256) ----
  const int e_start = row_ptr[s * KSUB];
  {
    const int e_end = row_ptr[s * KSUB + KSUB];
    for (int e = e_start + tid; e < e_end; e += 256)
      ssrc_lds[e - e_start] = ssrc[e];
  }

  // ---- phase A (BN coef inline; c constant across 'it' since 1024 % 128 == 0) ----
  float csc[4], csh[4];
  const int cb = (tid * 4) & 127;
  if constexpr (!FIRST) {
    const float invM = 1.0f / (float)SKK;
#pragma unroll
    for (int e = 0; e < 4; ++e) {
      const float mu = stats[cb + e] * invM;
      const float var = fmaf(-mu, mu, stats[HH + cb + e] * invM);
      const float sc = rsqrtf(var + 1e-5f) * gamma[cb + e];
      csc[e] = sc; csh[e] = fmaf(-mu, sc, beta[cb + e]);
    }
  }
#pragma unroll
  for (int it = 0; it < 8; ++it) {
    const int idx = it * 1024 + tid * 4;
    const int m = idx >> 7, c = idx & 127;
    float4 hv = *(const float4*)&h[base + idx];
    if constexpr (!FIRST) {
      half4 u4 = *(const half4*)&uh[base + idx];
      hv.x += fmaf((float)u4.x, csc[0], csh[0]);
      hv.y += fmaf((float)u4.y, csc[1], csh[1]);
      hv.z += fmaf((float)u4.z, csc[2], csh[2]);
      hv.w += fmaf((float)u4.w, csc[3], csh[3]);
      *(float4*)&h[base + idx] = hv;
    }
    *(float4*)&hl[m * LDH + c] = hv;
  }
  __syncthreads();

  // ---- phase B: aggregation (interleaved channel mapping; ssrc from LDS) ----
  const float ep1 = 1.0f + gin_eps[layer];
  const int d = tid >> 2, q4 = (tid & 3) * 4;   // cols q4 + 16*j + k
  const int g = s * KSUB + d;
  const int e0 = row_ptr[g], e1 = row_ptr[g + 1];
  float a[32];
  {
    const float* hp0 = &hl[d * LDH + q4];
#pragma unroll
    for (int j = 0; j < 8; ++j) {
      float4 v = *(const float4*)(hp0 + 16 * j);
      a[4 * j + 0] = ep1 * v.x; a[4 * j + 1] = ep1 * v.y;
      a[4 * j + 2] = ep1 * v.z; a[4 * j + 3] = ep1 * v.w;
    }
    for (int e = e0; e < e1; ++e) {
      const float* hp = &hl[ssrc_lds[e - e_start] * LDH + q4];
#pragma unroll
      for (int j = 0; j < 8; ++j) {
        float4 v = *(const float4*)(hp + 16 * j);
        a[4 * j + 0] += v.x; a[4 * j + 1] += v.y;
        a[4 * j + 2] += v.z; a[4 * j + 3] += v.w;
      }
    }
  }
  __syncthreads();          // all hl reads done (Z aliases hl)

  // ---- phase C: split z_agg into swizzled LDS tile (8B writes) ----
#pragma unroll
  for (int j = 0; j < 8; ++j) {
    ushort th[4], tl[4];
#pragma unroll
    for (int k = 0; k < 4; ++k) fsplit(a[4 * j + k], th[k], tl[k]);
    const int o = zoff(d, q4 + 16 * j);
    *(uint2*)((char*)Zh + o) = *(uint2*)th;
    *(uint2*)((char*)Zl + o) = *(uint2*)tl;
  }
  __syncthreads();

  // ---- MLP GEMMs ----
  const int lane = tid & 63, wv = tid >> 6;
  const int fr = lane & 15, quad = lane >> 4;
  const int nj0 = wv * 32 + fr, nj1 = nj0 + 16;

  f32x4 acc[4][2];
#pragma unroll
  for (int i = 0; i < 4; ++i) { acc[i][0] = (f32x4){0,0,0,0}; acc[i][1] = (f32x4){0,0,0,0}; }

  // MLP1: t = relu(Z @ W1 + b1)
#pragma unroll
  for (int ch = 0; ch < 4; ++ch) {
    bhalf8 afh[4], afl[4], bfh[2], bfl[2];
#pragma unroll
    for (int i = 0; i < 4; ++i) {
      const int o = zoff(i * 16 + fr, ch * 32 + quad * 8);
      afh[i] = *(const bhalf8*)((const char*)Zh + o);
      afl[i] = *(const bhalf8*)((const char*)Zl + o);
    }
#pragma unroll
    for (int j = 0; j < 2; ++j) {
      const size_t off = (size_t)(wv * 32 + j * 16 + fr) * HH + ch * 32 + quad * 8;
      bfh[j] = *(const bhalf8*)(B1h + off);
      bfl[j] = *(const bhalf8*)(B1l + off);
    }
#pragma unroll
    for (int i = 0; i < 4; ++i)
#pragma unroll
      for (int j = 0; j < 2; ++j) {
        acc[i][j] = __builtin_amdgcn_mfma_f32_16x16x32_bf16(afh[i], bfh[j], acc[i][j], 0, 0, 0);
        acc[i][j] = __builtin_amdgcn_mfma_f32_16x16x32_bf16(afl[i], bfh[j], acc[i][j], 0, 0, 0);
        acc[i][j] = __builtin_amdgcn_mfma_f32_16x16x32_bf16(afh[i], bfl[j], acc[i][j], 0, 0, 0);
      }
  }
  __syncthreads();          // all Z reads done (T aliases Z)

  // epilogue 1: T = relu(acc + b1), split, into swizzled LDS
  {
    const float b10 = bias1[nj0], b11 = bias1[nj1];
#pragma unroll
    for (int i = 0; i < 4; ++i)
#pragma unroll
      for (int r = 0; r < 4; ++r) {
        const int row = i * 16 + quad * 4 + r;
        const float o0 = fmaxf(acc[i][0][r] + b10, 0.f);
        const float o1 = fmaxf(acc[i][1][r] + b11, 0.f);
        ushort h0, l0, h1, l1; fsplit(o0, h0, l0); fsplit(o1, h1, l1);
        *(ushort*)((char*)Zh + zoff(row, nj0)) = h0;
        *(ushort*)((char*)Zl + zoff(row, nj0)) = l0;
        *(ushort*)((char*)Zh + zoff(row, nj1)) = h1;
        *(ushort*)((char*)Zl + zoff(row, nj1)) = l1;
      }
  }
  __syncthreads();

  // MLP2: z = T @ W2 + b2
#pragma unroll
  for (int i = 0; i < 4; ++i) { acc[i][0] = (f32x4){0,0,0,0}; acc[i][1] = (f32x4){0,0,0,0}; }
#pragma unroll
  for (int ch = 0; ch < 4; ++ch) {
    bhalf8 afh[4], afl[4], bfh[2], bfl[2];
#pragma unroll
    for (int i = 0; i < 4; ++i) {
      const int o = zoff(i * 16 + fr, ch * 32 + quad * 8);
      afh[i] = *(const bhalf8*)((const char*)Zh + o);
      afl[i] = *(const bhalf8*)((const char*)Zl + o);
    }
#pragma unroll
    for (int j = 0; j < 2; ++j) {
      const size_t off = (size_t)(wv * 32 + j * 16 + fr) * HH + ch * 32 + quad * 8;
      bfh[j] = *(const bhalf8*)(B2h + off);
      bfl[j] = *(const bhalf8*)(B2l + off);
    }
#pragma unroll
    for (int i = 0; i < 4; ++i)
#pragma unroll
      for (int j = 0; j < 2; ++j) {
        acc[i][j] = __builtin_amdgcn_mfma_f32_16x16x32_bf16(afh[i], bfh[j], acc[i][j], 0, 0, 0);
        acc[i][j] = __builtin_amdgcn_mfma_f32_16x16x32_bf16(afl[i], bfh[j], acc[i][j], 0, 0, 0);
        acc[i][j] = __builtin_amdgcn_mfma_f32_16x16x32_bf16(afh[i], bfl[j], acc[i][j], 0, 0, 0);
      }
  }
  __syncthreads();          // all T reads done — Z/T tiles now dead, reuse for z

  // epilogue 2a: split z into swizzled LDS (same pattern as epilogue 1)
  {
    const float b20 = bias2[nj0], b21 = bias2[nj1];
#pragma unroll
    for (int i = 0; i < 4; ++i)
#pragma unroll
      for (int r = 0; r < 4; ++r) {
        const int row = i * 16 + quad * 4 + r;
        const float o0 = acc[i][0][r] + b20;
        const float o1 = acc[i][1][r] + b21;
        ushort h0, l0, h1, l1; fsplit(o0, h0, l0); fsplit(o1, h1, l1);
        *(ushort*)((char*)Zh + zoff(row, nj0)) = h0;
        *(ushort*)((char*)Zl + zoff(row, nj0)) = l0;
        *(ushort*)((char*)Zh + zoff(row, nj1)) = h1;
        *(ushort*)((char*)Zl + zoff(row, nj1)) = l1;
      }
  }
  __syncthreads();

  // epilogue 2b: coalesced copy-out. Thread t, iter k: 16B at global ushort
  // index t*8 + k*2048 -> lanes contiguous (1KB per wave-instruction).
#pragma unroll
  for (int k = 0; k < 4; ++k) {
    const int gidx = tid * 8 + k * 2048;         // ushort index in [0, 8192)
    const int row = gidx >> 7;
    const int col = gidx & 127;
    const int o = zoff(row, col);
    *(uint4*)(zh + base + gidx) = *(const uint4*)((const char*)Zh + o);
    *(uint4*)(zl + base + gidx) = *(const uint4*)((const char*)Zl + o);
  }
}

// ---------------------------------------------------------------------------
// MP-2 GEMM: verified 128-row LDS-staged structure + TWO-DEEP T14 prefetch.
// u output now stored as fp16 (halves the u round-trip HBM traffic; BN stats
// still accumulated from fp32 accumulators).
// ---------------------------------------------------------------------------
__launch_bounds__(256, 3)
__global__ void mp2_k(const ushort* __restrict__ Ah, const ushort* __restrict__ Al,
                      const ushort* __restrict__ A2h, const ushort* __restrict__ A2l,
                      const ushort* __restrict__ Bh, const ushort* __restrict__ Bl,
                      const float* __restrict__ bias, _Float16* __restrict__ Cf,
                      const int* __restrict__ idc, float* __restrict__ stats) {
  constexpr int LDP = 40;   // LDS row stride in shorts
  __shared__ __align__(16) ushort Ash[128 * LDP];
  __shared__ __align__(16) ushort Asl[128 * LDP];
  __shared__ __align__(16) ushort Bsh[128 * LDP];
  __shared__ __align__(16) ushort Bsl[128 * LDP];
  const int tid = threadIdx.x;
  const int row0 = blockIdx.x * 128;
  const int lane = tid & 63, wv = tid >> 6;
  const int wm = (wv >> 1) * 64, wn = (wv & 1) * 64;
  const int fr = lane & 15, quad = lane >> 4;
  const int sr = tid >> 1;            // staging row 0..127
  const int sc = (tid & 1) * 16;      // staging short-offset {0,16}
  const int grow = idc[row0 + sr];    // gather row for K-half 2 (hoisted)

  f32x4 acc[4][4];
#pragma unroll
  for (int i = 0; i < 4; ++i)
#pragma unroll
    for (int j = 0; j < 4; ++j) acc[i][j] = (f32x4){0.f, 0.f, 0.f, 0.f};

  // two named prefetch sets (E = even chunks, O = odd chunks)
  uint4 eA0, eA1, eA2, eA3, eB0, eB1, eB2, eB3;
  uint4 oA0, oA1, oA2, oA3, oB0, oB1, oB2, oB3;
  auto aptr = [&](int ch) -> const ushort* {
    if (ch >= 4) return A2h + ((size_t)grow * HH + (ch - 4) * 32 + sc);
    return Ah + ((size_t)(row0 + sr) * HH + ch * 32 + sc);
  };
  auto aptrl = [&](int ch) -> const ushort* {
    if (ch >= 4) return A2l + ((size_t)grow * HH + (ch - 4) * 32 + sc);
    return Al + ((size_t)(row0 + sr) * HH + ch * 32 + sc);
  };
  auto LE = [&](int ch) {
    const ushort* ph = aptr(ch); const ushort* pl = aptrl(ch);
    eA0 = *(const uint4*)(ph); eA1 = *(const uint4*)(ph + 8);
    eA2 = *(const uint4*)(pl); eA3 = *(const uint4*)(pl + 8);
    const size_t off = (size_t)sr * 256 + ch * 32 + sc;
    eB0 = *(const uint4*)(Bh + off); eB1 = *(const uint4*)(Bh + off + 8);
    eB2 = *(const uint4*)(Bl + off); eB3 = *(const uint4*)(Bl + off + 8);
  };
  auto LO = [&](int ch) {
    const ushort* ph = aptr(ch); const ushort* pl = aptrl(ch);
    oA0 = *(const uint4*)(ph); oA1 = *(const uint4*)(ph + 8);
    oA2 = *(const uint4*)(pl); oA3 = *(const uint4*)(pl + 8);
    const size_t off = (size_t)sr * 256 + ch * 32 + sc;
    oB0 = *(const uint4*)(Bh + off); oB1 = *(const uint4*)(Bh + off + 8);
    oB2 = *(const uint4*)(Bl + off); oB3 = *(const uint4*)(Bl + off + 8);
  };
  auto STAGE = [&](uint4 a0, uint4 a1, uint4 a2, uint4 a3,
                   uint4 b0, uint4 b1, uint4 b2, uint4 b3) {
    *(uint4*)&Ash[sr * LDP + sc]     = a0;
    *(uint4*)&Ash[sr * LDP + sc + 8] = a1;
    *(uint4*)&Asl[sr * LDP + sc]     = a2;
    *(uint4*)&Asl[sr * LDP + sc + 8] = a3;
    *(uint4*)&Bsh[sr * LDP + sc]     = b0;
    *(uint4*)&Bsh[sr * LDP + sc + 8] = b1;
    *(uint4*)&Bsl[sr * LDP + sc]     = b2;
    *(uint4*)&Bsl[sr * LDP + sc + 8] = b3;
  };
  auto MFMA_STEP = [&]() {
    bhalf8 afh[4], afl[4], bfh[4], bfl[4];
#pragma unroll
    for (int i = 0; i < 4; ++i) {
      const int r = (wm + i * 16 + fr) * LDP + quad * 8;
      afh[i] = *(const bhalf8*)&Ash[r];
      afl[i] = *(const bhalf8*)&Asl[r];
    }
#pragma unroll
    for (int j = 0; j < 4; ++j) {
      const int r = (wn + j * 16 + fr) * LDP + quad * 8;
      bfh[j] = *(const bhalf8*)&Bsh[r];
      bfl[j] = *(const bhalf8*)&Bsl[r];
    }
#pragma unroll
    for (int i = 0; i < 4; ++i)
#pragma unroll
      for (int j = 0; j < 4; ++j) {
        acc[i][j] = __builtin_amdgcn_mfma_f32_16x16x32_bf16(afh[i], bfh[j], acc[i][j], 0, 0, 0);
        acc[i][j] = __builtin_amdgcn_mfma_f32_16x16x32_bf16(afl[i], bfh[j], acc[i][j], 0, 0, 0);
        acc[i][j] = __builtin_amdgcn_mfma_f32_16x16x32_bf16(afh[i], bfl[j], acc[i][j], 0, 0, 0);
      }
  };

  LE(0); LO(1);
#pragma unroll
  for (int chp = 0; chp < 4; ++chp) {
    // even chunk 2*chp: consume E, refill E with chunk 2*chp+2
    STAGE(eA0, eA1, eA2, eA3, eB0, eB1, eB2, eB3);
    __syncthreads();
    if (chp < 3) LE(2 * chp + 2);
    MFMA_STEP();
    __syncthreads();
    // odd chunk 2*chp+1: consume O, refill O with chunk 2*chp+3
    STAGE(oA0, oA1, oA2, oA3, oB0, oB1, oB2, oB3);
    __syncthreads();
    if (chp < 3) LO(2 * chp + 3);
    MFMA_STEP();
    __syncthreads();
  }

  // ---- epilogue: relu + bias, fp16 u write, BN stats (from fp32) ----
  const int nj[4] = {wn + fr, wn + 16 + fr, wn + 32 + fr, wn + 48 + fr};
  float bb[4];
#pragma unroll
  for (int j = 0; j < 4; ++j) bb[j] = bias[nj[j]];
  float psum[4] = {0.f, 0.f, 0.f, 0.f}, psq[4] = {0.f, 0.f, 0.f, 0.f};
#pragma unroll
  for (int i = 0; i < 4; ++i)
#pragma unroll
    for (int r = 0; r < 4; ++r) {
      const int m = row0 + wm + i * 16 + quad * 4 + r;
      const size_t base = (size_t)m * HH;
#pragma unroll
      for (int j = 0; j < 4; ++j) {
        float o = fmaxf(acc[i][j][r] + bb[j], 0.f);
        Cf[base + nj[j]] = (_Float16)o;
        psum[j] += o; psq[j] += o * o;
      }
    }
  float* ssum = (float*)Ash;      // dead past last barrier
  float* ssq = ssum + HH;
  if (tid < HH) { ssum[tid] = 0.f; ssq[tid] = 0.f; }
  __syncthreads();
#pragma unroll
  for (int j = 0; j < 4; ++j) {
    atomicAdd(&ssum[nj[j]], psum[j]);
    atomicAdd(&ssq[nj[j]], psq[j]);
  }
  __syncthreads();
  if (tid < HH) {
    unsafeAtomicAdd(&stats[tid], ssum[tid]);
    unsafeAtomicAdd(&stats[HH + tid], ssq[tid]);
  }
}

// ---------------------------------------------------------------------------
// Init GEMM (MODE 0): verified LDS-staged structure + T14 issue-early
// prefetch + 3 blocks/CU.
// ---------------------------------------------------------------------------
__launch_bounds__(256, 3)
__global__ void mgemm0_k(const float* __restrict__ Afp,
                         const ushort* __restrict__ Bh, const ushort* __restrict__ Bl,
                         float* __restrict__ Cf,
                         const int* __restrict__ idc, const float* __restrict__ log_probs,
                         const int* __restrict__ root_local, const float* __restrict__ vl,
                         const float* __restrict__ c0v, const float* __restrict__ rev) {
  constexpr int LDP = 40;
  __shared__ __align__(16) ushort Ash[128 * LDP];
  __shared__ __align__(16) ushort Asl[128 * LDP];
  __shared__ __align__(16) ushort Bsh[128 * LDP];
  __shared__ __align__(16) ushort Bsl[128 * LDP];
  const int tid = threadIdx.x;
  const int row0 = blockIdx.x * 128;
  const int lane = tid & 63, wv = tid >> 6;
  const int wm = (wv >> 1) * 64, wn = (wv & 1) * 64;
  const int fr = lane & 15, quad = lane >> 4;
  const int sr = tid >> 1;
  const int sc = (tid & 1) * 16;
  const int arow = idc[row0 + sr];   // hoisted gather row

  f32x4 acc[4][4];
#pragma unroll
  for (int i = 0; i < 4; ++i)
#pragma unroll
    for (int j = 0; j < 4; ++j) acc[i][j] = (f32x4){0.f, 0.f, 0.f, 0.f};

  float4 pf0, pf1, pf2, pf3;
  uint4  pb0, pb1, pb2, pb3;
  auto LA = [&](int ch) {
    const float* src = Afp + (size_t)arow * HH + ch * 32 + sc;
    pf0 = *(const float4*)(src);     pf1 = *(const float4*)(src + 4);
    pf2 = *(const float4*)(src + 8); pf3 = *(const float4*)(src + 12);
  };
  auto LB = [&](int ch) {
    const size_t off = (size_t)sr * HH + ch * 32 + sc;
    pb0 = *(const uint4*)(Bh + off); pb1 = *(const uint4*)(Bh + off + 8);
    pb2 = *(const uint4*)(Bl + off); pb3 = *(const uint4*)(Bl + off + 8);
  };

  LA(0); LB(0);
#pragma unroll
  for (int ch = 0; ch < 4; ++ch) {
    {
      float fv[16];
      *(float4*)&fv[0]  = pf0; *(float4*)&fv[4]  = pf1;
      *(float4*)&fv[8]  = pf2; *(float4*)&fv[12] = pf3;
      ushort hi[16], lo[16];
#pragma unroll
      for (int e = 0; e < 16; ++e) fsplit(fv[e], hi[e], lo[e]);
      *(uint4*)&Ash[sr * LDP + sc]     = *(uint4*)&hi[0];
      *(uint4*)&Ash[sr * LDP + sc + 8] = *(uint4*)&hi[8];
      *(uint4*)&Asl[sr * LDP + sc]     = *(uint4*)&lo[0];
      *(uint4*)&Asl[sr * LDP + sc + 8] = *(uint4*)&lo[8];
    }
    *(uint4*)&Bsh[sr * LDP + sc]     = pb0;
    *(uint4*)&Bsh[sr * LDP + sc + 8] = pb1;
    *(uint4*)&Bsl[sr * LDP + sc]     = pb2;
    *(uint4*)&Bsl[sr * LDP + sc + 8] = pb3;
    __syncthreads();
    if (ch < 3) { LA(ch + 1); LB(ch + 1); }
    bhalf8 afh[4], afl[4], bfh[4], bfl[4];
#pragma unroll
    for (int i = 0; i < 4; ++i) {
      const int r = (wm + i * 16 + fr) * LDP + quad * 8;
      afh[i] = *(const bhalf8*)&Ash[r];
      afl[i] = *(const bhalf8*)&Asl[r];
    }
#pragma unroll
    for (int j = 0; j < 4; ++j) {
      const int r = (wn + j * 16 + fr) * LDP + quad * 8;
      bfh[j] = *(const bhalf8*)&Bsh[r];
      bfl[j] = *(const bhalf8*)&Bsl[r];
    }
#pragma unroll
    for (int i = 0; i < 4; ++i)
#pragma unroll
      for (int j = 0; j < 4; ++j) {
        acc[i][j] = __builtin_amdgcn_mfma_f32_16x16x32_bf16(afh[i], bfh[j], acc[i][j], 0, 0, 0);
        acc[i][j] = __builtin_amdgcn_mfma_f32_16x16x32_bf16(afl[i], bfh[j], acc[i][j], 0, 0, 0);
        acc[i][j] = __builtin_amdgcn_mfma_f32_16x16x32_bf16(afh[i], bfl[j], acc[i][j], 0, 0, 0);
      }
    __syncthreads();
  }

  const int nj[4] = {wn + fr, wn + 16 + fr, wn + 32 + fr, wn + 48 + fr};
  float c0a[4], vla[4], re0[4], re1[4];
#pragma unroll
  for (int j = 0; j < 4; ++j) {
    c0a[j] = c0v[nj[j]]; vla[j] = vl[nj[j]];
    re0[j] = rev[nj[j]]; re1[j] = rev[HH + nj[j]];
  }
#pragma unroll
  for (int i = 0; i < 4; ++i)
#pragma unroll
    for (int r = 0; r < 4; ++r) {
      const int m = row0 + wm + i * 16 + quad * 4 + r;
      const int s = m >> 6;
      const float lp = log_probs[s];
      const bool isr = (m & 63) == root_local[s];
      const size_t base = (size_t)m * HH;
#pragma unroll
      for (int j = 0; j < 4; ++j)
        Cf[base + nj[j]] = acc[i][j][r] + c0a[j] + lp * vla[j] + (isr ? re1[j] : re0[j]);
    }
}

// ---------------------------------------------------------------------------
// Final BN apply with residual; coef computed inline from stats; fp16 u input.
// ---------------------------------------------------------------------------
__launch_bounds__(256)
__global__ void bn_apply_k(const _Float16* __restrict__ u, float* __restrict__ h,
                           const float* __restrict__ stats,
                           const float* __restrict__ gamma, const float* __restrict__ beta) {
  size_t i4 = (size_t)(blockIdx.x * 256 + threadIdx.x) * 4;
  int c = (int)(i4 & 127);
  const float invM = 1.0f / (float)SKK;
  float sc[4], sh[4];
#pragma unroll
  for (int e = 0; e < 4; ++e) {
    const float mu = stats[c + e] * invM;
    const float var = fmaf(-mu, mu, stats[HH + c + e] * invM);
    const float s = rsqrtf(var + 1e-5f) * gamma[c + e];
    sc[e] = s; sh[e] = fmaf(-mu, s, beta[c + e]);
  }
  half4 uv = *(const half4*)(u + i4);
  float4 hv = *(const float4*)(h + i4);
  float4 o;
  o.x = fmaf((float)uv.x, sc[0], sh[0]) + hv.x;
  o.y = fmaf((float)uv.y, sc[1], sh[1]) + hv.y;
  o.z = fmaf((float)uv.z, sc[2], sh[2]) + hv.z;
  o.w = fmaf((float)uv.w, sc[3], sh[3]) + hv.w;
  *(float4*)(h + i4) = o;
}

// ---------------------------------------------------------------------------
extern "C" void kernel_launch(void* const* d_in, const int* in_sizes, int n_in,
                              void* d_out, int out_size, void* d_ws, size_t ws_size,
                              hipStream_t stream) {
  const float* x          = (const float*)d_in[0];
  const float* log_probs  = (const float*)d_in[1];
  const float* node_w     = (const float*)d_in[2];
  const float* node_b     = (const float*)d_in[3];
  const float* logp_w     = (const float*)d_in[4];
  const float* logp_b     = (const float*)d_in[5];
  const float* root_emb   = (const float*)d_in[6];
  const float* init_w     = (const float*)d_in[7];
  const float* init_b     = (const float*)d_in[8];
  const float* gin_eps    = (const float*)d_in[9];
  const float* w1         = (const float*)d_in[10];
  const float* b1         = (const float*)d_in[11];
  const float* w2         = (const float*)d_in[12];
  const float* b2         = (const float*)d_in[13];
  const float* mp2w       = (const float*)d_in[14];
  const float* mp2b       = (const float*)d_in[15];
  const float* gamma      = (const float*)d_in[16];
  const float* beta       = (const float*)d_in[17];
  const int*   nodes      = (const int*)d_in[18];
  const int*   root_local = (const int*)d_in[19];
  const int*   edge_idx   = (const int*)d_in[20];
  const int*   edge_ptr   = (const int*)d_in[21];
  float* h = (float*)d_out;   // fp32 residual stream lives in d_out

  // ---- workspace carve ----
  char* wp = (char*)d_ws;
  auto take = [&](size_t bytes) { char* p = wp; wp += (bytes + 255) & ~(size_t)255; return p; };
  ushort* zh    = (ushort*)take((size_t)SKK * HH * 2);   // 32 MB
  ushort* zl    = (ushort*)take((size_t)SKK * HH * 2);
  _Float16* uh  = (_Float16*)take((size_t)SKK * HH * 2); // 32 MB fp16 u
  ushort* xah   = (ushort*)take((size_t)NN * HH * 2);
  ushort* xal   = (ushort*)take((size_t)NN * HH * 2);
  ushort* Mth   = (ushort*)take((size_t)HH * HH * 2);
  ushort* Mtl   = (ushort*)take((size_t)HH * HH * 2);
  ushort* w1th  = (ushort*)take((size_t)LLAY * HH * HH * 2);
  ushort* w1tl  = (ushort*)take((size_t)LLAY * HH * HH * 2);
  ushort* w2th  = (ushort*)take((size_t)LLAY * HH * HH * 2);
  ushort* w2tl  = (ushort*)take((size_t)LLAY * HH * HH * 2);
  ushort* mp2th = (ushort*)take((size_t)LLAY * HH * 256 * 2);
  ushort* mp2tl = (ushort*)take((size_t)LLAY * HH * 256 * 2);
  float* vl       = (float*)take(HH * 4);
  float* c0v      = (float*)take(HH * 4);
  float* rev      = (float*)take(2 * HH * 4);
  float* bn_stats = (float*)take(LLAY * 2 * HH * 4);
  int*   cnti     = (int*)take((size_t)NN * 4);
  int*   excl     = (int*)take((size_t)NBLK * 256 * 4);
  int*   bsum     = (int*)take(256 * 4);
  int*   boff     = (int*)take(256 * 4);
  int*   node_ptr = (int*)take((size_t)(NN + 1) * 4);
  int*   cur      = (int*)take((size_t)NN * 4);
  int*   rowlist  = (int*)take((size_t)SKK * 4);
  int*   row_ptr  = (int*)take((size_t)(SKK + 1) * 4);
  int*   ssrc     = (int*)take((size_t)EE * 4);

  // ---- prologue ----
  hipMemsetAsync(cnti, 0, (size_t)NN * 4, stream);
  hipMemsetAsync(cur, 0, (size_t)NN * 4, stream);
  hipMemsetAsync(bn_stats, 0, LLAY * 2 * HH * 4, stream);
  fold_M_k<<<HH, HH, 0, stream>>>(node_w, init_w, Mth, Mtl);
  fold_vec_k<<<1, HH, 0, stream>>>(init_w, logp_w, node_b, logp_b, init_b, root_emb,
                                   vl, c0v, rev);
  wconv_k<<<2560, HH, 0, stream>>>(w1, w2, mp2w, w1th, w1tl, w2th, w2tl, mp2th, mp2tl);
  count_k<<<SKK / 256, 256, 0, stream>>>(nodes, cnti);
  scan1_k<<<NBLK, 256, 0, stream>>>(cnti, excl, bsum);
  scan2_k<<<1, 256, 0, stream>>>(bsum, boff);
  scan3_k<<<NBLK, 256, 0, stream>>>(excl, boff, node_ptr);
  fill_rows_k<<<SKK / 256, 256, 0, stream>>>(nodes, node_ptr, cur, rowlist);
  presort_k<<<SS, 256, 0, stream>>>(edge_idx, edge_idx + EE, edge_ptr, row_ptr, ssrc);

  // initial h (fp32, in d_out)
  mgemm0_k<<<SKK / 128, 256, 0, stream>>>(x, Mth, Mtl, h,
                                          nodes, log_probs, root_local, vl, c0v, rev);

  for (int l = 0; l < LLAY; ++l) {
    if (l == 0) {
      gin_mega_k<true><<<SS, 256, 0, stream>>>(h, nullptr, nullptr, nullptr, nullptr,
                                               row_ptr, ssrc, gin_eps, l,
                                               w1th + (size_t)l * HH * HH,
                                               w1tl + (size_t)l * HH * HH,
                                               w2th + (size_t)l * HH * HH,
                                               w2tl + (size_t)l * HH * HH,
                                               b1 + l * HH, b2 + l * HH, zh, zl);
    } else {
      gin_mega_k<false><<<SS, 256, 0, stream>>>(h, uh, bn_stats + (l - 1) * 2 * HH,
                                                gamma + (l - 1) * HH, beta + (l - 1) * HH,
                                                row_ptr, ssrc, gin_eps, l,
                                                w1th + (size_t)l * HH * HH,
                                                w1tl + (size_t)l * HH * HH,
                                                w2th + (size_t)l * HH * HH,
                                                w2tl + (size_t)l * HH * HH,
                                                b1 + l * HH, b2 + l * HH, zh, zl);
    }
    scatter_mean_k<<<(NN + 15) / 16, 256, 0, stream>>>(zh, zl, node_ptr, rowlist, xah, xal);
    mp2_k<<<SKK / 128, 256, 0, stream>>>(zh, zl, xah, xal,
                                         mp2th + (size_t)l * HH * 256,
                                         mp2tl + (size_t)l * HH * 256,
                                         mp2b + l * HH, uh, nodes,
                                         bn_stats + l * 2 * HH);
  }
  // final BN+residual apply (layer 4) -> h in d_out
  bn_apply_k<<<(SKK * HH / 4) / 256, 256, 0, stream>>>(uh, h, bn_stats + 4 * 2 * HH,
                                                       gamma + 4 * HH, beta + 4 * HH);
}

// Round 14
// 910.642 us; speedup vs baseline: 1.1724x; 1.0738x over previous
//
#include <hip/hip_runtime.h>
#include <cstdint>

#define NN   50000
#define SS   2048
#define KSUB 64
#define HH   128
#define EE   (SS * 256)
#define SKK  (SS * KSUB)    // 131072
#define LLAY 5
#define NBLK 196            // ceil(NN/256)

typedef __attribute__((ext_vector_type(8))) short bhalf8;
typedef __attribute__((ext_vector_type(4))) float f32x4;
typedef __attribute__((ext_vector_type(4))) _Float16 half4;

__device__ __forceinline__ ushort f2b(float f) {
  uint u = __builtin_bit_cast(uint, f);
  uint r = (u + 0x7FFFu + ((u >> 16) & 1u)) >> 16;
  return (ushort)r;
}
__device__ __forceinline__ float b2f(ushort u) {
  uint v = ((uint)u) << 16;
  return __builtin_bit_cast(float, v);
}
// split fp32 -> (hi, lo) bf16 pair; hi + lo ~= f with ~2^-18 residual
__device__ __forceinline__ void fsplit(float f, ushort& hi, ushort& lo) {
  hi = f2b(f);
  lo = f2b(f - b2f(hi));
}
// byte offset into a [64][128]-short LDS tile, T2 XOR swizzle (row stride 256B)
__device__ __forceinline__ int zoff(int row, int col) {
  return row * 256 + (((col * 2) & 255) ^ ((row & 7) << 4));
}

// ---------------------------------------------------------------------------
// Fold node_proj through init_proj; emit split bf16 B^T layout [n][c]
// ---------------------------------------------------------------------------
__global__ void fold_M_k(const float* __restrict__ Wn, const float* __restrict__ Wi,
                         ushort* __restrict__ Mth, ushort* __restrict__ Mtl) {
  int c = blockIdx.x, n = threadIdx.x;
  float s = 0.f;
  for (int k = 0; k < HH; ++k) s = fmaf(Wn[c * HH + k], Wi[k * HH + n], s);
  ushort hi, lo; fsplit(s, hi, lo);
  Mth[n * HH + c] = hi; Mtl[n * HH + c] = lo;
}

__global__ void fold_vec_k(const float* __restrict__ Wi, const float* __restrict__ wl,
                           const float* __restrict__ bnb, const float* __restrict__ blb,
                           const float* __restrict__ bi, const float* __restrict__ remb,
                           float* __restrict__ vl, float* __restrict__ c0,
                           float* __restrict__ rev) {
  int n = threadIdx.x;
  float svl = 0.f, sc0 = bi[n], r0 = 0.f, r1 = 0.f;
  for (int k = 0; k < HH; ++k) {
    svl = fmaf(wl[k], Wi[(HH + k) * HH + n], svl);
    sc0 = fmaf(bnb[k], Wi[k * HH + n], sc0);
    sc0 = fmaf(blb[k], Wi[(HH + k) * HH + n], sc0);
    r0  = fmaf(remb[k],      Wi[(2 * HH + k) * HH + n], r0);
    r1  = fmaf(remb[HH + k], Wi[(2 * HH + k) * HH + n], r1);
  }
  vl[n] = svl; c0[n] = sc0; rev[n] = r0; rev[HH + n] = r1;
}

// ---------------------------------------------------------------------------
// Transpose+convert all layer weights to split bf16 B^T layout (one launch).
// ---------------------------------------------------------------------------
__global__ void wconv_k(const float* __restrict__ w1, const float* __restrict__ w2,
                        const float* __restrict__ mp2w,
                        ushort* __restrict__ w1th, ushort* __restrict__ w1tl,
                        ushort* __restrict__ w2th, ushort* __restrict__ w2tl,
                        ushort* __restrict__ mp2th, ushort* __restrict__ mp2tl) {
  int b = blockIdx.x, n = threadIdx.x;
  ushort hi, lo;
  if (b < 640) {
    int l = b >> 7, k = b & 127;
    fsplit(w1[((size_t)l * HH + k) * HH + n], hi, lo);
    w1th[((size_t)l * HH + n) * HH + k] = hi;
    w1tl[((size_t)l * HH + n) * HH + k] = lo;
  } else if (b < 1280) {
    int bb = b - 640; int l = bb >> 7, k = bb & 127;
    fsplit(w2[((size_t)l * HH + k) * HH + n], hi, lo);
    w2th[((size_t)l * HH + n) * HH + k] = hi;
    w2tl[((size_t)l * HH + n) * HH + k] = lo;
  } else {
    int bb = b - 1280; int l = bb >> 8, k = bb & 255;
    fsplit(mp2w[((size_t)l * 256 + k) * HH + n], hi, lo);
    mp2th[((size_t)l * HH + n) * 256 + k] = hi;
    mp2tl[((size_t)l * HH + n) * 256 + k] = lo;
  }
}

// ---------------------------------------------------------------------------
// Node-CSR construction: count -> exclusive scan -> fill
// ---------------------------------------------------------------------------
__global__ void count_k(const int* __restrict__ idc, int* __restrict__ cnt) {
  int i = blockIdx.x * 256 + threadIdx.x;
  if (i < SKK) atomicAdd(&cnt[idc[i]], 1);
}

__global__ void scan1_k(const int* __restrict__ cnt, int* __restrict__ excl,
                        int* __restrict__ bsum) {
  __shared__ int sh[256];
  const int tid = threadIdx.x;
  const int i = blockIdx.x * 256 + tid;
  int v = (i < NN) ? cnt[i] : 0;
  sh[tid] = v;
  __syncthreads();
#pragma unroll
  for (int off = 1; off < 256; off <<= 1) {
    int t = (tid >= off) ? sh[tid - off] : 0;
    __syncthreads();
    sh[tid] += t;
    __syncthreads();
  }
  excl[i] = sh[tid] - v;
  if (tid == 255) bsum[blockIdx.x] = sh[tid];
}

__global__ void scan2_k(int* __restrict__ bsum, int* __restrict__ boff) {
  __shared__ int sh[256];
  const int tid = threadIdx.x;
  int v = (tid < NBLK) ? bsum[tid] : 0;
  sh[tid] = v;
  __syncthreads();
#pragma unroll
  for (int off = 1; off < 256; off <<= 1) {
    int t = (tid >= off) ? sh[tid - off] : 0;
    __syncthreads();
    sh[tid] += t;
    __syncthreads();
  }
  boff[tid] = sh[tid] - v;
}

__global__ void scan3_k(const int* __restrict__ excl, const int* __restrict__ boff,
                        int* __restrict__ node_ptr) {
  int i = blockIdx.x * 256 + threadIdx.x;
  if (i < NN) node_ptr[i] = excl[i] + boff[blockIdx.x];
  if (i == 0) node_ptr[NN] = SKK;
}

__global__ void fill_rows_k(const int* __restrict__ idc, const int* __restrict__ node_ptr,
                            int* __restrict__ cur, int* __restrict__ rowlist) {
  int i = blockIdx.x * 256 + threadIdx.x;
  if (i < SKK) {
    int id = idc[i];
    int pos = atomicAdd(&cur[id], 1);
    rowlist[node_ptr[id] + pos] = i;
  }
}

// ---------------------------------------------------------------------------
// Cross-subgraph scatter-mean as a GATHER. Vectorized: 16 lanes/node,
// 16B uint4 loads per lane, 16 nodes/block.
// ---------------------------------------------------------------------------
__launch_bounds__(256)
__global__ void scatter_mean_k(const ushort* __restrict__ zh, const ushort* __restrict__ zl,
                               const int* __restrict__ node_ptr,
                               const int* __restrict__ rowlist,
                               ushort* __restrict__ xah, ushort* __restrict__ xal) {
  const int tid = threadIdx.x;
  const int n = blockIdx.x * 16 + (tid >> 4);
  if (n >= NN) return;
  const int c8 = (tid & 15) * 8;
  const int p0 = node_ptr[n], p1 = node_ptr[n + 1];
  float s[8] = {0.f, 0.f, 0.f, 0.f, 0.f, 0.f, 0.f, 0.f};
  for (int p = p0; p < p1; ++p) {
    const size_t off = (size_t)rowlist[p] * HH + c8;
    uint4 vh = *(const uint4*)(zh + off);
    uint4 vl = *(const uint4*)(zl + off);
    const uint hw[4] = {vh.x, vh.y, vh.z, vh.w};
    const uint lw[4] = {vl.x, vl.y, vl.z, vl.w};
#pragma unroll
    for (int k = 0; k < 4; ++k) {
      s[2 * k]     += b2f((ushort)hw[k])        + b2f((ushort)lw[k]);
      s[2 * k + 1] += b2f((ushort)(hw[k] >> 16)) + b2f((ushort)(lw[k] >> 16));
    }
  }
  const float inv = 1.0f / (float)max(p1 - p0, 1);
  ushort hi[8], lo[8];
#pragma unroll
  for (int k = 0; k < 8; ++k) fsplit(s[k] * inv, hi[k], lo[k]);
  *(uint4*)(xah + (size_t)n * HH + c8) = *(uint4*)hi;
  *(uint4*)(xal + (size_t)n * HH + c8) = *(uint4*)lo;
}

// ---------------------------------------------------------------------------
// Per-subgraph counting sort of edges by dst -> CSR
// ---------------------------------------------------------------------------
__launch_bounds__(256)
__global__ void presort_k(const int* __restrict__ e_src, const int* __restrict__ e_dst,
                          const int* __restrict__ edge_ptr, int* __restrict__ row_ptr,
                          int* __restrict__ ssrc) {
  __shared__ int cnt[KSUB];
  __shared__ int base[KSUB];
  __shared__ int cur[KSUB];
  const int s = blockIdx.x, tid = threadIdx.x;
  const int p0 = edge_ptr[s], p1 = edge_ptr[s + 1];
  if (tid < KSUB) cnt[tid] = 0;
  __syncthreads();
  for (int e = p0 + tid; e < p1; e += 256) atomicAdd(&cnt[e_dst[e]], 1);
  __syncthreads();
  if (tid == 0) {
    int a = 0;
    for (int d = 0; d < KSUB; ++d) { base[d] = a; a += cnt[d]; }
  }
  __syncthreads();
  if (tid < KSUB) { row_ptr[s * KSUB + tid] = p0 + base[tid]; cur[tid] = base[tid]; }
  if (s == 0 && tid == 0) row_ptr[SS * KSUB] = edge_ptr[SS];
  __syncthreads();
  for (int e = p0 + tid; e < p1; e += 256) {
    int d = e_dst[e];
    int pos = atomicAdd(&cur[d], 1);
    ssrc[p0 + pos] = e_src[e];
  }
}

// ---------------------------------------------------------------------------
// MEGA kernel: per subgraph (64 rows):
//   phase A: h_new = bn(u_fp16) + h_old (residual) [skip BN if FIRST];
//            BN coef computed INLINE from stats; write h_new, keep fp32 in LDS
//            + stage this subgraph's 256 ssrc entries into LDS (1 KB)
//   phase B: GIN aggregation (interleaved channel mapping, ssrc from LDS)
//   phase C: split z_agg -> swizzled bf16 LDS tile Z (aliases hl)
//   MLP1:    t = relu(Z @ W1 + b1) -> swizzled LDS tile T (aliases Z)
//   MLP2:    z = T @ W2 + b2 -> staged into dead Z/T LDS tiles (swizzled),
//            then COALESCED copy-out (4x dwordx4/thread/buffer)
// ---------------------------------------------------------------------------
template <bool FIRST>
__launch_bounds__(256, 4)
__global__ void gin_mega_k(float* __restrict__ h, const _Float16* __restrict__ uh,
                           const float* __restrict__ stats,
                           const float* __restrict__ gamma, const float* __restrict__ beta,
                           const int* __restrict__ row_ptr, const int* __restrict__ ssrc,
                           const float* __restrict__ gin_eps, const int layer,
                           const ushort* __restrict__ B1h, const ushort* __restrict__ B1l,
                           const ushort* __restrict__ B2h, const ushort* __restrict__ B2l,
                           const float* __restrict__ bias1, const float* __restrict__ bias2,
                           ushort* __restrict__ zh, ushort* __restrict__ zl) {
  constexpr int LDH = 132;
  __shared__ __align__(16) char smem[KSUB * LDH * 4];   // 33792 B, phase-aliased
  __shared__ int ssrc_lds[256];                          // 1 KB edge-source cache
  float*  hl = (float*)smem;                 // [64][132] fp32 (phases A,B)
  ushort* Zh = (ushort*)smem;                // [64][128] swizzled (phases C..out)
  ushort* Zl = (ushort*)(smem + KSUB * HH * 2);
  const int s = blockIdx.x, tid = threadIdx.x;
  const size_t base = (size_t)s * KSUB * HH;

  // ---- stage ssrc (coalesced, 1 iteration for ES=256) ----
  const int e_start = row_ptr[s * KSUB];
  {
    const int e_end = row_ptr[s * KSUB + KSUB];
    for (int e = e_start + tid; e < e_end; e += 256)
      ssrc_lds[e - e_start] = ssrc[e];
  }

  // ---- phase A (BN coef inline; c constant across 'it' since 1024 % 128 == 0) ----
  float csc[4], csh[4];
  const int cb = (tid * 4) & 127;
  if constexpr (!FIRST) {
    const float invM = 1.0f / (float)SKK;
#pragma unroll
    for (int e = 0; e < 4; ++e) {
      const float mu = stats[cb + e] * invM;
      const float var = fmaf(-mu, mu, stats[HH + cb + e] * invM);
      const float sc = rsqrtf(var + 1e-5f) * gamma[cb + e];
      csc[e] = sc; csh[e] = fmaf(-mu, sc, beta[cb + e]);
    }
  }
#pragma unroll
  for (int it = 0; it < 8; ++it) {
    const int idx = it * 1024 + tid * 4;
    const int m = idx >> 7, c = idx & 127;
    float4 hv = *(const float4*)&h[base + idx];
    if constexpr (!FIRST) {
      half4 u4 = *(const half4*)&uh[base + idx];
      hv.x += fmaf((float)u4.x, csc[0], csh[0]);
      hv.y += fmaf((float)u4.y, csc[1], csh[1]);
      hv.z += fmaf((float)u4.z, csc[2], csh[2]);
      hv.w += fmaf((float)u4.w, csc[3], csh[3]);
      *(float4*)&h[base + idx] = hv;
    }
    *(float4*)&hl[m * LDH + c] = hv;
  }
  __syncthreads();

  // ---- phase B: aggregation (interleaved channel mapping; ssrc from LDS) ----
  const float ep1 = 1.0f + gin_eps[layer];
  const int d = tid >> 2, q4 = (tid & 3) * 4;   // cols q4 + 16*j + k
  const int g = s * KSUB + d;
  const int e0 = row_ptr[g], e1 = row_ptr[g + 1];
  float a[32];
  {
    const float* hp0 = &hl[d * LDH + q4];
#pragma unroll
    for (int j = 0; j < 8; ++j) {
      float4 v = *(const float4*)(hp0 + 16 * j);
      a[4 * j + 0] = ep1 * v.x; a[4 * j + 1] = ep1 * v.y;
      a[4 * j + 2] = ep1 * v.z; a[4 * j + 3] = ep1 * v.w;
    }
    for (int e = e0; e < e1; ++e) {
      const float* hp = &hl[ssrc_lds[e - e_start] * LDH + q4];
#pragma unroll
      for (int j = 0; j < 8; ++j) {
        float4 v = *(const float4*)(hp + 16 * j);
        a[4 * j + 0] += v.x; a[4 * j + 1] += v.y;
        a[4 * j + 2] += v.z; a[4 * j + 3] += v.w;
      }
    }
  }
  __syncthreads();          // all hl reads done (Z aliases hl)

  // ---- phase C: split z_agg into swizzled LDS tile (8B writes) ----
#pragma unroll
  for (int j = 0; j < 8; ++j) {
    ushort th[4], tl[4];
#pragma unroll
    for (int k = 0; k < 4; ++k) fsplit(a[4 * j + k], th[k], tl[k]);
    const int o = zoff(d, q4 + 16 * j);
    *(uint2*)((char*)Zh + o) = *(uint2*)th;
    *(uint2*)((char*)Zl + o) = *(uint2*)tl;
  }
  __syncthreads();

  // ---- MLP GEMMs ----
  const int lane = tid & 63, wv = tid >> 6;
  const int fr = lane & 15, quad = lane >> 4;
  const int nj0 = wv * 32 + fr, nj1 = nj0 + 16;

  f32x4 acc[4][2];
#pragma unroll
  for (int i = 0; i < 4; ++i) { acc[i][0] = (f32x4){0,0,0,0}; acc[i][1] = (f32x4){0,0,0,0}; }

  // MLP1: t = relu(Z @ W1 + b1)
#pragma unroll
  for (int ch = 0; ch < 4; ++ch) {
    bhalf8 afh[4], afl[4], bfh[2], bfl[2];
#pragma unroll
    for (int i = 0; i < 4; ++i) {
      const int o = zoff(i * 16 + fr, ch * 32 + quad * 8);
      afh[i] = *(const bhalf8*)((const char*)Zh + o);
      afl[i] = *(const bhalf8*)((const char*)Zl + o);
    }
#pragma unroll
    for (int j = 0; j < 2; ++j) {
      const size_t off = (size_t)(wv * 32 + j * 16 + fr) * HH + ch * 32 + quad * 8;
      bfh[j] = *(const bhalf8*)(B1h + off);
      bfl[j] = *(const bhalf8*)(B1l + off);
    }
#pragma unroll
    for (int i = 0; i < 4; ++i)
#pragma unroll
      for (int j = 0; j < 2; ++j) {
        acc[i][j] = __builtin_amdgcn_mfma_f32_16x16x32_bf16(afh[i], bfh[j], acc[i][j], 0, 0, 0);
        acc[i][j] = __builtin_amdgcn_mfma_f32_16x16x32_bf16(afl[i], bfh[j], acc[i][j], 0, 0, 0);
        acc[i][j] = __builtin_amdgcn_mfma_f32_16x16x32_bf16(afh[i], bfl[j], acc[i][j], 0, 0, 0);
      }
  }
  __syncthreads();          // all Z reads done (T aliases Z)

  // epilogue 1: T = relu(acc + b1), split, into swizzled LDS
  {
    const float b10 = bias1[nj0], b11 = bias1[nj1];
#pragma unroll
    for (int i = 0; i < 4; ++i)
#pragma unroll
      for (int r = 0; r < 4; ++r) {
        const int row = i * 16 + quad * 4 + r;
        const float o0 = fmaxf(acc[i][0][r] + b10, 0.f);
        const float o1 = fmaxf(acc[i][1][r] + b11, 0.f);
        ushort h0, l0, h1, l1; fsplit(o0, h0, l0); fsplit(o1, h1, l1);
        *(ushort*)((char*)Zh + zoff(row, nj0)) = h0;
        *(ushort*)((char*)Zl + zoff(row, nj0)) = l0;
        *(ushort*)((char*)Zh + zoff(row, nj1)) = h1;
        *(ushort*)((char*)Zl + zoff(row, nj1)) = l1;
      }
  }
  __syncthreads();

  // MLP2: z = T @ W2 + b2
#pragma unroll
  for (int i = 0; i < 4; ++i) { acc[i][0] = (f32x4){0,0,0,0}; acc[i][1] = (f32x4){0,0,0,0}; }
#pragma unroll
  for (int ch = 0; ch < 4; ++ch) {
    bhalf8 afh[4], afl[4], bfh[2], bfl[2];
#pragma unroll
    for (int i = 0; i < 4; ++i) {
      const int o = zoff(i * 16 + fr, ch * 32 + quad * 8);
      afh[i] = *(const bhalf8*)((const char*)Zh + o);
      afl[i] = *(const bhalf8*)((const char*)Zl + o);
    }
#pragma unroll
    for (int j = 0; j < 2; ++j) {
      const size_t off = (size_t)(wv * 32 + j * 16 + fr) * HH + ch * 32 + quad * 8;
      bfh[j] = *(const bhalf8*)(B2h + off);
      bfl[j] = *(const bhalf8*)(B2l + off);
    }
#pragma unroll
    for (int i = 0; i < 4; ++i)
#pragma unroll
      for (int j = 0; j < 2; ++j) {
        acc[i][j] = __builtin_amdgcn_mfma_f32_16x16x32_bf16(afh[i], bfh[j], acc[i][j], 0, 0, 0);
        acc[i][j] = __builtin_amdgcn_mfma_f32_16x16x32_bf16(afl[i], bfh[j], acc[i][j], 0, 0, 0);
        acc[i][j] = __builtin_amdgcn_mfma_f32_16x16x32_bf16(afh[i], bfl[j], acc[i][j], 0, 0, 0);
      }
  }
  __syncthreads();          // all T reads done — Z/T tiles now dead, reuse for z

  // epilogue 2a: split z into swizzled LDS (same pattern as epilogue 1)
  {
    const float b20 = bias2[nj0], b21 = bias2[nj1];
#pragma unroll
    for (int i = 0; i < 4; ++i)
#pragma unroll
      for (int r = 0; r < 4; ++r) {
        const int row = i * 16 + quad * 4 + r;
        const float o0 = acc[i][0][r] + b20;
        const float o1 = acc[i][1][r] + b21;
        ushort h0, l0, h1, l1; fsplit(o0, h0, l0); fsplit(o1, h1, l1);
        *(ushort*)((char*)Zh + zoff(row, nj0)) = h0;
        *(ushort*)((char*)Zl + zoff(row, nj0)) = l0;
        *(ushort*)((char*)Zh + zoff(row, nj1)) = h1;
        *(ushort*)((char*)Zl + zoff(row, nj1)) = l1;
      }
  }
  __syncthreads();

  // epilogue 2b: coalesced copy-out. Thread t, iter k: 16B at global ushort
  // index t*8 + k*2048 -> lanes contiguous (1KB per wave-instruction).
#pragma unroll
  for (int k = 0; k < 4; ++k) {
    const int gidx = tid * 8 + k * 2048;         // ushort index in [0, 8192)
    const int row = gidx >> 7;
    const int col = gidx & 127;
    const int o = zoff(row, col);
    *(uint4*)(zh + base + gidx) = *(const uint4*)((const char*)Zh + o);
    *(uint4*)(zl + base + gidx) = *(const uint4*)((const char*)Zl + o);
  }
}

// ---------------------------------------------------------------------------
// MP-2 GEMM: verified 128-row LDS-staged structure + TWO-DEEP T14 prefetch.
// u stored fp16; epilogue stages u through the dead staging LDS ([128][136]
// fp16 tile, 16B-aligned rows) then COALESCED copy-out — fixes the half-line
// RMW amplification of direct scalar fp16 stores (round-13 counters:
// FETCH +8MB, WRITE 69 vs 36 expected).
// ---------------------------------------------------------------------------
__launch_bounds__(256, 3)
__global__ void mp2_k(const ushort* __restrict__ Ah, const ushort* __restrict__ Al,
                      const ushort* __restrict__ A2h, const ushort* __restrict__ A2l,
                      const ushort* __restrict__ Bh, const ushort* __restrict__ Bl,
                      const float* __restrict__ bias, _Float16* __restrict__ Cf,
                      const int* __restrict__ idc, float* __restrict__ stats) {
  constexpr int LDP = 40;   // LDS row stride in shorts (staging phase)
  constexpr int LDU = 136;  // fp16 u-tile row stride (epilogue; 272B = 16B mult)
  __shared__ __align__(16) char smem[4 * 128 * LDP * 2];   // 40960 B, phase-aliased
  ushort* Ash = (ushort*)smem;
  ushort* Asl = (ushort*)(smem + 10240);
  ushort* Bsh = (ushort*)(smem + 20480);
  ushort* Bsl = (ushort*)(smem + 30720);
  const int tid = threadIdx.x;
  const int row0 = blockIdx.x * 128;
  const int lane = tid & 63, wv = tid >> 6;
  const int wm = (wv >> 1) * 64, wn = (wv & 1) * 64;
  const int fr = lane & 15, quad = lane >> 4;
  const int sr = tid >> 1;            // staging row 0..127
  const int sc = (tid & 1) * 16;      // staging short-offset {0,16}
  const int grow = idc[row0 + sr];    // gather row for K-half 2 (hoisted)

  f32x4 acc[4][4];
#pragma unroll
  for (int i = 0; i < 4; ++i)
#pragma unroll
    for (int j = 0; j < 4; ++j) acc[i][j] = (f32x4){0.f, 0.f, 0.f, 0.f};

  // two named prefetch sets (E = even chunks, O = odd chunks)
  uint4 eA0, eA1, eA2, eA3, eB0, eB1, eB2, eB3;
  uint4 oA0, oA1, oA2, oA3, oB0, oB1, oB2, oB3;
  auto aptr = [&](int ch) -> const ushort* {
    if (ch >= 4) return A2h + ((size_t)grow * HH + (ch - 4) * 32 + sc);
    return Ah + ((size_t)(row0 + sr) * HH + ch * 32 + sc);
  };
  auto aptrl = [&](int ch) -> const ushort* {
    if (ch >= 4) return A2l + ((size_t)grow * HH + (ch - 4) * 32 + sc);
    return Al + ((size_t)(row0 + sr) * HH + ch * 32 + sc);
  };
  auto LE = [&](int ch) {
    const ushort* ph = aptr(ch); const ushort* pl = aptrl(ch);
    eA0 = *(const uint4*)(ph); eA1 = *(const uint4*)(ph + 8);
    eA2 = *(const uint4*)(pl); eA3 = *(const uint4*)(pl + 8);
    const size_t off = (size_t)sr * 256 + ch * 32 + sc;
    eB0 = *(const uint4*)(Bh + off); eB1 = *(const uint4*)(Bh + off + 8);
    eB2 = *(const uint4*)(Bl + off); eB3 = *(const uint4*)(Bl + off + 8);
  };
  auto LO = [&](int ch) {
    const ushort* ph = aptr(ch); const ushort* pl = aptrl(ch);
    oA0 = *(const uint4*)(ph); oA1 = *(const uint4*)(ph + 8);
    oA2 = *(const uint4*)(pl); oA3 = *(const uint4*)(pl + 8);
    const size_t off = (size_t)sr * 256 + ch * 32 + sc;
    oB0 = *(const uint4*)(Bh + off); oB1 = *(const uint4*)(Bh + off + 8);
    oB2 = *(const uint4*)(Bl + off); oB3 = *(const uint4*)(Bl + off + 8);
  };
  auto STAGE = [&](uint4 a0, uint4 a1, uint4 a2, uint4 a3,
                   uint4 b0, uint4 b1, uint4 b2, uint4 b3) {
    *(uint4*)&Ash[sr * LDP + sc]     = a0;
    *(uint4*)&Ash[sr * LDP + sc + 8] = a1;
    *(uint4*)&Asl[sr * LDP + sc]     = a2;
    *(uint4*)&Asl[sr * LDP + sc + 8] = a3;
    *(uint4*)&Bsh[sr * LDP + sc]     = b0;
    *(uint4*)&Bsh[sr * LDP + sc + 8] = b1;
    *(uint4*)&Bsl[sr * LDP + sc]     = b2;
    *(uint4*)&Bsl[sr * LDP + sc + 8] = b3;
  };
  auto MFMA_STEP = [&]() {
    bhalf8 afh[4], afl[4], bfh[4], bfl[4];
#pragma unroll
    for (int i = 0; i < 4; ++i) {
      const int r = (wm + i * 16 + fr) * LDP + quad * 8;
      afh[i] = *(const bhalf8*)&Ash[r];
      afl[i] = *(const bhalf8*)&Asl[r];
    }
#pragma unroll
    for (int j = 0; j < 4; ++j) {
      const int r = (wn + j * 16 + fr) * LDP + quad * 8;
      bfh[j] = *(const bhalf8*)&Bsh[r];
      bfl[j] = *(const bhalf8*)&Bsl[r];
    }
#pragma unroll
    for (int i = 0; i < 4; ++i)
#pragma unroll
      for (int j = 0; j < 4; ++j) {
        acc[i][j] = __builtin_amdgcn_mfma_f32_16x16x32_bf16(afh[i], bfh[j], acc[i][j], 0, 0, 0);
        acc[i][j] = __builtin_amdgcn_mfma_f32_16x16x32_bf16(afl[i], bfh[j], acc[i][j], 0, 0, 0);
        acc[i][j] = __builtin_amdgcn_mfma_f32_16x16x32_bf16(afh[i], bfl[j], acc[i][j], 0, 0, 0);
      }
  };

  LE(0); LO(1);
#pragma unroll
  for (int chp = 0; chp < 4; ++chp) {
    // even chunk 2*chp: consume E, refill E with chunk 2*chp+2
    STAGE(eA0, eA1, eA2, eA3, eB0, eB1, eB2, eB3);
    __syncthreads();
    if (chp < 3) LE(2 * chp + 2);
    MFMA_STEP();
    __syncthreads();
    // odd chunk 2*chp+1: consume O, refill O with chunk 2*chp+3
    STAGE(oA0, oA1, oA2, oA3, oB0, oB1, oB2, oB3);
    __syncthreads();
    if (chp < 3) LO(2 * chp + 3);
    MFMA_STEP();
    __syncthreads();
  }

  // ---- epilogue: relu + bias -> fp16 u tile in LDS; BN stats from fp32 ----
  _Float16* uT  = (_Float16*)smem;            // [128][LDU] = 34816 B
  float*    ssum = (float*)(smem + 35072);    // 256 floats (align 16)
  float*    ssq  = ssum + HH;
  const int nj[4] = {wn + fr, wn + 16 + fr, wn + 32 + fr, wn + 48 + fr};
  float bb[4];
#pragma unroll
  for (int j = 0; j < 4; ++j) bb[j] = bias[nj[j]];
  float psum[4] = {0.f, 0.f, 0.f, 0.f}, psq[4] = {0.f, 0.f, 0.f, 0.f};
#pragma unroll
  for (int i = 0; i < 4; ++i)
#pragma unroll
    for (int r = 0; r < 4; ++r) {
      const int row = wm + i * 16 + quad * 4 + r;   // 0..127 within tile
#pragma unroll
      for (int j = 0; j < 4; ++j) {
        float o = fmaxf(acc[i][j][r] + bb[j], 0.f);
        uT[row * LDU + nj[j]] = (_Float16)o;
        psum[j] += o; psq[j] += o * o;
      }
    }
  sred_zero:
  ssum[tid] = 0.f;                             // covers ssum+ssq (256 floats)
  __syncthreads();
#pragma unroll
  for (int j = 0; j < 4; ++j) {
    atomicAdd(&ssum[nj[j]], psum[j]);
    atomicAdd(&ssq[nj[j]], psq[j]);
  }
  __syncthreads();
  // coalesced fp16 copy-out: 8 x uint4 (8 fp16) per thread, lanes contiguous
#pragma unroll
  for (int k = 0; k < 8; ++k) {
    const int idx = tid * 8 + k * 2048;        // fp16 index in [0, 16384)
    const int row = idx >> 7;
    const int col = idx & 127;
    *(uint4*)(Cf + (size_t)(row0 + row) * HH + col) = *(const uint4*)(uT + row * LDU + col);
  }
  if (tid < HH) {
    unsafeAtomicAdd(&stats[tid], ssum[tid]);
    unsafeAtomicAdd(&stats[HH + tid], ssq[tid]);
  }
}

// ---------------------------------------------------------------------------
// Init GEMM (MODE 0): verified LDS-staged structure + T14 issue-early
// prefetch + 3 blocks/CU.
// ---------------------------------------------------------------------------
__launch_bounds__(256, 3)
__global__ void mgemm0_k(const float* __restrict__ Afp,
                         const ushort* __restrict__ Bh, const ushort* __restrict__ Bl,
                         float* __restrict__ Cf,
                         const int* __restrict__ idc, const float* __restrict__ log_probs,
                         const int* __restrict__ root_local, const float* __restrict__ vl,
                         const float* __restrict__ c0v, const float* __restrict__ rev) {
  constexpr int LDP = 40;
  __shared__ __align__(16) ushort Ash[128 * LDP];
  __shared__ __align__(16) ushort Asl[128 * LDP];
  __shared__ __align__(16) ushort Bsh[128 * LDP];
  __shared__ __align__(16) ushort Bsl[128 * LDP];
  const int tid = threadIdx.x;
  const int row0 = blockIdx.x * 128;
  const int lane = tid & 63, wv = tid >> 6;
  const int wm = (wv >> 1) * 64, wn = (wv & 1) * 64;
  const int fr = lane & 15, quad = lane >> 4;
  const int sr = tid >> 1;
  const int sc = (tid & 1) * 16;
  const int arow = idc[row0 + sr];   // hoisted gather row

  f32x4 acc[4][4];
#pragma unroll
  for (int i = 0; i < 4; ++i)
#pragma unroll
    for (int j = 0; j < 4; ++j) acc[i][j] = (f32x4){0.f, 0.f, 0.f, 0.f};

  float4 pf0, pf1, pf2, pf3;
  uint4  pb0, pb1, pb2, pb3;
  auto LA = [&](int ch) {
    const float* src = Afp + (size_t)arow * HH + ch * 32 + sc;
    pf0 = *(const float4*)(src);     pf1 = *(const float4*)(src + 4);
    pf2 = *(const float4*)(src + 8); pf3 = *(const float4*)(src + 12);
  };
  auto LB = [&](int ch) {
    const size_t off = (size_t)sr * HH + ch * 32 + sc;
    pb0 = *(const uint4*)(Bh + off); pb1 = *(const uint4*)(Bh + off + 8);
    pb2 = *(const uint4*)(Bl + off); pb3 = *(const uint4*)(Bl + off + 8);
  };

  LA(0); LB(0);
#pragma unroll
  for (int ch = 0; ch < 4; ++ch) {
    {
      float fv[16];
      *(float4*)&fv[0]  = pf0; *(float4*)&fv[4]  = pf1;
      *(float4*)&fv[8]  = pf2; *(float4*)&fv[12] = pf3;
      ushort hi[16], lo[16];
#pragma unroll
      for (int e = 0; e < 16; ++e) fsplit(fv[e], hi[e], lo[e]);
      *(uint4*)&Ash[sr * LDP + sc]     = *(uint4*)&hi[0];
      *(uint4*)&Ash[sr * LDP + sc + 8] = *(uint4*)&hi[8];
      *(uint4*)&Asl[sr * LDP + sc]     = *(uint4*)&lo[0];
      *(uint4*)&Asl[sr * LDP + sc + 8] = *(uint4*)&lo[8];
    }
    *(uint4*)&Bsh[sr * LDP + sc]     = pb0;
    *(uint4*)&Bsh[sr * LDP + sc + 8] = pb1;
    *(uint4*)&Bsl[sr * LDP + sc]     = pb2;
    *(uint4*)&Bsl[sr * LDP + sc + 8] = pb3;
    __syncthreads();
    if (ch < 3) { LA(ch + 1); LB(ch + 1); }
    bhalf8 afh[4], afl[4], bfh[4], bfl[4];
#pragma unroll
    for (int i = 0; i < 4; ++i) {
      const int r = (wm + i * 16 + fr) * LDP + quad * 8;
      afh[i] = *(const bhalf8*)&Ash[r];
      afl[i] = *(const bhalf8*)&Asl[r];
    }
#pragma unroll
    for (int j = 0; j < 4; ++j) {
      const int r = (wn + j * 16 + fr) * LDP + quad * 8;
      bfh[j] = *(const bhalf8*)&Bsh[r];
      bfl[j] = *(const bhalf8*)&Bsl[r];
    }
#pragma unroll
    for (int i = 0; i < 4; ++i)
#pragma unroll
      for (int j = 0; j < 4; ++j) {
        acc[i][j] = __builtin_amdgcn_mfma_f32_16x16x32_bf16(afh[i], bfh[j], acc[i][j], 0, 0, 0);
        acc[i][j] = __builtin_amdgcn_mfma_f32_16x16x32_bf16(afl[i], bfh[j], acc[i][j], 0, 0, 0);
        acc[i][j] = __builtin_amdgcn_mfma_f32_16x16x32_bf16(afh[i], bfl[j], acc[i][j], 0, 0, 0);
      }
    __syncthreads();
  }

  const int nj[4] = {wn + fr, wn + 16 + fr, wn + 32 + fr, wn + 48 + fr};
  float c0a[4], vla[4], re0[4], re1[4];
#pragma unroll
  for (int j = 0; j < 4; ++j) {
    c0a[j] = c0v[nj[j]]; vla[j] = vl[nj[j]];
    re0[j] = rev[nj[j]]; re1[j] = rev[HH + nj[j]];
  }
#pragma unroll
  for (int i = 0; i < 4; ++i)
#pragma unroll
    for (int r = 0; r < 4; ++r) {
      const int m = row0 + wm + i * 16 + quad * 4 + r;
      const int s = m >> 6;
      const float lp = log_probs[s];
      const bool isr = (m & 63) == root_local[s];
      const size_t base = (size_t)m * HH;
#pragma unroll
      for (int j = 0; j < 4; ++j)
        Cf[base + nj[j]] = acc[i][j][r] + c0a[j] + lp * vla[j] + (isr ? re1[j] : re0[j]);
    }
}

// ---------------------------------------------------------------------------
// Final BN apply with residual; coef computed inline from stats; fp16 u input.
// ---------------------------------------------------------------------------
__launch_bounds__(256)
__global__ void bn_apply_k(const _Float16* __restrict__ u, float* __restrict__ h,
                           const float* __restrict__ stats,
                           const float* __restrict__ gamma, const float* __restrict__ beta) {
  size_t i4 = (size_t)(blockIdx.x * 256 + threadIdx.x) * 4;
  int c = (int)(i4 & 127);
  const float invM = 1.0f / (float)SKK;
  float sc[4], sh[4];
#pragma unroll
  for (int e = 0; e < 4; ++e) {
    const float mu = stats[c + e] * invM;
    const float var = fmaf(-mu, mu, stats[HH + c + e] * invM);
    const float s = rsqrtf(var + 1e-5f) * gamma[c + e];
    sc[e] = s; sh[e] = fmaf(-mu, s, beta[c + e]);
  }
  half4 uv = *(const half4*)(u + i4);
  float4 hv = *(const float4*)(h + i4);
  float4 o;
  o.x = fmaf((float)uv.x, sc[0], sh[0]) + hv.x;
  o.y = fmaf((float)uv.y, sc[1], sh[1]) + hv.y;
  o.z = fmaf((float)uv.z, sc[2], sh[2]) + hv.z;
  o.w = fmaf((float)uv.w, sc[3], sh[3]) + hv.w;
  *(float4*)(h + i4) = o;
}

// ---------------------------------------------------------------------------
extern "C" void kernel_launch(void* const* d_in, const int* in_sizes, int n_in,
                              void* d_out, int out_size, void* d_ws, size_t ws_size,
                              hipStream_t stream) {
  const float* x          = (const float*)d_in[0];
  const float* log_probs  = (const float*)d_in[1];
  const float* node_w     = (const float*)d_in[2];
  const float* node_b     = (const float*)d_in[3];
  const float* logp_w     = (const float*)d_in[4];
  const float* logp_b     = (const float*)d_in[5];
  const float* root_emb   = (const float*)d_in[6];
  const float* init_w     = (const float*)d_in[7];
  const float* init_b     = (const float*)d_in[8];
  const float* gin_eps    = (const float*)d_in[9];
  const float* w1         = (const float*)d_in[10];
  const float* b1         = (const float*)d_in[11];
  const float* w2         = (const float*)d_in[12];
  const float* b2         = (const float*)d_in[13];
  const float* mp2w       = (const float*)d_in[14];
  const float* mp2b       = (const float*)d_in[15];
  const float* gamma      = (const float*)d_in[16];
  const float* beta       = (const float*)d_in[17];
  const int*   nodes      = (const int*)d_in[18];
  const int*   root_local = (const int*)d_in[19];
  const int*   edge_idx   = (const int*)d_in[20];
  const int*   edge_ptr   = (const int*)d_in[21];
  float* h = (float*)d_out;   // fp32 residual stream lives in d_out

  // ---- workspace carve ----
  char* wp = (char*)d_ws;
  auto take = [&](size_t bytes) { char* p = wp; wp += (bytes + 255) & ~(size_t)255; return p; };
  ushort* zh    = (ushort*)take((size_t)SKK * HH * 2);   // 32 MB
  ushort* zl    = (ushort*)take((size_t)SKK * HH * 2);
  _Float16* uh  = (_Float16*)take((size_t)SKK * HH * 2); // 32 MB fp16 u
  ushort* xah   = (ushort*)take((size_t)NN * HH * 2);
  ushort* xal   = (ushort*)take((size_t)NN * HH * 2);
  ushort* Mth   = (ushort*)take((size_t)HH * HH * 2);
  ushort* Mtl   = (ushort*)take((size_t)HH * HH * 2);
  ushort* w1th  = (ushort*)take((size_t)LLAY * HH * HH * 2);
  ushort* w1tl  = (ushort*)take((size_t)LLAY * HH * HH * 2);
  ushort* w2th  = (ushort*)take((size_t)LLAY * HH * HH * 2);
  ushort* w2tl  = (ushort*)take((size_t)LLAY * HH * HH * 2);
  ushort* mp2th = (ushort*)take((size_t)LLAY * HH * 256 * 2);
  ushort* mp2tl = (ushort*)take((size_t)LLAY * HH * 256 * 2);
  float* vl       = (float*)take(HH * 4);
  float* c0v      = (float*)take(HH * 4);
  float* rev      = (float*)take(2 * HH * 4);
  float* bn_stats = (float*)take(LLAY * 2 * HH * 4);
  int*   cnti     = (int*)take((size_t)NN * 4);
  int*   excl     = (int*)take((size_t)NBLK * 256 * 4);
  int*   bsum     = (int*)take(256 * 4);
  int*   boff     = (int*)take(256 * 4);
  int*   node_ptr = (int*)take((size_t)(NN + 1) * 4);
  int*   cur      = (int*)take((size_t)NN * 4);
  int*   rowlist  = (int*)take((size_t)SKK * 4);
  int*   row_ptr  = (int*)take((size_t)(SKK + 1) * 4);
  int*   ssrc     = (int*)take((size_t)EE * 4);

  // ---- prologue ----
  hipMemsetAsync(cnti, 0, (size_t)NN * 4, stream);
  hipMemsetAsync(cur, 0, (size_t)NN * 4, stream);
  hipMemsetAsync(bn_stats, 0, LLAY * 2 * HH * 4, stream);
  fold_M_k<<<HH, HH, 0, stream>>>(node_w, init_w, Mth, Mtl);
  fold_vec_k<<<1, HH, 0, stream>>>(init_w, logp_w, node_b, logp_b, init_b, root_emb,
                                   vl, c0v, rev);
  wconv_k<<<2560, HH, 0, stream>>>(w1, w2, mp2w, w1th, w1tl, w2th, w2tl, mp2th, mp2tl);
  count_k<<<SKK / 256, 256, 0, stream>>>(nodes, cnti);
  scan1_k<<<NBLK, 256, 0, stream>>>(cnti, excl, bsum);
  scan2_k<<<1, 256, 0, stream>>>(bsum, boff);
  scan3_k<<<NBLK, 256, 0, stream>>>(excl, boff, node_ptr);
  fill_rows_k<<<SKK / 256, 256, 0, stream>>>(nodes, node_ptr, cur, rowlist);
  presort_k<<<SS, 256, 0, stream>>>(edge_idx, edge_idx + EE, edge_ptr, row_ptr, ssrc);

  // initial h (fp32, in d_out)
  mgemm0_k<<<SKK / 128, 256, 0, stream>>>(x, Mth, Mtl, h,
                                          nodes, log_probs, root_local, vl, c0v, rev);

  for (int l = 0; l < LLAY; ++l) {
    if (l == 0) {
      gin_mega_k<true><<<SS, 256, 0, stream>>>(h, nullptr, nullptr, nullptr, nullptr,
                                               row_ptr, ssrc, gin_eps, l,
                                               w1th + (size_t)l * HH * HH,
                                               w1tl + (size_t)l * HH * HH,
                                               w2th + (size_t)l * HH * HH,
                                               w2tl + (size_t)l * HH * HH,
                                               b1 + l * HH, b2 + l * HH, zh, zl);
    } else {
      gin_mega_k<false><<<SS, 256, 0, stream>>>(h, uh, bn_stats + (l - 1) * 2 * HH,
                                                gamma + (l - 1) * HH, beta + (l - 1) * HH,
                                                row_ptr, ssrc, gin_eps, l,
                                                w1th + (size_t)l * HH * HH,
                                                w1tl + (size_t)l * HH * HH,
                                                w2th + (size_t)l * HH * HH,
                                                w2tl + (size_t)l * HH * HH,
                                                b1 + l * HH, b2 + l * HH, zh, zl);
    }
    scatter_mean_k<<<(NN + 15) / 16, 256, 0, stream>>>(zh, zl, node_ptr, rowlist, xah, xal);
    mp2_k<<<SKK / 128, 256, 0, stream>>>(zh, zl, xah, xal,
                                         mp2th + (size_t)l * HH * 256,
                                         mp2tl + (size_t)l * HH * 256,
                                         mp2b + l * HH, uh, nodes,
                                         bn_stats + l * 2 * HH);
  }
  // final BN+residual apply (layer 4) -> h in d_out
  bn_apply_k<<<(SKK * HH / 4) / 256, 256, 0, stream>>>(uh, h, bn_stats + 4 * 2 * HH,
                                                       gamma + 4 * HH, beta + 4 * HH);
}

// Round 15
// 800.079 us; speedup vs baseline: 1.3344x; 1.1382x over previous
//
#include <hip/hip_runtime.h>
#include <cstdint>

#define NN   50000
#define SS   2048
#define KSUB 64
#define HH   128
#define EE   (SS * 256)
#define SKK  (SS * KSUB)    // 131072
#define LLAY 5
#define NBLK 196            // ceil(NN/256)

typedef __attribute__((ext_vector_type(8))) short bhalf8;
typedef __attribute__((ext_vector_type(4))) float f32x4;
typedef __attribute__((ext_vector_type(4))) _Float16 half4;

__device__ __forceinline__ ushort f2b(float f) {
  uint u = __builtin_bit_cast(uint, f);
  uint r = (u + 0x7FFFu + ((u >> 16) & 1u)) >> 16;
  return (ushort)r;
}
__device__ __forceinline__ float b2f(ushort u) {
  uint v = ((uint)u) << 16;
  return __builtin_bit_cast(float, v);
}
// split fp32 -> (hi, lo) bf16 pair; hi + lo ~= f with ~2^-18 residual
__device__ __forceinline__ void fsplit(float f, ushort& hi, ushort& lo) {
  hi = f2b(f);
  lo = f2b(f - b2f(hi));
}
// byte offset into a [64][128]-short LDS tile, T2 XOR swizzle (row stride 256B)
__device__ __forceinline__ int zoff(int row, int col) {
  return row * 256 + (((col * 2) & 255) ^ ((row & 7) << 4));
}

// ---------------------------------------------------------------------------
// Fold node_proj through init_proj; emit split bf16 B^T layout [n][c]
// ---------------------------------------------------------------------------
__global__ void fold_M_k(const float* __restrict__ Wn, const float* __restrict__ Wi,
                         ushort* __restrict__ Mth, ushort* __restrict__ Mtl) {
  int c = blockIdx.x, n = threadIdx.x;
  float s = 0.f;
  for (int k = 0; k < HH; ++k) s = fmaf(Wn[c * HH + k], Wi[k * HH + n], s);
  ushort hi, lo; fsplit(s, hi, lo);
  Mth[n * HH + c] = hi; Mtl[n * HH + c] = lo;
}

__global__ void fold_vec_k(const float* __restrict__ Wi, const float* __restrict__ wl,
                           const float* __restrict__ bnb, const float* __restrict__ blb,
                           const float* __restrict__ bi, const float* __restrict__ remb,
                           float* __restrict__ vl, float* __restrict__ c0,
                           float* __restrict__ rev) {
  int n = threadIdx.x;
  float svl = 0.f, sc0 = bi[n], r0 = 0.f, r1 = 0.f;
  for (int k = 0; k < HH; ++k) {
    svl = fmaf(wl[k], Wi[(HH + k) * HH + n], svl);
    sc0 = fmaf(bnb[k], Wi[k * HH + n], sc0);
    sc0 = fmaf(blb[k], Wi[(HH + k) * HH + n], sc0);
    r0  = fmaf(remb[k],      Wi[(2 * HH + k) * HH + n], r0);
    r1  = fmaf(remb[HH + k], Wi[(2 * HH + k) * HH + n], r1);
  }
  vl[n] = svl; c0[n] = sc0; rev[n] = r0; rev[HH + n] = r1;
}

// ---------------------------------------------------------------------------
// Transpose+convert all layer weights to split bf16 B^T layout (one launch).
// ---------------------------------------------------------------------------
__global__ void wconv_k(const float* __restrict__ w1, const float* __restrict__ w2,
                        const float* __restrict__ mp2w,
                        ushort* __restrict__ w1th, ushort* __restrict__ w1tl,
                        ushort* __restrict__ w2th, ushort* __restrict__ w2tl,
                        ushort* __restrict__ mp2th, ushort* __restrict__ mp2tl) {
  int b = blockIdx.x, n = threadIdx.x;
  ushort hi, lo;
  if (b < 640) {
    int l = b >> 7, k = b & 127;
    fsplit(w1[((size_t)l * HH + k) * HH + n], hi, lo);
    w1th[((size_t)l * HH + n) * HH + k] = hi;
    w1tl[((size_t)l * HH + n) * HH + k] = lo;
  } else if (b < 1280) {
    int bb = b - 640; int l = bb >> 7, k = bb & 127;
    fsplit(w2[((size_t)l * HH + k) * HH + n], hi, lo);
    w2th[((size_t)l * HH + n) * HH + k] = hi;
    w2tl[((size_t)l * HH + n) * HH + k] = lo;
  } else {
    int bb = b - 1280; int l = bb >> 8, k = bb & 255;
    fsplit(mp2w[((size_t)l * 256 + k) * HH + n], hi, lo);
    mp2th[((size_t)l * HH + n) * 256 + k] = hi;
    mp2tl[((size_t)l * HH + n) * 256 + k] = lo;
  }
}

// ---------------------------------------------------------------------------
// Node-CSR construction: count -> exclusive scan -> fill
// ---------------------------------------------------------------------------
__global__ void count_k(const int* __restrict__ idc, int* __restrict__ cnt) {
  int i = blockIdx.x * 256 + threadIdx.x;
  if (i < SKK) atomicAdd(&cnt[idc[i]], 1);
}

__global__ void scan1_k(const int* __restrict__ cnt, int* __restrict__ excl,
                        int* __restrict__ bsum) {
  __shared__ int sh[256];
  const int tid = threadIdx.x;
  const int i = blockIdx.x * 256 + tid;
  int v = (i < NN) ? cnt[i] : 0;
  sh[tid] = v;
  __syncthreads();
#pragma unroll
  for (int off = 1; off < 256; off <<= 1) {
    int t = (tid >= off) ? sh[tid - off] : 0;
    __syncthreads();
    sh[tid] += t;
    __syncthreads();
  }
  excl[i] = sh[tid] - v;
  if (tid == 255) bsum[blockIdx.x] = sh[tid];
}

__global__ void scan2_k(int* __restrict__ bsum, int* __restrict__ boff) {
  __shared__ int sh[256];
  const int tid = threadIdx.x;
  int v = (tid < NBLK) ? bsum[tid] : 0;
  sh[tid] = v;
  __syncthreads();
#pragma unroll
  for (int off = 1; off < 256; off <<= 1) {
    int t = (tid >= off) ? sh[tid - off] : 0;
    __syncthreads();
    sh[tid] += t;
    __syncthreads();
  }
  boff[tid] = sh[tid] - v;
}

__global__ void scan3_k(const int* __restrict__ excl, const int* __restrict__ boff,
                        int* __restrict__ node_ptr) {
  int i = blockIdx.x * 256 + threadIdx.x;
  if (i < NN) node_ptr[i] = excl[i] + boff[blockIdx.x];
  if (i == 0) node_ptr[NN] = SKK;
}

__global__ void fill_rows_k(const int* __restrict__ idc, const int* __restrict__ node_ptr,
                            int* __restrict__ cur, int* __restrict__ rowlist) {
  int i = blockIdx.x * 256 + threadIdx.x;
  if (i < SKK) {
    int id = idc[i];
    int pos = atomicAdd(&cur[id], 1);
    rowlist[node_ptr[id] + pos] = i;
  }
}

// ---------------------------------------------------------------------------
// Cross-subgraph scatter-mean as a GATHER. Single-bf16 z in / xa out.
// 16 lanes/node, 16B uint4 loads per lane, 16 nodes/block.
// ---------------------------------------------------------------------------
__launch_bounds__(256)
__global__ void scatter_mean_k(const ushort* __restrict__ zh,
                               const int* __restrict__ node_ptr,
                               const int* __restrict__ rowlist,
                               ushort* __restrict__ xah) {
  const int tid = threadIdx.x;
  const int n = blockIdx.x * 16 + (tid >> 4);
  if (n >= NN) return;
  const int c8 = (tid & 15) * 8;
  const int p0 = node_ptr[n], p1 = node_ptr[n + 1];
  float s[8] = {0.f, 0.f, 0.f, 0.f, 0.f, 0.f, 0.f, 0.f};
  for (int p = p0; p < p1; ++p) {
    const size_t off = (size_t)rowlist[p] * HH + c8;
    uint4 vh = *(const uint4*)(zh + off);
    const uint hw[4] = {vh.x, vh.y, vh.z, vh.w};
#pragma unroll
    for (int k = 0; k < 4; ++k) {
      s[2 * k]     += b2f((ushort)hw[k]);
      s[2 * k + 1] += b2f((ushort)(hw[k] >> 16));
    }
  }
  const float inv = 1.0f / (float)max(p1 - p0, 1);
  ushort hi[8];
#pragma unroll
  for (int k = 0; k < 8; ++k) hi[k] = f2b(s[k] * inv);
  *(uint4*)(xah + (size_t)n * HH + c8) = *(uint4*)hi;
}

// ---------------------------------------------------------------------------
// Per-subgraph counting sort of edges by dst -> CSR
// ---------------------------------------------------------------------------
__launch_bounds__(256)
__global__ void presort_k(const int* __restrict__ e_src, const int* __restrict__ e_dst,
                          const int* __restrict__ edge_ptr, int* __restrict__ row_ptr,
                          int* __restrict__ ssrc) {
  __shared__ int cnt[KSUB];
  __shared__ int base[KSUB];
  __shared__ int cur[KSUB];
  const int s = blockIdx.x, tid = threadIdx.x;
  const int p0 = edge_ptr[s], p1 = edge_ptr[s + 1];
  if (tid < KSUB) cnt[tid] = 0;
  __syncthreads();
  for (int e = p0 + tid; e < p1; e += 256) atomicAdd(&cnt[e_dst[e]], 1);
  __syncthreads();
  if (tid == 0) {
    int a = 0;
    for (int d = 0; d < KSUB; ++d) { base[d] = a; a += cnt[d]; }
  }
  __syncthreads();
  if (tid < KSUB) { row_ptr[s * KSUB + tid] = p0 + base[tid]; cur[tid] = base[tid]; }
  if (s == 0 && tid == 0) row_ptr[SS * KSUB] = edge_ptr[SS];
  __syncthreads();
  for (int e = p0 + tid; e < p1; e += 256) {
    int d = e_dst[e];
    int pos = atomicAdd(&cur[d], 1);
    ssrc[p0 + pos] = e_src[e];
  }
}

// ---------------------------------------------------------------------------
// MEGA kernel: per subgraph (64 rows). Internal Z/T LDS tiles stay SPLIT
// (full precision for MLP1/MLP2); only the global z output is single bf16.
// ---------------------------------------------------------------------------
template <bool FIRST>
__launch_bounds__(256, 4)
__global__ void gin_mega_k(float* __restrict__ h, const _Float16* __restrict__ uh,
                           const float* __restrict__ stats,
                           const float* __restrict__ gamma, const float* __restrict__ beta,
                           const int* __restrict__ row_ptr, const int* __restrict__ ssrc,
                           const float* __restrict__ gin_eps, const int layer,
                           const ushort* __restrict__ B1h, const ushort* __restrict__ B1l,
                           const ushort* __restrict__ B2h, const ushort* __restrict__ B2l,
                           const float* __restrict__ bias1, const float* __restrict__ bias2,
                           ushort* __restrict__ zh) {
  constexpr int LDH = 132;
  __shared__ __align__(16) char smem[KSUB * LDH * 4];   // 33792 B, phase-aliased
  __shared__ int ssrc_lds[256];                          // 1 KB edge-source cache
  float*  hl = (float*)smem;                 // [64][132] fp32 (phases A,B)
  ushort* Zh = (ushort*)smem;                // [64][128] swizzled (phases C..out)
  ushort* Zl = (ushort*)(smem + KSUB * HH * 2);
  const int s = blockIdx.x, tid = threadIdx.x;
  const size_t base = (size_t)s * KSUB * HH;

  // ---- stage ssrc (coalesced, 1 iteration for ES=256) ----
  const int e_start = row_ptr[s * KSUB];
  {
    const int e_end = row_ptr[s * KSUB + KSUB];
    for (int e = e_start + tid; e < e_end; e += 256)
      ssrc_lds[e - e_start] = ssrc[e];
  }

  // ---- phase A (BN coef inline; c constant across 'it' since 1024 % 128 == 0) ----
  float csc[4], csh[4];
  const int cb = (tid * 4) & 127;
  if constexpr (!FIRST) {
    const float invM = 1.0f / (float)SKK;
#pragma unroll
    for (int e = 0; e < 4; ++e) {
      const float mu = stats[cb + e] * invM;
      const float var = fmaf(-mu, mu, stats[HH + cb + e] * invM);
      const float sc = rsqrtf(var + 1e-5f) * gamma[cb + e];
      csc[e] = sc; csh[e] = fmaf(-mu, sc, beta[cb + e]);
    }
  }
#pragma unroll
  for (int it = 0; it < 8; ++it) {
    const int idx = it * 1024 + tid * 4;
    const int m = idx >> 7, c = idx & 127;
    float4 hv = *(const float4*)&h[base + idx];
    if constexpr (!FIRST) {
      half4 u4 = *(const half4*)&uh[base + idx];
      hv.x += fmaf((float)u4.x, csc[0], csh[0]);
      hv.y += fmaf((float)u4.y, csc[1], csh[1]);
      hv.z += fmaf((float)u4.z, csc[2], csh[2]);
      hv.w += fmaf((float)u4.w, csc[3], csh[3]);
      *(float4*)&h[base + idx] = hv;
    }
    *(float4*)&hl[m * LDH + c] = hv;
  }
  __syncthreads();

  // ---- phase B: aggregation (interleaved channel mapping; ssrc from LDS) ----
  const float ep1 = 1.0f + gin_eps[layer];
  const int d = tid >> 2, q4 = (tid & 3) * 4;   // cols q4 + 16*j + k
  const int g = s * KSUB + d;
  const int e0 = row_ptr[g], e1 = row_ptr[g + 1];
  float a[32];
  {
    const float* hp0 = &hl[d * LDH + q4];
#pragma unroll
    for (int j = 0; j < 8; ++j) {
      float4 v = *(const float4*)(hp0 + 16 * j);
      a[4 * j + 0] = ep1 * v.x; a[4 * j + 1] = ep1 * v.y;
      a[4 * j + 2] = ep1 * v.z; a[4 * j + 3] = ep1 * v.w;
    }
    for (int e = e0; e < e1; ++e) {
      const float* hp = &hl[ssrc_lds[e - e_start] * LDH + q4];
#pragma unroll
      for (int j = 0; j < 8; ++j) {
        float4 v = *(const float4*)(hp + 16 * j);
        a[4 * j + 0] += v.x; a[4 * j + 1] += v.y;
        a[4 * j + 2] += v.z; a[4 * j + 3] += v.w;
      }
    }
  }
  __syncthreads();          // all hl reads done (Z aliases hl)

  // ---- phase C: split z_agg into swizzled LDS tile (8B writes) ----
#pragma unroll
  for (int j = 0; j < 8; ++j) {
    ushort th[4], tl[4];
#pragma unroll
    for (int k = 0; k < 4; ++k) fsplit(a[4 * j + k], th[k], tl[k]);
    const int o = zoff(d, q4 + 16 * j);
    *(uint2*)((char*)Zh + o) = *(uint2*)th;
    *(uint2*)((char*)Zl + o) = *(uint2*)tl;
  }
  __syncthreads();

  // ---- MLP GEMMs ----
  const int lane = tid & 63, wv = tid >> 6;
  const int fr = lane & 15, quad = lane >> 4;
  const int nj0 = wv * 32 + fr, nj1 = nj0 + 16;

  f32x4 acc[4][2];
#pragma unroll
  for (int i = 0; i < 4; ++i) { acc[i][0] = (f32x4){0,0,0,0}; acc[i][1] = (f32x4){0,0,0,0}; }

  // MLP1: t = relu(Z @ W1 + b1)
#pragma unroll
  for (int ch = 0; ch < 4; ++ch) {
    bhalf8 afh[4], afl[4], bfh[2], bfl[2];
#pragma unroll
    for (int i = 0; i < 4; ++i) {
      const int o = zoff(i * 16 + fr, ch * 32 + quad * 8);
      afh[i] = *(const bhalf8*)((const char*)Zh + o);
      afl[i] = *(const bhalf8*)((const char*)Zl + o);
    }
#pragma unroll
    for (int j = 0; j < 2; ++j) {
      const size_t off = (size_t)(wv * 32 + j * 16 + fr) * HH + ch * 32 + quad * 8;
      bfh[j] = *(const bhalf8*)(B1h + off);
      bfl[j] = *(const bhalf8*)(B1l + off);
    }
#pragma unroll
    for (int i = 0; i < 4; ++i)
#pragma unroll
      for (int j = 0; j < 2; ++j) {
        acc[i][j] = __builtin_amdgcn_mfma_f32_16x16x32_bf16(afh[i], bfh[j], acc[i][j], 0, 0, 0);
        acc[i][j] = __builtin_amdgcn_mfma_f32_16x16x32_bf16(afl[i], bfh[j], acc[i][j], 0, 0, 0);
        acc[i][j] = __builtin_amdgcn_mfma_f32_16x16x32_bf16(afh[i], bfl[j], acc[i][j], 0, 0, 0);
      }
  }
  __syncthreads();          // all Z reads done (T aliases Z)

  // epilogue 1: T = relu(acc + b1), split, into swizzled LDS
  {
    const float b10 = bias1[nj0], b11 = bias1[nj1];
#pragma unroll
    for (int i = 0; i < 4; ++i)
#pragma unroll
      for (int r = 0; r < 4; ++r) {
        const int row = i * 16 + quad * 4 + r;
        const float o0 = fmaxf(acc[i][0][r] + b10, 0.f);
        const float o1 = fmaxf(acc[i][1][r] + b11, 0.f);
        ushort h0, l0, h1, l1; fsplit(o0, h0, l0); fsplit(o1, h1, l1);
        *(ushort*)((char*)Zh + zoff(row, nj0)) = h0;
        *(ushort*)((char*)Zl + zoff(row, nj0)) = l0;
        *(ushort*)((char*)Zh + zoff(row, nj1)) = h1;
        *(ushort*)((char*)Zl + zoff(row, nj1)) = l1;
      }
  }
  __syncthreads();

  // MLP2: z = T @ W2 + b2
#pragma unroll
  for (int i = 0; i < 4; ++i) { acc[i][0] = (f32x4){0,0,0,0}; acc[i][1] = (f32x4){0,0,0,0}; }
#pragma unroll
  for (int ch = 0; ch < 4; ++ch) {
    bhalf8 afh[4], afl[4], bfh[2], bfl[2];
#pragma unroll
    for (int i = 0; i < 4; ++i) {
      const int o = zoff(i * 16 + fr, ch * 32 + quad * 8);
      afh[i] = *(const bhalf8*)((const char*)Zh + o);
      afl[i] = *(const bhalf8*)((const char*)Zl + o);
    }
#pragma unroll
    for (int j = 0; j < 2; ++j) {
      const size_t off = (size_t)(wv * 32 + j * 16 + fr) * HH + ch * 32 + quad * 8;
      bfh[j] = *(const bhalf8*)(B2h + off);
      bfl[j] = *(const bhalf8*)(B2l + off);
    }
#pragma unroll
    for (int i = 0; i < 4; ++i)
#pragma unroll
      for (int j = 0; j < 2; ++j) {
        acc[i][j] = __builtin_amdgcn_mfma_f32_16x16x32_bf16(afh[i], bfh[j], acc[i][j], 0, 0, 0);
        acc[i][j] = __builtin_amdgcn_mfma_f32_16x16x32_bf16(afl[i], bfh[j], acc[i][j], 0, 0, 0);
        acc[i][j] = __builtin_amdgcn_mfma_f32_16x16x32_bf16(afh[i], bfl[j], acc[i][j], 0, 0, 0);
      }
  }
  __syncthreads();          // all T reads done — Z tile now dead, reuse for z

  // epilogue 2a: round z to single bf16 into swizzled Zh tile
  {
    const float b20 = bias2[nj0], b21 = bias2[nj1];
#pragma unroll
    for (int i = 0; i < 4; ++i)
#pragma unroll
      for (int r = 0; r < 4; ++r) {
        const int row = i * 16 + quad * 4 + r;
        *(ushort*)((char*)Zh + zoff(row, nj0)) = f2b(acc[i][0][r] + b20);
        *(ushort*)((char*)Zh + zoff(row, nj1)) = f2b(acc[i][1][r] + b21);
      }
  }
  __syncthreads();

  // epilogue 2b: coalesced copy-out (single buffer now)
#pragma unroll
  for (int k = 0; k < 4; ++k) {
    const int gidx = tid * 8 + k * 2048;         // ushort index in [0, 8192)
    const int row = gidx >> 7;
    const int col = gidx & 127;
    const int o = zoff(row, col);
    *(uint4*)(zh + base + gidx) = *(const uint4*)((const char*)Zh + o);
  }
}

// ---------------------------------------------------------------------------
// MP-2 GEMM: 128-row LDS-staged + two-deep T14 prefetch. A-side is single
// bf16 (z / xa), B-side stays split: 2 MFMAs per fragment (Ah*Bh + Ah*Bl).
// fp16 u staged through LDS then coalesced copy-out (round-14 verified).
// ---------------------------------------------------------------------------
__launch_bounds__(256, 3)
__global__ void mp2_k(const ushort* __restrict__ Ah,
                      const ushort* __restrict__ A2h,
                      const ushort* __restrict__ Bh, const ushort* __restrict__ Bl,
                      const float* __restrict__ bias, _Float16* __restrict__ Cf,
                      const int* __restrict__ idc, float* __restrict__ stats) {
  constexpr int LDP = 40;   // LDS row stride in shorts (staging phase)
  constexpr int LDU = 136;  // fp16 u-tile row stride (epilogue)
  __shared__ __align__(16) char smem[35840];   // staging 30720B / epilogue 35840B
  ushort* Ash = (ushort*)smem;
  ushort* Bsh = (ushort*)(smem + 10240);
  ushort* Bsl = (ushort*)(smem + 20480);
  const int tid = threadIdx.x;
  const int row0 = blockIdx.x * 128;
  const int lane = tid & 63, wv = tid >> 6;
  const int wm = (wv >> 1) * 64, wn = (wv & 1) * 64;
  const int fr = lane & 15, quad = lane >> 4;
  const int sr = tid >> 1;            // staging row 0..127
  const int sc = (tid & 1) * 16;      // staging short-offset {0,16}
  const int grow = idc[row0 + sr];    // gather row for K-half 2 (hoisted)

  f32x4 acc[4][4];
#pragma unroll
  for (int i = 0; i < 4; ++i)
#pragma unroll
    for (int j = 0; j < 4; ++j) acc[i][j] = (f32x4){0.f, 0.f, 0.f, 0.f};

  // two named prefetch sets (E = even chunks, O = odd chunks)
  uint4 eA0, eA1, eB0, eB1, eB2, eB3;
  uint4 oA0, oA1, oB0, oB1, oB2, oB3;
  auto aptr = [&](int ch) -> const ushort* {
    if (ch >= 4) return A2h + ((size_t)grow * HH + (ch - 4) * 32 + sc);
    return Ah + ((size_t)(row0 + sr) * HH + ch * 32 + sc);
  };
  auto LE = [&](int ch) {
    const ushort* ph = aptr(ch);
    eA0 = *(const uint4*)(ph); eA1 = *(const uint4*)(ph + 8);
    const size_t off = (size_t)sr * 256 + ch * 32 + sc;
    eB0 = *(const uint4*)(Bh + off); eB1 = *(const uint4*)(Bh + off + 8);
    eB2 = *(const uint4*)(Bl + off); eB3 = *(const uint4*)(Bl + off + 8);
  };
  auto LO = [&](int ch) {
    const ushort* ph = aptr(ch);
    oA0 = *(const uint4*)(ph); oA1 = *(const uint4*)(ph + 8);
    const size_t off = (size_t)sr * 256 + ch * 32 + sc;
    oB0 = *(const uint4*)(Bh + off); oB1 = *(const uint4*)(Bh + off + 8);
    oB2 = *(const uint4*)(Bl + off); oB3 = *(const uint4*)(Bl + off + 8);
  };
  auto STAGE = [&](uint4 a0, uint4 a1,
                   uint4 b0, uint4 b1, uint4 b2, uint4 b3) {
    *(uint4*)&Ash[sr * LDP + sc]     = a0;
    *(uint4*)&Ash[sr * LDP + sc + 8] = a1;
    *(uint4*)&Bsh[sr * LDP + sc]     = b0;
    *(uint4*)&Bsh[sr * LDP + sc + 8] = b1;
    *(uint4*)&Bsl[sr * LDP + sc]     = b2;
    *(uint4*)&Bsl[sr * LDP + sc + 8] = b3;
  };
  auto MFMA_STEP = [&]() {
    bhalf8 afh[4], bfh[4], bfl[4];
#pragma unroll
    for (int i = 0; i < 4; ++i) {
      const int r = (wm + i * 16 + fr) * LDP + quad * 8;
      afh[i] = *(const bhalf8*)&Ash[r];
    }
#pragma unroll
    for (int j = 0; j < 4; ++j) {
      const int r = (wn + j * 16 + fr) * LDP + quad * 8;
      bfh[j] = *(const bhalf8*)&Bsh[r];
      bfl[j] = *(const bhalf8*)&Bsl[r];
    }
#pragma unroll
    for (int i = 0; i < 4; ++i)
#pragma unroll
      for (int j = 0; j < 4; ++j) {
        acc[i][j] = __builtin_amdgcn_mfma_f32_16x16x32_bf16(afh[i], bfh[j], acc[i][j], 0, 0, 0);
        acc[i][j] = __builtin_amdgcn_mfma_f32_16x16x32_bf16(afh[i], bfl[j], acc[i][j], 0, 0, 0);
      }
  };

  LE(0); LO(1);
#pragma unroll
  for (int chp = 0; chp < 4; ++chp) {
    STAGE(eA0, eA1, eB0, eB1, eB2, eB3);
    __syncthreads();
    if (chp < 3) LE(2 * chp + 2);
    MFMA_STEP();
    __syncthreads();
    STAGE(oA0, oA1, oB0, oB1, oB2, oB3);
    __syncthreads();
    if (chp < 3) LO(2 * chp + 3);
    MFMA_STEP();
    __syncthreads();
  }

  // ---- epilogue: relu + bias -> fp16 u tile in LDS; BN stats from fp32 ----
  _Float16* uT  = (_Float16*)smem;            // [128][LDU] = 34816 B
  float*    ssum = (float*)(smem + 34816);    // 256 floats
  float*    ssq  = ssum + HH;
  const int nj[4] = {wn + fr, wn + 16 + fr, wn + 32 + fr, wn + 48 + fr};
  float bb[4];
#pragma unroll
  for (int j = 0; j < 4; ++j) bb[j] = bias[nj[j]];
  float psum[4] = {0.f, 0.f, 0.f, 0.f}, psq[4] = {0.f, 0.f, 0.f, 0.f};
#pragma unroll
  for (int i = 0; i < 4; ++i)
#pragma unroll
    for (int r = 0; r < 4; ++r) {
      const int row = wm + i * 16 + quad * 4 + r;   // 0..127 within tile
#pragma unroll
      for (int j = 0; j < 4; ++j) {
        float o = fmaxf(acc[i][j][r] + bb[j], 0.f);
        uT[row * LDU + nj[j]] = (_Float16)o;
        psum[j] += o; psq[j] += o * o;
      }
    }
  ssum[tid] = 0.f;                             // covers ssum+ssq (256 floats)
  __syncthreads();
#pragma unroll
  for (int j = 0; j < 4; ++j) {
    atomicAdd(&ssum[nj[j]], psum[j]);
    atomicAdd(&ssq[nj[j]], psq[j]);
  }
  __syncthreads();
  // coalesced fp16 copy-out: 8 x uint4 (8 fp16) per thread, lanes contiguous
#pragma unroll
  for (int k = 0; k < 8; ++k) {
    const int idx = tid * 8 + k * 2048;        // fp16 index in [0, 16384)
    const int row = idx >> 7;
    const int col = idx & 127;
    *(uint4*)(Cf + (size_t)(row0 + row) * HH + col) = *(const uint4*)(uT + row * LDU + col);
  }
  if (tid < HH) {
    unsafeAtomicAdd(&stats[tid], ssum[tid]);
    unsafeAtomicAdd(&stats[HH + tid], ssq[tid]);
  }
}

// ---------------------------------------------------------------------------
// Init GEMM (MODE 0): verified LDS-staged structure + T14 issue-early
// prefetch + 3 blocks/CU.
// ---------------------------------------------------------------------------
__launch_bounds__(256, 3)
__global__ void mgemm0_k(const float* __restrict__ Afp,
                         const ushort* __restrict__ Bh, const ushort* __restrict__ Bl,
                         float* __restrict__ Cf,
                         const int* __restrict__ idc, const float* __restrict__ log_probs,
                         const int* __restrict__ root_local, const float* __restrict__ vl,
                         const float* __restrict__ c0v, const float* __restrict__ rev) {
  constexpr int LDP = 40;
  __shared__ __align__(16) ushort Ash[128 * LDP];
  __shared__ __align__(16) ushort Asl[128 * LDP];
  __shared__ __align__(16) ushort Bsh[128 * LDP];
  __shared__ __align__(16) ushort Bsl[128 * LDP];
  const int tid = threadIdx.x;
  const int row0 = blockIdx.x * 128;
  const int lane = tid & 63, wv = tid >> 6;
  const int wm = (wv >> 1) * 64, wn = (wv & 1) * 64;
  const int fr = lane & 15, quad = lane >> 4;
  const int sr = tid >> 1;
  const int sc = (tid & 1) * 16;
  const int arow = idc[row0 + sr];   // hoisted gather row

  f32x4 acc[4][4];
#pragma unroll
  for (int i = 0; i < 4; ++i)
#pragma unroll
    for (int j = 0; j < 4; ++j) acc[i][j] = (f32x4){0.f, 0.f, 0.f, 0.f};

  float4 pf0, pf1, pf2, pf3;
  uint4  pb0, pb1, pb2, pb3;
  auto LA = [&](int ch) {
    const float* src = Afp + (size_t)arow * HH + ch * 32 + sc;
    pf0 = *(const float4*)(src);     pf1 = *(const float4*)(src + 4);
    pf2 = *(const float4*)(src + 8); pf3 = *(const float4*)(src + 12);
  };
  auto LB = [&](int ch) {
    const size_t off = (size_t)sr * HH + ch * 32 + sc;
    pb0 = *(const uint4*)(Bh + off); pb1 = *(const uint4*)(Bh + off + 8);
    pb2 = *(const uint4*)(Bl + off); pb3 = *(const uint4*)(Bl + off + 8);
  };

  LA(0); LB(0);
#pragma unroll
  for (int ch = 0; ch < 4; ++ch) {
    {
      float fv[16];
      *(float4*)&fv[0]  = pf0; *(float4*)&fv[4]  = pf1;
      *(float4*)&fv[8]  = pf2; *(float4*)&fv[12] = pf3;
      ushort hi[16], lo[16];
#pragma unroll
      for (int e = 0; e < 16; ++e) fsplit(fv[e], hi[e], lo[e]);
      *(uint4*)&Ash[sr * LDP + sc]     = *(uint4*)&hi[0];
      *(uint4*)&Ash[sr * LDP + sc + 8] = *(uint4*)&hi[8];
      *(uint4*)&Asl[sr * LDP + sc]     = *(uint4*)&lo[0];
      *(uint4*)&Asl[sr * LDP + sc + 8] = *(uint4*)&lo[8];
    }
    *(uint4*)&Bsh[sr * LDP + sc]     = pb0;
    *(uint4*)&Bsh[sr * LDP + sc + 8] = pb1;
    *(uint4*)&Bsl[sr * LDP + sc]     = pb2;
    *(uint4*)&Bsl[sr * LDP + sc + 8] = pb3;
    __syncthreads();
    if (ch < 3) { LA(ch + 1); LB(ch + 1); }
    bhalf8 afh[4], afl[4], bfh[4], bfl[4];
#pragma unroll
    for (int i = 0; i < 4; ++i) {
      const int r = (wm + i * 16 + fr) * LDP + quad * 8;
      afh[i] = *(const bhalf8*)&Ash[r];
      afl[i] = *(const bhalf8*)&Asl[r];
    }
#pragma unroll
    for (int j = 0; j < 4; ++j) {
      const int r = (wn + j * 16 + fr) * LDP + quad * 8;
      bfh[j] = *(const bhalf8*)&Bsh[r];
      bfl[j] = *(const bhalf8*)&Bsl[r];
    }
#pragma unroll
    for (int i = 0; i < 4; ++i)
#pragma unroll
      for (int j = 0; j < 4; ++j) {
        acc[i][j] = __builtin_amdgcn_mfma_f32_16x16x32_bf16(afh[i], bfh[j], acc[i][j], 0, 0, 0);
        acc[i][j] = __builtin_amdgcn_mfma_f32_16x16x32_bf16(afl[i], bfh[j], acc[i][j], 0, 0, 0);
        acc[i][j] = __builtin_amdgcn_mfma_f32_16x16x32_bf16(afh[i], bfl[j], acc[i][j], 0, 0, 0);
      }
    __syncthreads();
  }

  const int nj[4] = {wn + fr, wn + 16 + fr, wn + 32 + fr, wn + 48 + fr};
  float c0a[4], vla[4], re0[4], re1[4];
#pragma unroll
  for (int j = 0; j < 4; ++j) {
    c0a[j] = c0v[nj[j]]; vla[j] = vl[nj[j]];
    re0[j] = rev[nj[j]]; re1[j] = rev[HH + nj[j]];
  }
#pragma unroll
  for (int i = 0; i < 4; ++i)
#pragma unroll
    for (int r = 0; r < 4; ++r) {
      const int m = row0 + wm + i * 16 + quad * 4 + r;
      const int s = m >> 6;
      const float lp = log_probs[s];
      const bool isr = (m & 63) == root_local[s];
      const size_t base = (size_t)m * HH;
#pragma unroll
      for (int j = 0; j < 4; ++j)
        Cf[base + nj[j]] = acc[i][j][r] + c0a[j] + lp * vla[j] + (isr ? re1[j] : re0[j]);
    }
}

// ---------------------------------------------------------------------------
// Final BN apply with residual; coef computed inline from stats; fp16 u input.
// ---------------------------------------------------------------------------
__launch_bounds__(256)
__global__ void bn_apply_k(const _Float16* __restrict__ u, float* __restrict__ h,
                           const float* __restrict__ stats,
                           const float* __restrict__ gamma, const float* __restrict__ beta) {
  size_t i4 = (size_t)(blockIdx.x * 256 + threadIdx.x) * 4;
  int c = (int)(i4 & 127);
  const float invM = 1.0f / (float)SKK;
  float sc[4], sh[4];
#pragma unroll
  for (int e = 0; e < 4; ++e) {
    const float mu = stats[c + e] * invM;
    const float var = fmaf(-mu, mu, stats[HH + c + e] * invM);
    const float s = rsqrtf(var + 1e-5f) * gamma[c + e];
    sc[e] = s; sh[e] = fmaf(-mu, s, beta[c + e]);
  }
  half4 uv = *(const half4*)(u + i4);
  float4 hv = *(const float4*)(h + i4);
  float4 o;
  o.x = fmaf((float)uv.x, sc[0], sh[0]) + hv.x;
  o.y = fmaf((float)uv.y, sc[1], sh[1]) + hv.y;
  o.z = fmaf((float)uv.z, sc[2], sh[2]) + hv.z;
  o.w = fmaf((float)uv.w, sc[3], sh[3]) + hv.w;
  *(float4*)(h + i4) = o;
}

// ---------------------------------------------------------------------------
extern "C" void kernel_launch(void* const* d_in, const int* in_sizes, int n_in,
                              void* d_out, int out_size, void* d_ws, size_t ws_size,
                              hipStream_t stream) {
  const float* x          = (const float*)d_in[0];
  const float* log_probs  = (const float*)d_in[1];
  const float* node_w     = (const float*)d_in[2];
  const float* node_b     = (const float*)d_in[3];
  const float* logp_w     = (const float*)d_in[4];
  const float* logp_b     = (const float*)d_in[5];
  const float* root_emb   = (const float*)d_in[6];
  const float* init_w     = (const float*)d_in[7];
  const float* init_b     = (const float*)d_in[8];
  const float* gin_eps    = (const float*)d_in[9];
  const float* w1         = (const float*)d_in[10];
  const float* b1         = (const float*)d_in[11];
  const float* w2         = (const float*)d_in[12];
  const float* b2         = (const float*)d_in[13];
  const float* mp2w       = (const float*)d_in[14];
  const float* mp2b       = (const float*)d_in[15];
  const float* gamma      = (const float*)d_in[16];
  const float* beta       = (const float*)d_in[17];
  const int*   nodes      = (const int*)d_in[18];
  const int*   root_local = (const int*)d_in[19];
  const int*   edge_idx   = (const int*)d_in[20];
  const int*   edge_ptr   = (const int*)d_in[21];
  float* h = (float*)d_out;   // fp32 residual stream lives in d_out

  // ---- workspace carve ----
  char* wp = (char*)d_ws;
  auto take = [&](size_t bytes) { char* p = wp; wp += (bytes + 255) & ~(size_t)255; return p; };
  ushort* zh    = (ushort*)take((size_t)SKK * HH * 2);   // 32 MB single-bf16 z
  _Float16* uh  = (_Float16*)take((size_t)SKK * HH * 2); // 32 MB fp16 u
  ushort* xah   = (ushort*)take((size_t)NN * HH * 2);
  ushort* Mth   = (ushort*)take((size_t)HH * HH * 2);
  ushort* Mtl   = (ushort*)take((size_t)HH * HH * 2);
  ushort* w1th  = (ushort*)take((size_t)LLAY * HH * HH * 2);
  ushort* w1tl  = (ushort*)take((size_t)LLAY * HH * HH * 2);
  ushort* w2th  = (ushort*)take((size_t)LLAY * HH * HH * 2);
  ushort* w2tl  = (ushort*)take((size_t)LLAY * HH * HH * 2);
  ushort* mp2th = (ushort*)take((size_t)LLAY * HH * 256 * 2);
  ushort* mp2tl = (ushort*)take((size_t)LLAY * HH * 256 * 2);
  float* vl       = (float*)take(HH * 4);
  float* c0v      = (float*)take(HH * 4);
  float* rev      = (float*)take(2 * HH * 4);
  float* bn_stats = (float*)take(LLAY * 2 * HH * 4);
  int*   cnti     = (int*)take((size_t)NN * 4);
  int*   excl     = (int*)take((size_t)NBLK * 256 * 4);
  int*   bsum     = (int*)take(256 * 4);
  int*   boff     = (int*)take(256 * 4);
  int*   node_ptr = (int*)take((size_t)(NN + 1) * 4);
  int*   cur      = (int*)take((size_t)NN * 4);
  int*   rowlist  = (int*)take((size_t)SKK * 4);
  int*   row_ptr  = (int*)take((size_t)(SKK + 1) * 4);
  int*   ssrc     = (int*)take((size_t)EE * 4);

  // ---- prologue ----
  hipMemsetAsync(cnti, 0, (size_t)NN * 4, stream);
  hipMemsetAsync(cur, 0, (size_t)NN * 4, stream);
  hipMemsetAsync(bn_stats, 0, LLAY * 2 * HH * 4, stream);
  fold_M_k<<<HH, HH, 0, stream>>>(node_w, init_w, Mth, Mtl);
  fold_vec_k<<<1, HH, 0, stream>>>(init_w, logp_w, node_b, logp_b, init_b, root_emb,
                                   vl, c0v, rev);
  wconv_k<<<2560, HH, 0, stream>>>(w1, w2, mp2w, w1th, w1tl, w2th, w2tl, mp2th, mp2tl);
  count_k<<<SKK / 256, 256, 0, stream>>>(nodes, cnti);
  scan1_k<<<NBLK, 256, 0, stream>>>(cnti, excl, bsum);
  scan2_k<<<1, 256, 0, stream>>>(bsum, boff);
  scan3_k<<<NBLK, 256, 0, stream>>>(excl, boff, node_ptr);
  fill_rows_k<<<SKK / 256, 256, 0, stream>>>(nodes, node_ptr, cur, rowlist);
  presort_k<<<SS, 256, 0, stream>>>(edge_idx, edge_idx + EE, edge_ptr, row_ptr, ssrc);

  // initial h (fp32, in d_out)
  mgemm0_k<<<SKK / 128, 256, 0, stream>>>(x, Mth, Mtl, h,
                                          nodes, log_probs, root_local, vl, c0v, rev);

  for (int l = 0; l < LLAY; ++l) {
    if (l == 0) {
      gin_mega_k<true><<<SS, 256, 0, stream>>>(h, nullptr, nullptr, nullptr, nullptr,
                                               row_ptr, ssrc, gin_eps, l,
                                               w1th + (size_t)l * HH * HH,
                                               w1tl + (size_t)l * HH * HH,
                                               w2th + (size_t)l * HH * HH,
                                               w2tl + (size_t)l * HH * HH,
                                               b1 + l * HH, b2 + l * HH, zh);
    } else {
      gin_mega_k<false><<<SS, 256, 0, stream>>>(h, uh, bn_stats + (l - 1) * 2 * HH,
                                                gamma + (l - 1) * HH, beta + (l - 1) * HH,
                                                row_ptr, ssrc, gin_eps, l,
                                                w1th + (size_t)l * HH * HH,
                                                w1tl + (size_t)l * HH * HH,
                                                w2th + (size_t)l * HH * HH,
                                                w2tl + (size_t)l * HH * HH,
                                                b1 + l * HH, b2 + l * HH, zh);
    }
    scatter_mean_k<<<(NN + 15) / 16, 256, 0, stream>>>(zh, node_ptr, rowlist, xah);
    mp2_k<<<SKK / 128, 256, 0, stream>>>(zh, xah,
                                         mp2th + (size_t)l * HH * 256,
                                         mp2tl + (size_t)l * HH * 256,
                                         mp2b + l * HH, uh, nodes,
                                         bn_stats + l * 2 * HH);
  }
  // final BN+residual apply (layer 4) -> h in d_out
  bn_apply_k<<<(SKK * HH / 4) / 256, 256, 0, stream>>>(uh, h, bn_stats + 4 * 2 * HH,
                                                       gamma + 4 * HH, beta + 4 * HH);
}